// Round 5
// baseline (1059.433 us; speedup 1.0000x reference)
//
#include <hip/hip_runtime.h>
#include <stdint.h>

#define EPS 1e-5f
#define SCALE 0.08838834764831845f  /* 1/sqrt(128) */

typedef __bf16 bf16x8 __attribute__((ext_vector_type(8)));
typedef float f32x4 __attribute__((ext_vector_type(4)));
typedef unsigned short u16;
typedef unsigned int u32;
typedef u16 u16x8 __attribute__((ext_vector_type(8)));

__device__ __forceinline__ u16 f2bf(float f) {
  union { float f; u32 u; } x; x.f = f;
  u32 r = x.u + 0x7fffu + ((x.u >> 16) & 1u);
  return (u16)(r >> 16);
}
__device__ __forceinline__ float bf2f(u16 u) {
  union { u32 u; float f; } x; x.u = ((u32)u) << 16; return x.f;
}
__device__ __forceinline__ void glds16(const void* g, void* l) {
  __builtin_amdgcn_global_load_lds((__attribute__((address_space(1))) void*)g,
                                   (__attribute__((address_space(3))) void*)l,
                                   16, 0, 0);
}

// ---------------- f32 -> bf16 convert (single big tensor) --------------------
__global__ __launch_bounds__(256) void f2b_kernel(const float* __restrict__ in,
                                                  u16* __restrict__ out, int n4) {
  int i = blockIdx.x * 256 + threadIdx.x;
  if (i >= n4) return;
  float4 v = ((const float4*)in)[i];
  ((ushort4*)out)[i] = make_ushort4(f2bf(v.x), f2bf(v.y), f2bf(v.z), f2bf(v.w));
}

// ---------------- f32 -> bf16 convert, 10 segments in one launch -------------
struct F2B10 {
  const float* in[10];
  u16* out[10];
  int n4[10];
};
__global__ __launch_bounds__(256) void f2b_multi(F2B10 j) {
  const int seg = blockIdx.y;
  const int n4 = j.n4[seg];
  const float* __restrict__ in = j.in[seg];
  u16* __restrict__ out = j.out[seg];
  for (int i = blockIdx.x * 256 + threadIdx.x; i < n4; i += gridDim.x * 256) {
    float4 v = ((const float4*)in)[i];
    ((ushort4*)out)[i] = make_ushort4(f2bf(v.x), f2bf(v.y), f2bf(v.z), f2bf(v.w));
  }
}

// =============================================================================
// 256x256 8-phase GEMM (T1+T2+T3+T4+T5): C[m,n] = sum_k A[m,k]*B[n,k] (+bias)
// 512 threads = 8 waves (2M x 4N); BK=64; LDS 128 KiB (2 dbuf x (A 32K + B 32K)).
// Swizzle: logical 16B-slot c16 of row r stored at c16 ^ (r&7); applied via
// pre-swizzled GLOBAL source (linear global_load_lds dest) + XOR on ds_read.
// Per phase: {ds_read subtile || stage 1 half-tile -> barrier -> 16 MFMA ->
// barrier}; counted vmcnt(4) only at phases 4/8 (never 0 in the loop).
// Requires M%256==0, N%256==0, K%128==0.
// =============================================================================
#define BAR __builtin_amdgcn_s_barrier()
#define VM4 asm volatile("s_waitcnt vmcnt(4)" ::: "memory")

#define LOADB(buf) do {                                                        \
  _Pragma("unroll") for (int nf = 0; nf < 4; ++nf)                             \
  _Pragma("unroll") for (int ks = 0; ks < 2; ++ks)                             \
    bfr[nf][ks] = *(const bf16x8*)(&sB[buf][wn*4096 + nf*1024 + lr*64 +        \
                                            ((((ks<<2)+lk)^swz)<<3)]);         \
} while (0)

#define LOADA(buf, q) do {                                                     \
  _Pragma("unroll") for (int i = 0; i < 2; ++i)                                \
  _Pragma("unroll") for (int ks = 0; ks < 2; ++ks)                             \
    af[i][ks] = *(const bf16x8*)(&sA[buf][wm*8192 + ((q)*2+i)*1024 + lr*64 +   \
                                          ((((ks<<2)+lk)^swz)<<3)]);           \
} while (0)

#define MFMA16(q) do {                                                         \
  __builtin_amdgcn_s_setprio(1);                                               \
  _Pragma("unroll") for (int i = 0; i < 2; ++i)                                \
  _Pragma("unroll") for (int nf = 0; nf < 4; ++nf)                             \
  _Pragma("unroll") for (int ks = 0; ks < 2; ++ks)                             \
    acc[(q)*2+i][nf] = __builtin_amdgcn_mfma_f32_16x16x32_bf16(                \
        af[i][ks], bfr[nf][ks], acc[(q)*2+i][nf], 0, 0, 0);                    \
  __builtin_amdgcn_s_setprio(0);                                               \
} while (0)

#define STAGEA(buf, h, kt) do {                                                \
  const u16* _s = Abase + (size_t)(h) * rs128 + (size_t)(kt) * 64;             \
  glds16(_s,        &sA[buf][(h)*8192 + woff]);                                \
  glds16(_s + rs64, &sA[buf][(h)*8192 + 4096 + woff]);                         \
} while (0)

#define STAGEB(buf, h, kt) do {                                                \
  const u16* _s = Bbase + (size_t)(h) * rs128 + (size_t)(kt) * 64;             \
  glds16(_s,        &sB[buf][(h)*8192 + woff]);                                \
  glds16(_s + rs64, &sB[buf][(h)*8192 + 4096 + woff]);                         \
} while (0)

__global__ __launch_bounds__(512, 2)
void gemm_bt8(const u16* __restrict__ A, const u16* __restrict__ B,
              const float* __restrict__ bias, u16* __restrict__ Cb,
              int M, int N, int K) {
  __shared__ u16 sA[2][16384];
  __shared__ u16 sB[2][16384];
  const int nwg = (int)(gridDim.x * gridDim.y);
  const int chunk = nwg >> 3;
  int s = blockIdx.y * gridDim.x + blockIdx.x;
  int t = (s & 7) * chunk + (s >> 3);
  const int nbx = (int)gridDim.x;
  const int bn0 = (t % nbx) * 256;
  const int bm0 = (t / nbx) * 256;
  const int tid = threadIdx.x;
  const int w = tid >> 6, l = tid & 63;
  const int wm = w >> 2, wn = w & 3;
  const int lr = l & 15, lk = l >> 4;
  const int swz = lr & 7;
  const int woff = w * 512;               // u16 units (wave base within pass)

  // staging source (pre-swizzled): thread covers row (tid>>3) of each 64-row
  // pass, element cols [scol, scol+8) where scol = ((tid&7)^(srow&7))*8
  const int srow = tid >> 3;
  const int scol = ((tid & 7) ^ (srow & 7)) << 3;
  const u16* Abase = A + (size_t)(bm0 + srow) * K + scol;
  const u16* Bbase = B + (size_t)(bn0 + srow) * K + scol;
  const size_t rs64 = (size_t)64 * K;
  const size_t rs128 = (size_t)128 * K;

  const int nt = K >> 6;                  // K-tiles (even)
  const int ni = nt >> 1;

  f32x4 acc[8][4] = {};
  bf16x8 bfr[4][2];

  // prologue: tile0 (B,A) + tile1 B; wait all but 2 newest half-tiles
  STAGEB(0, 0, 0); STAGEB(0, 1, 0);
  STAGEA(0, 0, 0); STAGEA(0, 1, 0);
  STAGEB(1, 0, 1); STAGEB(1, 1, 1);
  VM4;
  BAR;

  for (int it = 0; it < ni; ++it) {
    const int kt1 = 2 * it + 1;
    int kt2 = 2 * it + 2; if (kt2 >= nt) kt2 -= nt;   // clamped (tail harmless)
    int kt3 = 2 * it + 3; if (kt3 >= nt) kt3 -= nt;
    bf16x8 af[2][2];
    // phase 1: read B(buf0)+A(buf0,q0); stage A-buf1 h0 (tile kt1)
    LOADB(0); LOADA(0, 0); STAGEA(1, 0, kt1);
    BAR; MFMA16(0); BAR;
    // phase 2
    LOADA(0, 1); STAGEA(1, 1, kt1);
    BAR; MFMA16(1); BAR;
    // phase 3 (B-buf0 free since phase 1)
    LOADA(0, 2); STAGEB(0, 0, kt2);
    BAR; MFMA16(2); BAR;
    // phase 4
    LOADA(0, 3); STAGEB(0, 1, kt2);
    BAR; MFMA16(3); VM4; BAR;
    // phase 5: read B(buf1)+A(buf1,q0); stage A-buf0 h0 (tile kt2)
    LOADB(1); LOADA(1, 0); STAGEA(0, 0, kt2);
    BAR; MFMA16(0); BAR;
    // phase 6
    LOADA(1, 1); STAGEA(0, 1, kt2);
    BAR; MFMA16(1); BAR;
    // phase 7 (B-buf1 free since phase 5)
    LOADA(1, 2); STAGEB(1, 0, kt3);
    BAR; MFMA16(2); BAR;
    // phase 8
    LOADA(1, 3); STAGEB(1, 1, kt3);
    BAR; MFMA16(3); VM4; BAR;
  }

  // epilogue: C-write (bf16 scalar stores; 32B row-chunks per 16-lane group)
#pragma unroll
  for (int mf = 0; mf < 8; ++mf) {
    const int grow0 = bm0 + wm * 128 + mf * 16 + lk * 4;
#pragma unroll
    for (int nf = 0; nf < 4; ++nf) {
      const int gcol = bn0 + wn * 64 + nf * 16 + lr;
      const float bv = bias ? bias[gcol] : 0.0f;
#pragma unroll
      for (int i = 0; i < 4; ++i)
        Cb[(size_t)(grow0 + i) * N + gcol] = f2bf(acc[mf][nf][i] + bv);
    }
  }
}

// ---------------- 128x128 GEMM (BK=64, T2-swizzled) for small M --------------
__global__ __launch_bounds__(256)
void gemm_bt(const u16* __restrict__ A, const u16* __restrict__ B,
             const float* __restrict__ bias, u16* __restrict__ Cb,
             int M, int N, int K) {
  __shared__ u16 sA[128 * 64];
  __shared__ u16 sB[128 * 64];
  const int nwg = (int)(gridDim.x * gridDim.y);
  const int chunk = nwg >> 3;
  int s = blockIdx.y * gridDim.x + blockIdx.x;
  int t = (s & 7) * chunk + (s >> 3);
  const int bn0 = (t & 7) * 128;
  const int bm0 = (t >> 3) * 128;
  const int tid = threadIdx.x;
  const int w = tid >> 6, l = tid & 63;
  const int wr = w >> 1, wc = w & 1;
  const int lr = l & 15, lk = l >> 4;
  const int swz = lr & 7;

  const int srow = tid >> 3;
  const int scol = ((tid & 7) ^ (srow & 7)) << 3;
  const u16* Ab = A + (size_t)(bm0 + srow) * K + scol;
  const u16* Bb = B + (size_t)(bn0 + srow) * K + scol;
  const size_t rstride32 = (size_t)32 * K;

  f32x4 acc[4][4] = {};

  for (int k0 = 0; k0 < K; k0 += 64) {
#pragma unroll
    for (int p = 0; p < 4; ++p) {
      glds16(Ab + p * rstride32 + k0, sA + p * 2048 + w * 512);
      glds16(Bb + p * rstride32 + k0, sB + p * 2048 + w * 512);
    }
    __syncthreads();
#pragma unroll
    for (int ks = 0; ks < 2; ++ks) {
      const int off = (((ks << 2) + lk) ^ swz) << 3;
      bf16x8 af[4], bfr[4];
#pragma unroll
      for (int m = 0; m < 4; ++m)
        af[m] = *(const bf16x8*)(sA + (wr * 64 + m * 16 + lr) * 64 + off);
#pragma unroll
      for (int n = 0; n < 4; ++n)
        bfr[n] = *(const bf16x8*)(sB + (wc * 64 + n * 16 + lr) * 64 + off);
#pragma unroll
      for (int m = 0; m < 4; ++m)
#pragma unroll
        for (int n = 0; n < 4; ++n)
          acc[m][n] = __builtin_amdgcn_mfma_f32_16x16x32_bf16(af[m], bfr[n], acc[m][n], 0, 0, 0);
    }
    __syncthreads();
  }

#pragma unroll
  for (int m = 0; m < 4; ++m) {
    const int grow0 = bm0 + wr * 64 + m * 16 + lk * 4;
#pragma unroll
    for (int n = 0; n < 4; ++n) {
      const int gcol = bn0 + wc * 64 + n * 16 + lr;
      const float bv = bias ? bias[gcol] : 0.0f;
#pragma unroll
      for (int i = 0; i < 4; ++i) {
        const float v = acc[m][n][i] + bv;
        Cb[(size_t)(grow0 + i) * N + gcol] = f2bf(v);
      }
    }
  }
}

// ---------------- batched score GEMM: S[bh] = q[b]@k[b,h]^T ------------------
__global__ __launch_bounds__(256)
void score_gemm(const u16* __restrict__ QV, const u16* __restrict__ KB,
                float* __restrict__ out) {
  __shared__ u16 sA[64 * 32];
  __shared__ u16 sB[128 * 32];
  const int bh = blockIdx.z;
  const int b = bh >> 3, h = bh & 7;
  const int bn0 = blockIdx.x * 128;
  const int tid = threadIdx.x;
  const int w = tid >> 6, l = tid & 63;
  const int lr = l & 15, lk = l >> 4;

  const u16* Abase = QV + (size_t)b * 64 * 1024 + h * 128;
  const u16* Bbase = KB + (size_t)b * 1024 * 1024 + (size_t)bn0 * 1024 + h * 128;

  f32x4 acc[4][2] = {};

  for (int k0 = 0; k0 < 128; k0 += 32) {
    {
      const int c = w * 64 + l;
      const int row = c >> 2, kc = c & 3;
      glds16(Abase + (size_t)row * 1024 + k0 + kc * 8, sA + w * 512);
    }
#pragma unroll
    for (int i = 0; i < 2; ++i) {
      const int c = (w * 2 + i) * 64 + l;
      const int row = c >> 2, kc = c & 3;
      glds16(Bbase + (size_t)row * 1024 + k0 + kc * 8, sB + (w * 2 + i) * 512);
    }
    __syncthreads();
    bf16x8 af[4], bfr[2];
#pragma unroll
    for (int m = 0; m < 4; ++m)
      af[m] = *(const bf16x8*)(sA + (m * 16 + lr) * 32 + lk * 8);
#pragma unroll
    for (int n = 0; n < 2; ++n)
      bfr[n] = *(const bf16x8*)(sB + (w * 32 + n * 16 + lr) * 32 + lk * 8);
#pragma unroll
    for (int m = 0; m < 4; ++m)
#pragma unroll
      for (int n = 0; n < 2; ++n)
        acc[m][n] = __builtin_amdgcn_mfma_f32_16x16x32_bf16(af[m], bfr[n], acc[m][n], 0, 0, 0);
    __syncthreads();
  }

  float* C = out + (size_t)bh * 64 * 1024;
#pragma unroll
  for (int m = 0; m < 4; ++m)
#pragma unroll
    for (int n = 0; n < 2; ++n)
#pragma unroll
      for (int i = 0; i < 4; ++i) {
        const int row = m * 16 + lk * 4 + i;
        const int col = bn0 + w * 32 + n * 16 + lr;
        C[(size_t)row * 1024 + col] = acc[m][n][i];
      }
}

// ---------------- vl softmax (in place, with query-mask scale) ---------------
__global__ __launch_bounds__(256)
void vl_softmax(float* __restrict__ S, const float* __restrict__ qmask) {
  __shared__ float red[4];
  const int row = blockIdx.x;          // 16384 = (b*8+h)*64+i
  const int b = row >> 9;
  const int i = row & 63;
  const float scale = qmask[b * 64 + i] * SCALE;
  float* p = S + (size_t)row * 1024;
  const int t = threadIdx.x;
  float4 v = ((const float4*)p)[t];
  v.x *= scale; v.y *= scale; v.z *= scale; v.w *= scale;
  float mx = fmaxf(fmaxf(v.x, v.y), fmaxf(v.z, v.w));
  for (int o = 32; o > 0; o >>= 1) mx = fmaxf(mx, __shfl_xor(mx, o, 64));
  if ((t & 63) == 0) red[t >> 6] = mx;
  __syncthreads();
  mx = fmaxf(fmaxf(red[0], red[1]), fmaxf(red[2], red[3]));
  const float e0 = expf(v.x - mx), e1 = expf(v.y - mx);
  const float e2 = expf(v.z - mx), e3 = expf(v.w - mx);
  float s = e0 + e1 + e2 + e3;
  for (int o = 32; o > 0; o >>= 1) s += __shfl_xor(s, o, 64);
  __syncthreads();
  if ((t & 63) == 0) red[t >> 6] = s;
  __syncthreads();
  s = red[0] + red[1] + red[2] + red[3];
  const float inv = 1.0f / s;
  ((float4*)p)[t] = make_float4(e0 * inv, e1 * inv, e2 * inv, e3 * inv);
}

// ---------------- column stats over bf16 [32768,1024] ------------------------
__global__ __launch_bounds__(256)
void colstats_partial_b(const u16* __restrict__ X, float* __restrict__ ps,
                        float* __restrict__ pq) {
  const int tid = threadIdx.x;
  const int chunk = blockIdx.x;
  const int colb = (tid & 127) * 8;
  const int rg = tid >> 7;
  const u16* p = X + ((size_t)chunk * 128 + rg * 64) * 1024 + colb;
  float s[8] = {}, q[8] = {};
  for (int r = 0; r < 64; ++r) {
    u16x8 v = *(const u16x8*)(p + (size_t)r * 1024);
#pragma unroll
    for (int j = 0; j < 8; ++j) {
      float f = bf2f(v[j]);
      s[j] += f; q[j] += f * f;
    }
  }
  float* dps = ps + (size_t)(chunk * 2 + rg) * 1024 + colb;
  float* dpq = pq + (size_t)(chunk * 2 + rg) * 1024 + colb;
  *(float4*)(dps) = make_float4(s[0], s[1], s[2], s[3]);
  *(float4*)(dps + 4) = make_float4(s[4], s[5], s[6], s[7]);
  *(float4*)(dpq) = make_float4(q[0], q[1], q[2], q[3]);
  *(float4*)(dpq + 4) = make_float4(q[4], q[5], q[6], q[7]);
}
// reduce 512 chunks -> stats. grid (32): block owns 32 cols, 8 chunk-groups.
__global__ __launch_bounds__(256)
void colstats_final(const float* __restrict__ ps, const float* __restrict__ pq,
                    float2* __restrict__ st, float inv_n) {
  __shared__ float rs[8][32], rq[8][32];
  const int cg = threadIdx.x >> 5, cl = threadIdx.x & 31;
  const int col = blockIdx.x * 32 + cl;
  float s = 0.f, q = 0.f;
  for (int i = 0; i < 64; ++i) {
    const size_t idx = (size_t)(cg * 64 + i) * 1024 + col;
    s += ps[idx]; q += pq[idx];
  }
  rs[cg][cl] = s; rq[cg][cl] = q;
  __syncthreads();
  if (cg == 0) {
    for (int i = 1; i < 8; ++i) { s += rs[i][cl]; q += rq[i][cl]; }
    const float m = s * inv_n;
    const float v = q * inv_n - m * m;
    st[col] = make_float2(m, rsqrtf(v + EPS));
  }
}

// ---------------- BN apply (bf16 in) -----------------------------------------
__global__ __launch_bounds__(256)
void bn_apply_bf16(const u16* __restrict__ X, const float2* __restrict__ st,
                   const float* __restrict__ g, const float* __restrict__ be,
                   u16* __restrict__ out) {
  const size_t i = ((size_t)blockIdx.x * 256 + threadIdx.x) * 8;
  const int c = (int)(i & 1023);
  u16x8 x = *(const u16x8*)(X + i);
  u16x8 o;
#pragma unroll
  for (int j = 0; j < 8; ++j) {
    float2 s = st[c + j];
    o[j] = f2bf((bf2f(x[j]) - s.x) * s.y * g[c + j] + be[c + j]);
  }
  *(u16x8*)(out + i) = o;
}
__global__ __launch_bounds__(256)
void bn_apply_f32(const u16* __restrict__ X, const float2* __restrict__ st,
                  const float* __restrict__ g, const float* __restrict__ be,
                  float* __restrict__ out) {
  const size_t i = ((size_t)blockIdx.x * 256 + threadIdx.x) * 8;
  const int c = (int)(i & 1023);
  u16x8 x = *(const u16x8*)(X + i);
  float o[8];
#pragma unroll
  for (int j = 0; j < 8; ++j) {
    float2 s = st[c + j];
    o[j] = (bf2f(x[j]) - s.x) * s.y * g[c + j] + be[c + j];
  }
  *(float4*)(out + i) = make_float4(o[0], o[1], o[2], o[3]);
  *(float4*)(out + i + 4) = make_float4(o[4], o[5], o[6], o[7]);
}

// ---------------- instance-norm stats (bf16 in) ------------------------------
__global__ __launch_bounds__(256)
void instats_partial_b(const u16* __restrict__ X, float* __restrict__ ps,
                       float* __restrict__ pq) {
  const int chunk = blockIdx.x, b = blockIdx.y;
  const int tid = threadIdx.x;
  const int colb = (tid & 127) * 8;
  const int rg = tid >> 7;
  const u16* p = X + (size_t)b * 1048576 + ((size_t)chunk * 128 + rg * 64) * 1024 + colb;
  float s[8] = {}, q[8] = {};
  for (int r = 0; r < 64; ++r) {
    u16x8 v = *(const u16x8*)(p + (size_t)r * 1024);
#pragma unroll
    for (int j = 0; j < 8; ++j) {
      float f = bf2f(v[j]);
      s[j] += f; q[j] += f * f;
    }
  }
  const size_t o = (size_t)(b * 16 + chunk * 2 + rg) * 1024 + colb;
  *(float4*)(ps + o) = make_float4(s[0], s[1], s[2], s[3]);
  *(float4*)(ps + o + 4) = make_float4(s[4], s[5], s[6], s[7]);
  *(float4*)(pq + o) = make_float4(q[0], q[1], q[2], q[3]);
  *(float4*)(pq + o + 4) = make_float4(q[4], q[5], q[6], q[7]);
}
// grid (32 b); thread owns 4 cols, reduce 16 chunks.
__global__ __launch_bounds__(256)
void instats_final(const float* __restrict__ ps, const float* __restrict__ pq,
                   float2* __restrict__ ist) {
  const int b = blockIdx.x, tid = threadIdx.x;
  float4 s = make_float4(0, 0, 0, 0), q = make_float4(0, 0, 0, 0);
#pragma unroll
  for (int i = 0; i < 16; ++i) {
    const size_t o = (size_t)(b * 16 + i) * 1024;
    float4 vs = ((const float4*)(ps + o))[tid];
    float4 vq = ((const float4*)(pq + o))[tid];
    s.x += vs.x; s.y += vs.y; s.z += vs.z; s.w += vs.w;
    q.x += vq.x; q.y += vq.y; q.z += vq.z; q.w += vq.w;
  }
  const float sv[4] = {s.x, s.y, s.z, s.w};
  const float qv[4] = {q.x, q.y, q.z, q.w};
#pragma unroll
  for (int j = 0; j < 4; ++j) {
    const float m = sv[j] * (1.0f / 1024.0f);
    const float var = qv[j] * (1.0f / 1024.0f) - m * m;
    ist[b * 1024 + tid * 4 + j] = make_float2(m, rsqrtf(var + EPS));
  }
}
__global__ __launch_bounds__(256)
void inorm_apply(const u16* __restrict__ X, const float2* __restrict__ ist,
                 u16* __restrict__ out) {
  const size_t i = ((size_t)blockIdx.x * 256 + threadIdx.x) * 8;
  const int b = (int)(i >> 20);
  const int c = (int)(i & 1023);
  u16x8 x = *(const u16x8*)(X + i);
  u16x8 o;
#pragma unroll
  for (int j = 0; j < 8; ++j) {
    float2 s = ist[b * 1024 + c + j];
    o[j] = f2bf((bf2f(x[j]) - s.x) * s.y);
  }
  *(u16x8*)(out + i) = o;
}

// ---------------- small f32 GEMM: out[m,n] = A[m,:]·W[n,:] + bias[n] ---------
__global__ __launch_bounds__(256)
void small_gemm(const float* __restrict__ A, const float* __restrict__ W,
                const float* __restrict__ bias, float* __restrict__ out,
                int N, int K) {
  __shared__ float sA[1024];
  const int m = blockIdx.y;
  const int n = blockIdx.x * 256 + threadIdx.x;
  for (int i = threadIdx.x; i < K; i += 256) sA[i] = A[(size_t)m * K + i];
  __syncthreads();
  const float4* w4 = (const float4*)(W + (size_t)n * K);
  const float4* a4 = (const float4*)sA;
  float acc = bias ? bias[n] : 0.0f;
  for (int k = 0; k < K / 4; ++k) {
    float4 wv = w4[k], av = a4[k];
    acc += av.x * wv.x + av.y * wv.y + av.z * wv.z + av.w * wv.w;
  }
  out[(size_t)m * N + n] = acc;
}

// ---------------- memory-fuse attention (per batch) --------------------------
__global__ __launch_bounds__(256)
void mem_attn(const float* __restrict__ qmf, const u16* __restrict__ KM,
              const u16* __restrict__ VM, const float* __restrict__ mask,
              float* __restrict__ att_out, float* __restrict__ attv_out) {
  __shared__ float qs[1024];
  __shared__ float sS[512];
  __shared__ float sP[512];
  __shared__ float sM[64];
  const int b = blockIdx.x;
  const int tid = threadIdx.x;
  for (int i = tid; i < 1024; i += 256) qs[i] = qmf[i];
  if (tid < 64) sM[tid] = mask[b * 64 + tid];
  __syncthreads();
  for (int p = tid; p < 512; p += 256) {
    const int h = p >> 6, j = p & 63;
    const u16* kr = KM + (size_t)(b * 64 + j) * 1024 + h * 128;
    float acc = 0.f;
    for (int d = 0; d < 128; ++d) acc += qs[h * 128 + d] * bf2f(kr[d]);
    sS[p] = acc * sM[j] * SCALE;
  }
  __syncthreads();
  if (tid < 8) {
    const int h = tid;
    float mx = -3.4e38f;
    for (int j = 0; j < 64; ++j) mx = fmaxf(mx, sS[h * 64 + j]);
    float sum = 0.f;
    for (int j = 0; j < 64; ++j) {
      float e = expf(sS[h * 64 + j] - mx);
      sP[h * 64 + j] = e; sum += e;
    }
    const float inv = 1.0f / sum;
    for (int j = 0; j < 64; ++j) {
      float pp = sP[h * 64 + j] * inv;
      sP[h * 64 + j] = pp;
      att_out[(size_t)(b * 8 + h) * 64 + j] = pp;
    }
  }
  __syncthreads();
  for (int c = tid; c < 1024; c += 256) {
    const int h = c >> 7;
    float acc = 0.f;
    for (int j = 0; j < 64; ++j)
      acc += sP[h * 64 + j] * sM[j] * bf2f(VM[(size_t)(b * 64 + j) * 1024 + c]);
    attv_out[(size_t)b * 1024 + c] = acc;
  }
}

// ---------------- cur = inorm(concat(neg_tok, mem_out)) ----------------------
__global__ __launch_bounds__(256)
void make_cur(const float* __restrict__ neg, const float* __restrict__ memo,
              float* __restrict__ cur_out, float* __restrict__ curw) {
  const int i = blockIdx.x * 256 + threadIdx.x;   // 32768
  const int b = i >> 10, c = i & 1023;
  const float a = neg[c], x = memo[i];
  const float mean = 0.5f * (a + x);
  const float d = a - mean;
  const float rs = rsqrtf(d * d + EPS);
  const float o0 = d * rs, o1 = -d * rs;
  cur_out[(size_t)(b * 2) * 1024 + c] = o0;
  cur_out[(size_t)(b * 2 + 1) * 1024 + c] = o1;
  curw[(size_t)(b * 2) * 1024 + c] = o0;
  curw[(size_t)(b * 2 + 1) * 1024 + c] = o1;
}

// ---------------- ff attention: 2 keys, wave per row -------------------------
__global__ __launch_bounds__(256)
void ff_attn(const u16* __restrict__ Q, const float* __restrict__ kf,
             const float* __restrict__ vf, float* __restrict__ att_out,
             u16* __restrict__ AV) {
  const int w = threadIdx.x >> 6, l = threadIdx.x & 63;
  const int r = blockIdx.x * 4 + w;
  const int b = r >> 10, t = r & 1023;
  const int h = l >> 3;
  const uint4* qrow = (const uint4*)(Q + (size_t)r * 1024);
  uint4 qa = qrow[2 * l], qb = qrow[2 * l + 1];
  u32 qu[8] = {qa.x, qa.y, qa.z, qa.w, qb.x, qb.y, qb.z, qb.w};
  float qv[16];
#pragma unroll
  for (int i = 0; i < 8; ++i) {
    qv[2 * i] = bf2f((u16)(qu[i] & 0xffffu));
    qv[2 * i + 1] = bf2f((u16)(qu[i] >> 16));
  }
  const float* k0 = kf + (size_t)b * 2048 + l * 16;
  const float* k1 = k0 + 1024;
  float s0 = 0.f, s1 = 0.f;
#pragma unroll
  for (int i = 0; i < 16; ++i) { s0 += qv[i] * k0[i]; s1 += qv[i] * k1[i]; }
#pragma unroll
  for (int o = 1; o < 8; o <<= 1) {
    s0 += __shfl_xor(s0, o, 64);
    s1 += __shfl_xor(s1, o, 64);
  }
  s0 *= SCALE; s1 *= SCALE;
  const float m = fmaxf(s0, s1);
  const float e0 = expf(s0 - m), e1 = expf(s1 - m);
  const float inv = 1.0f / (e0 + e1);
  const float p0 = e0 * inv, p1 = e1 * inv;
  if ((l & 7) == 0) {
    float* o = att_out + ((size_t)(b * 8 + h) * 1024 + t) * 2;
    o[0] = p0; o[1] = p1;
  }
  const float* v0 = vf + (size_t)b * 2048 + l * 16;
  const float* v1 = v0 + 1024;
  u32 packed[8];
#pragma unroll
  for (int i = 0; i < 8; ++i) {
    u16 lo = f2bf(p0 * v0[2 * i] + p1 * v1[2 * i]);
    u16 hi = f2bf(p0 * v0[2 * i + 1] + p1 * v1[2 * i + 1]);
    packed[i] = (u32)lo | ((u32)hi << 16);
  }
  uint4* dst = (uint4*)(AV + (size_t)r * 1024 + l * 16);
  dst[0] = make_uint4(packed[0], packed[1], packed[2], packed[3]);
  dst[1] = make_uint4(packed[4], packed[5], packed[6], packed[7]);
}

// =============================================================================
extern "C" void kernel_launch(void* const* d_in, const int* in_sizes, int n_in,
                              void* d_out, int out_size, void* d_ws, size_t ws_size,
                              hipStream_t stream) {
  (void)in_sizes; (void)n_in; (void)out_size; (void)ws_size;

  const float* src      = (const float*)d_in[0];
  const float* lan      = (const float*)d_in[1];
  /* d_in[2] pos_embed: unused by reference */
  const float* qmask    = (const float*)d_in[3];
  const float* ip_w     = (const float*)d_in[4];
  /* ip_b (d_in[5]) cancels under BN */
  const float* ip_g     = (const float*)d_in[6];
  const float* ip_beta  = (const float*)d_in[7];
  const float* lp_w     = (const float*)d_in[8];
  const float* lp_b     = (const float*)d_in[9];
  const float* mem_tok  = (const float*)d_in[10];
  const float* neg_tok  = (const float*)d_in[11];
  const float* vl_qw    = (const float*)d_in[12];
  const float* vl_qb    = (const float*)d_in[13];
  const float* vl_kw    = (const float*)d_in[14];
  const float* vl_kb    = (const float*)d_in[15];
  /* vl_vw/vl_vb/vl_ow/vl_ob (16..19): dead — vl_out unused downstream */
  const float* mf_qw    = (const float*)d_in[20];
  const float* mf_qb    = (const float*)d_in[21];
  const float* mf_kw    = (const float*)d_in[22];
  const float* mf_kb    = (const float*)d_in[23];
  const float* mf_vw    = (const float*)d_in[24];
  const float* mf_vb    = (const float*)d_in[25];
  const float* mf_ow    = (const float*)d_in[26];
  const float* mf_ob    = (const float*)d_in[27];
  const float* ff_qw    = (const float*)d_in[28];
  const float* ff_qb    = (const float*)d_in[29];
  const float* ff_kw    = (const float*)d_in[30];
  const float* ff_kb    = (const float*)d_in[31];
  const float* ff_vw    = (const float*)d_in[32];
  const float* ff_vb    = (const float*)d_in[33];
  const float* ff_ow    = (const float*)d_in[34];
  const float* ff_ob    = (const float*)d_in[35];
  const float* op_w     = (const float*)d_in[36];
  /* op_b (37) cancels under BN */
  const float* op_g     = (const float*)d_in[38];
  const float* op_beta  = (const float*)d_in[39];

  float* out_final = (float*)d_out;
  float* out_cur   = out_final + 33554432ull;
  float* out_vl    = out_cur + 65536ull;
  float* out_mem   = out_vl + 16777216ull;
  float* out_ff    = out_mem + 16384ull;

  // ---- workspace carve (all-bf16 intermediates) ----
  char* wp = (char*)d_ws;
  auto take = [&](size_t sz) { char* r = wp; wp += (sz + 255) & ~(size_t)255; return r; };
  u16*   W1   = (u16*)  take(67108864);    // src_p -> ff_out -> (dead)
  u16*   W2   = (u16*)  take(67108864);    // Y1 -> vl_k -> ff_q -> ff_n
  u16*   SB   = (u16*)  take(67108864);    // src bf16 -> AV -> Z
  u16*   LP   = (u16*)  take(4194304);     // lan_p bf16 [2048,1024]
  u16*   QV   = (u16*)  take(4194304);     // vl q bf16 [2048,1024]
  u16*   KM   = (u16*)  take(4194304);     // mf k bf16
  u16*   VM   = (u16*)  take(4194304);     // mf v bf16
  u16*   LANB = (u16*)  take(3145728);     // lan bf16 [2048,768]
  u16*   wip  = (u16*)  take(2097152);
  u16*   wlp  = (u16*)  take(1572864);
  u16*   wvq  = (u16*)  take(2097152);
  u16*   wvk  = (u16*)  take(2097152);
  u16*   wmk  = (u16*)  take(2097152);
  u16*   wmv  = (u16*)  take(2097152);
  u16*   wfq  = (u16*)  take(2097152);
  u16*   wfo  = (u16*)  take(2097152);
  u16*   wop  = (u16*)  take(2097152);
  float* qmf   = (float*)take(4096);
  float* attvm = (float*)take(131072);
  float* memo  = (float*)take(131072);
  float* curw  = (float*)take(262144);
  float* kff   = (float*)take(262144);
  float* vff   = (float*)take(262144);
  float* ps    = (float*)take(2097152);    // [512][1024] f32 partials
  float* pq    = (float*)take(2097152);
  float2* st1  = (float2*)take(8192);
  float2* st2  = (float2*)take(8192);
  float2* ist  = (float2*)take(262144);

  const dim3 blk(256);
  const dim3 blk8(512);
  const dim3 grid8(4, 128);   // (N/256, M/256) for M=32768, N=1024

  // conversions: src (big, own launch) + 10 segments in one launch
  f2b_kernel<<<dim3(32768), blk, 0, stream>>>(src, SB, 8388608);
  {
    F2B10 j;
    const float* ins[10] = {lan, ip_w, lp_w, vl_qw, vl_kw, mf_kw, mf_vw, ff_qw, ff_ow, op_w};
    u16* outs[10] = {LANB, wip, wlp, wvq, wvk, wmk, wmv, wfq, wfo, wop};
    int n4s[10] = {393216, 262144, 196608, 262144, 262144, 262144, 262144, 262144, 262144, 262144};
    for (int i = 0; i < 10; ++i) { j.in[i] = ins[i]; j.out[i] = outs[i]; j.n4[i] = n4s[i]; }
    f2b_multi<<<dim3(1024, 10), blk, 0, stream>>>(j);
  }

  // stage 0: input proj -> Y1 (bf16, W2); BN -> src_p (bf16, W1)
  gemm_bt8<<<grid8, blk8, 0, stream>>>(SB, wip, nullptr, W2, 32768, 1024, 1024);
  colstats_partial_b<<<dim3(256), blk, 0, stream>>>(W2, ps, pq);
  colstats_final<<<dim3(32), blk, 0, stream>>>(ps, pq, st1, 1.0f / 32768.0f);
  bn_apply_bf16<<<dim3(16384), blk, 0, stream>>>(W2, st1, ip_g, ip_beta, W1);

  // lan proj
  gemm_bt<<<dim3(8, 16), blk, 0, stream>>>(LANB, wlp, lp_b, LP, 2048, 1024, 768);

  // stage 1 (vl): only vl_att is live downstream
  gemm_bt<<<dim3(8, 16), blk, 0, stream>>>(LP, wvq, vl_qb, QV, 2048, 1024, 1024);
  gemm_bt8<<<grid8, blk8, 0, stream>>>(W1, wvk, vl_kb, W2, 32768, 1024, 1024);
  score_gemm<<<dim3(8, 1, 256), blk, 0, stream>>>(QV, W2, out_vl);
  vl_softmax<<<dim3(16384), blk, 0, stream>>>(out_vl, qmask);

  // stage 2 (memory fuse)
  small_gemm<<<dim3(4, 1), blk, 0, stream>>>(mem_tok, mf_qw, mf_qb, qmf, 1024, 1024);
  gemm_bt<<<dim3(8, 16), blk, 0, stream>>>(LP, wmk, mf_kb, KM, 2048, 1024, 1024);
  gemm_bt<<<dim3(8, 16), blk, 0, stream>>>(LP, wmv, mf_vb, VM, 2048, 1024, 1024);
  mem_attn<<<dim3(32), blk, 0, stream>>>(qmf, KM, VM, qmask, out_mem, attvm);
  small_gemm<<<dim3(4, 32), blk, 0, stream>>>(attvm, mf_ow, mf_ob, memo, 1024, 1024);
  make_cur<<<dim3(128), blk, 0, stream>>>(neg_tok, memo, out_cur, curw);

  // stage 3 (feature fuse)
  small_gemm<<<dim3(4, 64), blk, 0, stream>>>(curw, ff_kw, ff_kb, kff, 1024, 1024);
  small_gemm<<<dim3(4, 64), blk, 0, stream>>>(curw, ff_vw, ff_vb, vff, 1024, 1024);
  gemm_bt8<<<grid8, blk8, 0, stream>>>(W1, wfq, ff_qb, W2, 32768, 1024, 1024);
  ff_attn<<<dim3(8192), blk, 0, stream>>>(W2, kff, vff, out_ff, SB);
  gemm_bt8<<<grid8, blk8, 0, stream>>>(SB, wfo, ff_ob, W1, 32768, 1024, 1024);
  instats_partial_b<<<dim3(8, 32), blk, 0, stream>>>(W1, ps, pq);
  instats_final<<<dim3(32), blk, 0, stream>>>(ps, pq, ist);
  inorm_apply<<<dim3(16384), blk, 0, stream>>>(W1, ist, W2);
  gemm_bt8<<<grid8, blk8, 0, stream>>>(W2, wop, nullptr, SB, 32768, 1024, 1024);
  colstats_partial_b<<<dim3(256), blk, 0, stream>>>(SB, ps, pq);
  colstats_final<<<dim3(32), blk, 0, stream>>>(ps, pq, st2, 1.0f / 32768.0f);
  bn_apply_f32<<<dim3(16384), blk, 0, stream>>>(SB, st2, op_g, op_beta, out_final);
}

// Round 6
// 889.618 us; speedup vs baseline: 1.1909x; 1.1909x over previous
//
#include <hip/hip_runtime.h>
#include <stdint.h>

#define EPS 1e-5f
#define SCALE 0.08838834764831845f  /* 1/sqrt(128) */

typedef __bf16 bf16x8 __attribute__((ext_vector_type(8)));
typedef float f32x4 __attribute__((ext_vector_type(4)));
typedef unsigned short u16;
typedef unsigned int u32;
typedef u16 u16x8 __attribute__((ext_vector_type(8)));

__device__ __forceinline__ u16 f2bf(float f) {
  union { float f; u32 u; } x; x.f = f;
  u32 r = x.u + 0x7fffu + ((x.u >> 16) & 1u);
  return (u16)(r >> 16);
}
__device__ __forceinline__ float bf2f(u16 u) {
  union { u32 u; float f; } x; x.u = ((u32)u) << 16; return x.f;
}
__device__ __forceinline__ void glds16(const void* g, void* l) {
  __builtin_amdgcn_global_load_lds((__attribute__((address_space(1))) void*)g,
                                   (__attribute__((address_space(3))) void*)l,
                                   16, 0, 0);
}

// ---------------- f32 -> bf16 convert (single big tensor) --------------------
__global__ __launch_bounds__(256) void f2b_kernel(const float* __restrict__ in,
                                                  u16* __restrict__ out, int n4) {
  int i = blockIdx.x * 256 + threadIdx.x;
  if (i >= n4) return;
  float4 v = ((const float4*)in)[i];
  ((ushort4*)out)[i] = make_ushort4(f2bf(v.x), f2bf(v.y), f2bf(v.z), f2bf(v.w));
}

// ---------------- f32 -> bf16 convert, 8 segments in one launch --------------
struct F2B8 {
  const float* in[8];
  u16* out[8];
  int n4[8];
};
__global__ __launch_bounds__(256) void f2b_multi(F2B8 j) {
  const int seg = blockIdx.y;
  const int n4 = j.n4[seg];
  const float* __restrict__ in = j.in[seg];
  u16* __restrict__ out = j.out[seg];
  for (int i = blockIdx.x * 256 + threadIdx.x; i < n4; i += gridDim.x * 256) {
    float4 v = ((const float4*)in)[i];
    ((ushort4*)out)[i] = make_ushort4(f2bf(v.x), f2bf(v.y), f2bf(v.z), f2bf(v.w));
  }
}

// ---------------- transpose weight: WT[m,n] = W[n,m], f32 -> bf16 ------------
__global__ __launch_bounds__(256)
void wtrans(const float* __restrict__ W, u16* __restrict__ WT) {
  __shared__ float tile[64][65];
  const int bx = blockIdx.x, by = blockIdx.y;   // 16 x 16 blocks of 64x64
  const int r = threadIdx.x >> 2, c0 = (threadIdx.x & 3) * 16;
  const float* src = W + (size_t)(by * 64 + r) * 1024 + bx * 64 + c0;
#pragma unroll
  for (int e = 0; e < 16; e += 4) {
    float4 v = *(const float4*)(src + e);
    tile[r][c0 + e] = v.x; tile[r][c0 + e + 1] = v.y;
    tile[r][c0 + e + 2] = v.z; tile[r][c0 + e + 3] = v.w;
  }
  __syncthreads();
  u16* dst = WT + (size_t)(bx * 64 + r) * 1024 + by * 64 + c0;
#pragma unroll
  for (int e = 0; e < 16; e += 4) {
    ushort4 o = make_ushort4(f2bf(tile[c0 + e][r]), f2bf(tile[c0 + e + 1][r]),
                             f2bf(tile[c0 + e + 2][r]), f2bf(tile[c0 + e + 3][r]));
    *(ushort4*)(dst + e) = o;
  }
}

// ---------------- 128x128 bf16 GEMM (BK=64, T1+T2): C=A@B^T (+bias) ----------
__global__ __launch_bounds__(256)
void gemm_bt(const u16* __restrict__ A, const u16* __restrict__ B,
             const float* __restrict__ bias, u16* __restrict__ Cb,
             int M, int N, int K) {
  __shared__ u16 sA[128 * 64];
  __shared__ u16 sB[128 * 64];
  const int nwg = (int)(gridDim.x * gridDim.y);
  const int chunk = nwg >> 3;
  int s = blockIdx.y * gridDim.x + blockIdx.x;
  int t = (s & 7) * chunk + (s >> 3);
  const int bn0 = (t & 7) * 128;
  const int bm0 = (t >> 3) * 128;
  const int tid = threadIdx.x;
  const int w = tid >> 6, l = tid & 63;
  const int wr = w >> 1, wc = w & 1;
  const int lr = l & 15, lk = l >> 4;
  const int swz = lr & 7;

  const int srow = tid >> 3;
  const int scol = ((tid & 7) ^ (srow & 7)) << 3;
  const u16* Ab = A + (size_t)(bm0 + srow) * K + scol;
  const u16* Bb = B + (size_t)(bn0 + srow) * K + scol;
  const size_t rstride32 = (size_t)32 * K;

  f32x4 acc[4][4] = {};

  for (int k0 = 0; k0 < K; k0 += 64) {
#pragma unroll
    for (int p = 0; p < 4; ++p) {
      glds16(Ab + p * rstride32 + k0, sA + p * 2048 + w * 512);
      glds16(Bb + p * rstride32 + k0, sB + p * 2048 + w * 512);
    }
    __syncthreads();
#pragma unroll
    for (int ks = 0; ks < 2; ++ks) {
      const int off = (((ks << 2) + lk) ^ swz) << 3;
      bf16x8 af[4], bfr[4];
#pragma unroll
      for (int m = 0; m < 4; ++m)
        af[m] = *(const bf16x8*)(sA + (wr * 64 + m * 16 + lr) * 64 + off);
#pragma unroll
      for (int n = 0; n < 4; ++n)
        bfr[n] = *(const bf16x8*)(sB + (wc * 64 + n * 16 + lr) * 64 + off);
#pragma unroll
      for (int m = 0; m < 4; ++m)
#pragma unroll
        for (int n = 0; n < 4; ++n)
          acc[m][n] = __builtin_amdgcn_mfma_f32_16x16x32_bf16(af[m], bfr[n], acc[m][n], 0, 0, 0);
    }
    __syncthreads();
  }

#pragma unroll
  for (int m = 0; m < 4; ++m) {
    const int grow0 = bm0 + wr * 64 + m * 16 + lk * 4;
#pragma unroll
    for (int n = 0; n < 4; ++n) {
      const int gcol = bn0 + wc * 64 + n * 16 + lr;
      const float bv = bias ? bias[gcol] : 0.0f;
#pragma unroll
      for (int i = 0; i < 4; ++i) {
        const float v = acc[m][n][i] + bv;
        Cb[(size_t)(grow0 + i) * N + gcol] = f2bf(v);
      }
    }
  }
}

// ---------------- q'' GEMM: Q2[b*512+h*64+i, m] = (QV[:,hs]@WT[:,hs]^T)*a[m] -
// A=QV (lda 1024, K=128 slice at h*128); B=wvkT (ldb 1024, slice h*128).
// grid (8, 16, 8 heads), 256 threads.
__global__ __launch_bounds__(256)
void gemm_qpp(const u16* __restrict__ QV, const u16* __restrict__ WT,
              const float* __restrict__ afv, u16* __restrict__ Q2) {
  __shared__ u16 sA[128 * 64];
  __shared__ u16 sB[128 * 64];
  const int h = blockIdx.z;
  int s = blockIdx.y * 8 + blockIdx.x;
  int t = (s & 7) * 16 + (s >> 3);
  const int bn0 = (t & 7) * 128;
  const int bm0 = (t >> 3) * 128;
  const int tid = threadIdx.x;
  const int w = tid >> 6, l = tid & 63;
  const int wr = w >> 1, wc = w & 1;
  const int lr = l & 15, lk = l >> 4;
  const int swz = lr & 7;

  const int srow = tid >> 3;
  const int scol = ((tid & 7) ^ (srow & 7)) << 3;
  const u16* Ab = QV + (size_t)(bm0 + srow) * 1024 + h * 128 + scol;
  const u16* Bb = WT + (size_t)(bn0 + srow) * 1024 + h * 128 + scol;
  const size_t rstride32 = (size_t)32 * 1024;

  f32x4 acc[4][4] = {};

  for (int k0 = 0; k0 < 128; k0 += 64) {
#pragma unroll
    for (int p = 0; p < 4; ++p) {
      glds16(Ab + p * rstride32 + k0, sA + p * 2048 + w * 512);
      glds16(Bb + p * rstride32 + k0, sB + p * 2048 + w * 512);
    }
    __syncthreads();
#pragma unroll
    for (int ks = 0; ks < 2; ++ks) {
      const int off = (((ks << 2) + lk) ^ swz) << 3;
      bf16x8 af[4], bfr[4];
#pragma unroll
      for (int m = 0; m < 4; ++m)
        af[m] = *(const bf16x8*)(sA + (wr * 64 + m * 16 + lr) * 64 + off);
#pragma unroll
      for (int n = 0; n < 4; ++n)
        bfr[n] = *(const bf16x8*)(sB + (wc * 64 + n * 16 + lr) * 64 + off);
#pragma unroll
      for (int m = 0; m < 4; ++m)
#pragma unroll
        for (int n = 0; n < 4; ++n)
          acc[m][n] = __builtin_amdgcn_mfma_f32_16x16x32_bf16(af[m], bfr[n], acc[m][n], 0, 0, 0);
    }
    __syncthreads();
  }

#pragma unroll
  for (int m = 0; m < 4; ++m) {
    const int grow0 = bm0 + wr * 64 + m * 16 + lk * 4;
#pragma unroll
    for (int n = 0; n < 4; ++n) {
      const int gcol = bn0 + wc * 64 + n * 16 + lr;
      const float a = afv[gcol];
#pragma unroll
      for (int i = 0; i < 4; ++i) {
        const int gr = grow0 + i;
        const int q2row = ((gr >> 6) << 9) + h * 64 + (gr & 63);
        Q2[(size_t)q2row * 1024 + gcol] = f2bf(acc[m][n][i] * a);
      }
    }
  }
}

// ---------------- batched vl-score GEMM: per b: S[512,1024] = Q2[b]@Y1[b]^T --
// f32 out to out_vl. grid (8, 4, 32), 256 threads.
__global__ __launch_bounds__(256)
void gemm_score_b(const u16* __restrict__ Q2, const u16* __restrict__ Y1,
                  float* __restrict__ out) {
  __shared__ u16 sA[128 * 64];
  __shared__ u16 sB[128 * 64];
  int s = (int)((blockIdx.z * gridDim.y + blockIdx.y) * gridDim.x + blockIdx.x);
  int t = (s & 7) * 128 + (s >> 3);
  const int b = t >> 5;
  const int rem = t & 31;
  const int bn0 = (rem & 7) * 128;
  const int bm0 = (rem >> 3) * 128;
  const int tid = threadIdx.x;
  const int w = tid >> 6, l = tid & 63;
  const int wr = w >> 1, wc = w & 1;
  const int lr = l & 15, lk = l >> 4;
  const int swz = lr & 7;

  const int srow = tid >> 3;
  const int scol = ((tid & 7) ^ (srow & 7)) << 3;
  const u16* Ab = Q2 + (size_t)b * 524288 + (size_t)(bm0 + srow) * 1024 + scol;
  const u16* Bb = Y1 + (size_t)b * 1048576 + (size_t)(bn0 + srow) * 1024 + scol;
  const size_t rstride32 = (size_t)32 * 1024;

  f32x4 acc[4][4] = {};

  for (int k0 = 0; k0 < 1024; k0 += 64) {
#pragma unroll
    for (int p = 0; p < 4; ++p) {
      glds16(Ab + p * rstride32 + k0, sA + p * 2048 + w * 512);
      glds16(Bb + p * rstride32 + k0, sB + p * 2048 + w * 512);
    }
    __syncthreads();
#pragma unroll
    for (int ks = 0; ks < 2; ++ks) {
      const int off = (((ks << 2) + lk) ^ swz) << 3;
      bf16x8 af[4], bfr[4];
#pragma unroll
      for (int m = 0; m < 4; ++m)
        af[m] = *(const bf16x8*)(sA + (wr * 64 + m * 16 + lr) * 64 + off);
#pragma unroll
      for (int n = 0; n < 4; ++n)
        bfr[n] = *(const bf16x8*)(sB + (wc * 64 + n * 16 + lr) * 64 + off);
#pragma unroll
      for (int m = 0; m < 4; ++m)
#pragma unroll
        for (int n = 0; n < 4; ++n)
          acc[m][n] = __builtin_amdgcn_mfma_f32_16x16x32_bf16(af[m], bfr[n], acc[m][n], 0, 0, 0);
    }
    __syncthreads();
  }

  float* C = out + (size_t)b * 524288;
#pragma unroll
  for (int m = 0; m < 4; ++m) {
    const int grow0 = bm0 + wr * 64 + m * 16 + lk * 4;
#pragma unroll
    for (int n = 0; n < 4; ++n) {
      const int gcol = bn0 + wc * 64 + n * 16 + lr;
#pragma unroll
      for (int i = 0; i < 4; ++i)
        C[(size_t)(grow0 + i) * 1024 + gcol] = acc[m][n][i];
    }
  }
}

// ---------------- vl softmax (+folded const from QV·wc, query-mask scale) ----
__global__ __launch_bounds__(256)
void vl_softmax(float* __restrict__ S, const float* __restrict__ qmask,
                const u16* __restrict__ QV, const float* __restrict__ wcv) {
  __shared__ float red[4];
  __shared__ float red2[4];
  const int row = blockIdx.x;          // (b*8+h)*64+i
  const int b = row >> 9;
  const int h = (row >> 6) & 7;
  const int i = row & 63;
  const int t = threadIdx.x;
  // const term: sum_{n in head} QV[b*64+i, h*128+n] * wcv[h*128+n]
  float cp = 0.f;
  if (t < 128) cp = bf2f(QV[(size_t)(b * 64 + i) * 1024 + h * 128 + t]) * wcv[h * 128 + t];
  for (int o = 32; o > 0; o >>= 1) cp += __shfl_xor(cp, o, 64);
  if ((t & 63) == 0) red2[t >> 6] = cp;
  __syncthreads();
  const float cst = red2[0] + red2[1];
  const float scale = qmask[b * 64 + i] * SCALE;
  float* p = S + (size_t)row * 1024;
  float4 v = ((const float4*)p)[t];
  v.x = (v.x + cst) * scale; v.y = (v.y + cst) * scale;
  v.z = (v.z + cst) * scale; v.w = (v.w + cst) * scale;
  float mx = fmaxf(fmaxf(v.x, v.y), fmaxf(v.z, v.w));
  for (int o = 32; o > 0; o >>= 1) mx = fmaxf(mx, __shfl_xor(mx, o, 64));
  __syncthreads();
  if ((t & 63) == 0) red[t >> 6] = mx;
  __syncthreads();
  mx = fmaxf(fmaxf(red[0], red[1]), fmaxf(red[2], red[3]));
  const float e0 = expf(v.x - mx), e1 = expf(v.y - mx);
  const float e2 = expf(v.z - mx), e3 = expf(v.w - mx);
  float sm = e0 + e1 + e2 + e3;
  for (int o = 32; o > 0; o >>= 1) sm += __shfl_xor(sm, o, 64);
  __syncthreads();
  if ((t & 63) == 0) red[t >> 6] = sm;
  __syncthreads();
  sm = red[0] + red[1] + red[2] + red[3];
  const float inv = 1.0f / sm;
  ((float4*)p)[t] = make_float4(e0 * inv, e1 * inv, e2 * inv, e3 * inv);
}

// ---------------- column stats over bf16 [32768,1024] ------------------------
__global__ __launch_bounds__(256)
void colstats_partial_b(const u16* __restrict__ X, float* __restrict__ ps,
                        float* __restrict__ pq) {
  const int tid = threadIdx.x;
  const int chunk = blockIdx.x;
  const int colb = (tid & 127) * 8;
  const int rg = tid >> 7;
  const u16* p = X + ((size_t)chunk * 128 + rg * 64) * 1024 + colb;
  float s[8] = {}, q[8] = {};
  for (int r = 0; r < 64; ++r) {
    u16x8 v = *(const u16x8*)(p + (size_t)r * 1024);
#pragma unroll
    for (int j = 0; j < 8; ++j) {
      float f = bf2f(v[j]);
      s[j] += f; q[j] += f * f;
    }
  }
  float* dps = ps + (size_t)(chunk * 2 + rg) * 1024 + colb;
  float* dpq = pq + (size_t)(chunk * 2 + rg) * 1024 + colb;
  *(float4*)(dps) = make_float4(s[0], s[1], s[2], s[3]);
  *(float4*)(dps + 4) = make_float4(s[4], s[5], s[6], s[7]);
  *(float4*)(dpq) = make_float4(q[0], q[1], q[2], q[3]);
  *(float4*)(dpq + 4) = make_float4(q[4], q[5], q[6], q[7]);
}
// reduce 512 chunks -> stats (+ optional BN-fold vectors a, c)
__global__ __launch_bounds__(256)
void colstats_final(const float* __restrict__ ps, const float* __restrict__ pq,
                    float2* __restrict__ st, const float* __restrict__ g,
                    const float* __restrict__ be, float* __restrict__ afv,
                    float* __restrict__ cfv, float inv_n) {
  __shared__ float rs_[8][32], rq_[8][32];
  const int cg = threadIdx.x >> 5, cl = threadIdx.x & 31;
  const int col = blockIdx.x * 32 + cl;
  float s = 0.f, q = 0.f;
  for (int i = 0; i < 64; ++i) {
    const size_t idx = (size_t)(cg * 64 + i) * 1024 + col;
    s += ps[idx]; q += pq[idx];
  }
  rs_[cg][cl] = s; rq_[cg][cl] = q;
  __syncthreads();
  if (cg == 0) {
    for (int i = 1; i < 8; ++i) { s += rs_[i][cl]; q += rq_[i][cl]; }
    const float m = s * inv_n;
    const float v = q * inv_n - m * m;
    const float rs = rsqrtf(v + EPS);
    st[col] = make_float2(m, rs);
    if (afv) {
      const float a = rs * g[col];
      afv[col] = a;
      cfv[col] = be[col] - m * a;
    }
  }
}

// ---------------- BN apply f32-out (final output) ----------------------------
__global__ __launch_bounds__(256)
void bn_apply_f32(const u16* __restrict__ X, const float2* __restrict__ st,
                  const float* __restrict__ g, const float* __restrict__ be,
                  float* __restrict__ out) {
  const size_t i = ((size_t)blockIdx.x * 256 + threadIdx.x) * 8;
  const int c = (int)(i & 1023);
  u16x8 x = *(const u16x8*)(X + i);
  float o[8];
#pragma unroll
  for (int j = 0; j < 8; ++j) {
    float2 s = st[c + j];
    o[j] = (bf2f(x[j]) - s.x) * s.y * g[c + j] + be[c + j];
  }
  *(float4*)(out + i) = make_float4(o[0], o[1], o[2], o[3]);
  *(float4*)(out + i + 4) = make_float4(o[4], o[5], o[6], o[7]);
}

// ---------------- instance-norm stats (bf16 in) ------------------------------
__global__ __launch_bounds__(256)
void instats_partial_b(const u16* __restrict__ X, float* __restrict__ ps,
                       float* __restrict__ pq) {
  const int chunk = blockIdx.x, b = blockIdx.y;
  const int tid = threadIdx.x;
  const int colb = (tid & 127) * 8;
  const int rg = tid >> 7;
  const u16* p = X + (size_t)b * 1048576 + ((size_t)chunk * 128 + rg * 64) * 1024 + colb;
  float s[8] = {}, q[8] = {};
  for (int r = 0; r < 64; ++r) {
    u16x8 v = *(const u16x8*)(p + (size_t)r * 1024);
#pragma unroll
    for (int j = 0; j < 8; ++j) {
      float f = bf2f(v[j]);
      s[j] += f; q[j] += f * f;
    }
  }
  const size_t o = (size_t)(b * 16 + chunk * 2 + rg) * 1024 + colb;
  *(float4*)(ps + o) = make_float4(s[0], s[1], s[2], s[3]);
  *(float4*)(ps + o + 4) = make_float4(s[4], s[5], s[6], s[7]);
  *(float4*)(pq + o) = make_float4(q[0], q[1], q[2], q[3]);
  *(float4*)(pq + o + 4) = make_float4(q[4], q[5], q[6], q[7]);
}
__global__ __launch_bounds__(256)
void instats_final(const float* __restrict__ ps, const float* __restrict__ pq,
                   float2* __restrict__ ist) {
  const int b = blockIdx.x, tid = threadIdx.x;
  float4 s = make_float4(0, 0, 0, 0), q = make_float4(0, 0, 0, 0);
#pragma unroll
  for (int i = 0; i < 16; ++i) {
    const size_t o = (size_t)(b * 16 + i) * 1024;
    float4 vs = ((const float4*)(ps + o))[tid];
    float4 vq = ((const float4*)(pq + o))[tid];
    s.x += vs.x; s.y += vs.y; s.z += vs.z; s.w += vs.w;
    q.x += vq.x; q.y += vq.y; q.z += vq.z; q.w += vq.w;
  }
  const float sv[4] = {s.x, s.y, s.z, s.w};
  const float qv[4] = {q.x, q.y, q.z, q.w};
#pragma unroll
  for (int j = 0; j < 4; ++j) {
    const float m = sv[j] * (1.0f / 1024.0f);
    const float var = qv[j] * (1.0f / 1024.0f) - m * m;
    ist[b * 1024 + tid * 4 + j] = make_float2(m, rsqrtf(var + EPS));
  }
}
__global__ __launch_bounds__(256)
void inorm_apply(const u16* __restrict__ X, const float2* __restrict__ ist,
                 u16* __restrict__ out) {
  const size_t i = ((size_t)blockIdx.x * 256 + threadIdx.x) * 8;
  const int b = (int)(i >> 20);
  const int c = (int)(i & 1023);
  u16x8 x = *(const u16x8*)(X + i);
  u16x8 o;
#pragma unroll
  for (int j = 0; j < 8; ++j) {
    float2 s = ist[b * 1024 + c + j];
    o[j] = f2bf((bf2f(x[j]) - s.x) * s.y);
  }
  *(u16x8*)(out + i) = o;
}

// ---------------- small f32 GEMM: out[m,n] = A[m,:]·W[n,:] + bias[n] ---------
__global__ __launch_bounds__(256)
void small_gemm(const float* __restrict__ A, const float* __restrict__ W,
                const float* __restrict__ bias, float* __restrict__ out,
                int N, int K) {
  __shared__ float sA[1024];
  const int m = blockIdx.y;
  const int n = blockIdx.x * 256 + threadIdx.x;
  for (int i = threadIdx.x; i < K; i += 256) sA[i] = A[(size_t)m * K + i];
  __syncthreads();
  const float4* w4 = (const float4*)(W + (size_t)n * K);
  const float4* a4 = (const float4*)sA;
  float acc = bias ? bias[n] : 0.0f;
  for (int k = 0; k < K / 4; ++k) {
    float4 wv = w4[k], av = a4[k];
    acc += av.x * wv.x + av.y * wv.y + av.z * wv.z + av.w * wv.w;
  }
  out[(size_t)m * N + n] = acc;
}

// ---------------- ff fold: w''[b,j,h,:] and const_ff[b,j,h] ------------------
// w'[m] = sum_{n in hs} kff[b,j,hs+n]*wfq[hs+n,m]; w''=w'*a; const = w'·c + qb·kff
// grid (16 jh, 32 b), 256 threads (thread owns 4 m-cols).
__global__ __launch_bounds__(256)
void ffw_fold(const float* __restrict__ kff, const float* __restrict__ wfq,
              const float* __restrict__ qb, const float* __restrict__ afv,
              const float* __restrict__ cfv, u16* __restrict__ w2ff,
              float* __restrict__ cff) {
  __shared__ float redl[4];
  const int b = blockIdx.y, jh = blockIdx.x;
  const int j = jh >> 3, h = jh & 7;
  const int tid = threadIdx.x;
  const int m0 = tid * 4;
  const float* kp = kff + (size_t)b * 2048 + j * 1024 + h * 128;
  float a0 = 0, a1 = 0, a2 = 0, a3 = 0;
  for (int n = 0; n < 128; ++n) {
    const float kv = kp[n];
    const float4 wv = *(const float4*)(wfq + (size_t)(h * 128 + n) * 1024 + m0);
    a0 += kv * wv.x; a1 += kv * wv.y; a2 += kv * wv.z; a3 += kv * wv.w;
  }
  float cpart = a0 * cfv[m0] + a1 * cfv[m0 + 1] + a2 * cfv[m0 + 2] + a3 * cfv[m0 + 3];
  if (tid < 128) cpart += qb[h * 128 + tid] * kp[tid];
  ushort4 o = make_ushort4(f2bf(a0 * afv[m0]), f2bf(a1 * afv[m0 + 1]),
                           f2bf(a2 * afv[m0 + 2]), f2bf(a3 * afv[m0 + 3]));
  *(ushort4*)(w2ff + (size_t)(b * 16 + jh) * 1024 + m0) = o;
  for (int o2 = 32; o2 > 0; o2 >>= 1) cpart += __shfl_xor(cpart, o2, 64);
  if ((tid & 63) == 0) redl[tid >> 6] = cpart;
  __syncthreads();
  if (tid == 0) cff[b * 16 + jh] = redl[0] + redl[1] + redl[2] + redl[3];
}

// ---------------- ff score: S2[b,t,jh] = Y1[b,t,:]·w''[b,jh,:] + cff ---------
// MFMA 16x16x32; 4 waves x 32 t = 128 t per block. grid (8 chunks, 32 b).
__global__ __launch_bounds__(256)
void ff_score(const u16* __restrict__ Y1, const u16* __restrict__ w2ff,
              const float* __restrict__ cff, float* __restrict__ S2) {
  __shared__ u16 sA[128 * 64];
  __shared__ u16 sB[16 * 1024];
  const int chunk = blockIdx.x, b = blockIdx.y;
  const int tid = threadIdx.x;
  const int w = tid >> 6, l = tid & 63;
  const int lr = l & 15, lk = l >> 4;
  const int swz = lr & 7;

  // load w'' (16x1024) into LDS with slot-XOR swizzle
  {
    const int n = tid >> 4;
    const int sb = (tid & 15) * 8;
#pragma unroll
    for (int v = 0; v < 8; ++v) {
      const int sidx = sb + v;
      u16x8 val = *(const u16x8*)(w2ff + (size_t)(b * 16 + n) * 1024 + sidx * 8);
      *(u16x8*)(sB + n * 1024 + ((sidx ^ (n & 7)) << 3)) = val;
    }
  }

  const int srow = tid >> 3;
  const int scol = ((tid & 7) ^ (srow & 7)) << 3;
  const u16* Ab = Y1 + ((size_t)(b * 1024 + chunk * 128) + srow) * 1024 + scol;
  const size_t rstride32 = (size_t)32 * 1024;

  f32x4 acc[2] = {};

  for (int k0 = 0; k0 < 1024; k0 += 64) {
#pragma unroll
    for (int p = 0; p < 4; ++p)
      glds16(Ab + p * rstride32 + k0, sA + p * 2048 + w * 512);
    __syncthreads();
#pragma unroll
    for (int ks = 0; ks < 2; ++ks) {
      const int off = (((ks << 2) + lk) ^ swz) << 3;
      bf16x8 a0 = *(const bf16x8*)(sA + (w * 32 + lr) * 64 + off);
      bf16x8 a1 = *(const bf16x8*)(sA + (w * 32 + 16 + lr) * 64 + off);
      const int bs = (k0 >> 3) + (ks << 2) + lk;
      bf16x8 bf_ = *(const bf16x8*)(sB + lr * 1024 + ((bs ^ swz) << 3));
      acc[0] = __builtin_amdgcn_mfma_f32_16x16x32_bf16(a0, bf_, acc[0], 0, 0, 0);
      acc[1] = __builtin_amdgcn_mfma_f32_16x16x32_bf16(a1, bf_, acc[1], 0, 0, 0);
    }
    __syncthreads();
  }

  const float cadd = cff[b * 16 + lr];
#pragma unroll
  for (int m = 0; m < 2; ++m)
#pragma unroll
    for (int i = 0; i < 4; ++i) {
      const int trow = chunk * 128 + w * 32 + m * 16 + lk * 4 + i;
      S2[((size_t)b * 1024 + trow) * 16 + lr] = acc[m][i] + cadd;
    }
}

// ---------------- ff attention finish: probs + AV ----------------------------
// grid (8 chunks, 32 b), 256 threads: thread = (t_local = tid>>1, half = tid&1)
__global__ __launch_bounds__(256)
void ff_attn2(const float* __restrict__ S2, const float* __restrict__ vf,
              float* __restrict__ att_out, u16* __restrict__ AV) {
  __shared__ float v0s[1024], v1s[1024];
  const int chunk = blockIdx.x, b = blockIdx.y;
  const int tid = threadIdx.x;
  for (int i = tid; i < 1024; i += 256) {
    v0s[i] = vf[(size_t)b * 2048 + i];
    v1s[i] = vf[(size_t)b * 2048 + 1024 + i];
  }
  __syncthreads();
  const int tl = tid >> 1, half = tid & 1;
  const int t = chunk * 128 + tl;
  const float* srow = S2 + ((size_t)b * 1024 + t) * 16;
  float p0[8], p1[8];
#pragma unroll
  for (int h = 0; h < 8; ++h) {
    const float s0 = srow[h] * SCALE, s1 = srow[8 + h] * SCALE;
    const float mx = fmaxf(s0, s1);
    const float e0 = expf(s0 - mx), e1 = expf(s1 - mx);
    const float inv = 1.0f / (e0 + e1);
    p0[h] = e0 * inv; p1[h] = e1 * inv;
    if (half == 0) {
      float* o = att_out + ((size_t)(b * 8 + h) * 1024 + t) * 2;
      o[0] = p0[h]; o[1] = p1[h];
    }
  }
  u16* dst = AV + ((size_t)(b * 1024 + t)) * 1024 + half * 512;
  const int cb = half * 512;
  for (int v = 0; v < 64; ++v) {
    u16x8 o;
#pragma unroll
    for (int e = 0; e < 8; ++e) {
      const int c = cb + v * 8 + e;
      const int h = c >> 7;
      o[e] = f2bf(p0[h] * v0s[c] + p1[h] * v1s[c]);
    }
    *(u16x8*)(dst + v * 8) = o;
  }
}

// ---------------- memory-fuse attention (per batch) --------------------------
__global__ __launch_bounds__(256)
void mem_attn(const float* __restrict__ qmf, const u16* __restrict__ KM,
              const u16* __restrict__ VM, const float* __restrict__ mask,
              float* __restrict__ att_out, float* __restrict__ attv_out) {
  __shared__ float qs[1024];
  __shared__ float sS[512];
  __shared__ float sP[512];
  __shared__ float sM[64];
  const int b = blockIdx.x;
  const int tid = threadIdx.x;
  for (int i = tid; i < 1024; i += 256) qs[i] = qmf[i];
  if (tid < 64) sM[tid] = mask[b * 64 + tid];
  __syncthreads();
  for (int p = tid; p < 512; p += 256) {
    const int h = p >> 6, j = p & 63;
    const u16* kr = KM + (size_t)(b * 64 + j) * 1024 + h * 128;
    float acc = 0.f;
    for (int d = 0; d < 128; ++d) acc += qs[h * 128 + d] * bf2f(kr[d]);
    sS[p] = acc * sM[j] * SCALE;
  }
  __syncthreads();
  if (tid < 8) {
    const int h = tid;
    float mx = -3.4e38f;
    for (int j = 0; j < 64; ++j) mx = fmaxf(mx, sS[h * 64 + j]);
    float sum = 0.f;
    for (int j = 0; j < 64; ++j) {
      float e = expf(sS[h * 64 + j] - mx);
      sP[h * 64 + j] = e; sum += e;
    }
    const float inv = 1.0f / sum;
    for (int j = 0; j < 64; ++j) {
      float pp = sP[h * 64 + j] * inv;
      sP[h * 64 + j] = pp;
      att_out[(size_t)(b * 8 + h) * 64 + j] = pp;
    }
  }
  __syncthreads();
  for (int c = tid; c < 1024; c += 256) {
    const int h = c >> 7;
    float acc = 0.f;
    for (int j = 0; j < 64; ++j)
      acc += sP[h * 64 + j] * sM[j] * bf2f(VM[(size_t)(b * 64 + j) * 1024 + c]);
    attv_out[(size_t)b * 1024 + c] = acc;
  }
}

// ---------------- cur = inorm(concat(neg_tok, mem_out)) ----------------------
__global__ __launch_bounds__(256)
void make_cur(const float* __restrict__ neg, const float* __restrict__ memo,
              float* __restrict__ cur_out, float* __restrict__ curw) {
  const int i = blockIdx.x * 256 + threadIdx.x;   // 32768
  const int b = i >> 10, c = i & 1023;
  const float a = neg[c], x = memo[i];
  const float mean = 0.5f * (a + x);
  const float d = a - mean;
  const float rs = rsqrtf(d * d + EPS);
  const float o0 = d * rs, o1 = -d * rs;
  cur_out[(size_t)(b * 2) * 1024 + c] = o0;
  cur_out[(size_t)(b * 2 + 1) * 1024 + c] = o1;
  curw[(size_t)(b * 2) * 1024 + c] = o0;
  curw[(size_t)(b * 2 + 1) * 1024 + c] = o1;
}

// =============================================================================
extern "C" void kernel_launch(void* const* d_in, const int* in_sizes, int n_in,
                              void* d_out, int out_size, void* d_ws, size_t ws_size,
                              hipStream_t stream) {
  (void)in_sizes; (void)n_in; (void)out_size; (void)ws_size;

  const float* src      = (const float*)d_in[0];
  const float* lan      = (const float*)d_in[1];
  const float* qmask    = (const float*)d_in[3];
  const float* ip_w     = (const float*)d_in[4];
  const float* ip_g     = (const float*)d_in[6];
  const float* ip_beta  = (const float*)d_in[7];
  const float* lp_w     = (const float*)d_in[8];
  const float* lp_b     = (const float*)d_in[9];
  const float* mem_tok  = (const float*)d_in[10];
  const float* neg_tok  = (const float*)d_in[11];
  const float* vl_qw    = (const float*)d_in[12];
  const float* vl_qb    = (const float*)d_in[13];
  const float* vl_kw    = (const float*)d_in[14];
  const float* vl_kb    = (const float*)d_in[15];
  const float* mf_qw    = (const float*)d_in[20];
  const float* mf_qb    = (const float*)d_in[21];
  const float* mf_kw    = (const float*)d_in[22];
  const float* mf_kb    = (const float*)d_in[23];
  const float* mf_vw    = (const float*)d_in[24];
  const float* mf_vb    = (const float*)d_in[25];
  const float* mf_ow    = (const float*)d_in[26];
  const float* mf_ob    = (const float*)d_in[27];
  const float* ff_qw    = (const float*)d_in[28];
  const float* ff_qb    = (const float*)d_in[29];
  const float* ff_kw    = (const float*)d_in[30];
  const float* ff_kb    = (const float*)d_in[31];
  const float* ff_vw    = (const float*)d_in[32];
  const float* ff_vb    = (const float*)d_in[33];
  const float* ff_ow    = (const float*)d_in[34];
  const float* ff_ob    = (const float*)d_in[35];
  const float* op_w     = (const float*)d_in[36];
  const float* op_g     = (const float*)d_in[38];
  const float* op_beta  = (const float*)d_in[39];

  float* out_final = (float*)d_out;
  float* out_cur   = out_final + 33554432ull;
  float* out_vl    = out_cur + 65536ull;
  float* out_mem   = out_vl + 16777216ull;
  float* out_ff    = out_mem + 16384ull;

  // ---- workspace carve ----
  char* wp = (char*)d_ws;
  auto take = [&](size_t sz) { char* r = wp; wp += (sz + 255) & ~(size_t)255; return r; };
  u16*   W1   = (u16*)  take(67108864);    // Q2 (st1) -> ff_n (st3)
  u16*   W2   = (u16*)  take(67108864);    // Y1 -> ff_out
  u16*   SB   = (u16*)  take(67108864);    // src bf16 -> AV -> Z
  u16*   LP   = (u16*)  take(4194304);     // lan_p bf16
  u16*   QV   = (u16*)  take(4194304);     // vl q bf16
  u16*   KM   = (u16*)  take(4194304);     // mf k bf16
  u16*   VM   = (u16*)  take(4194304);     // mf v bf16
  u16*   LANB = (u16*)  take(3145728);     // lan bf16
  u16*   wip  = (u16*)  take(2097152);
  u16*   wlp  = (u16*)  take(1572864);
  u16*   wvq  = (u16*)  take(2097152);
  u16*   wmk  = (u16*)  take(2097152);
  u16*   wmv  = (u16*)  take(2097152);
  u16*   wfo  = (u16*)  take(2097152);
  u16*   wop  = (u16*)  take(2097152);
  u16*   wvkT = (u16*)  take(2097152);     // wvk transposed bf16
  u16*   w2ff = (u16*)  take(1048576);     // folded ff weights [32][16][1024]
  float* qmf   = (float*)take(4096);
  float* attvm = (float*)take(131072);
  float* memo  = (float*)take(131072);
  float* curw  = (float*)take(262144);
  float* kff   = (float*)take(262144);
  float* vff   = (float*)take(262144);
  float* ps    = (float*)take(2097152);
  float* pq    = (float*)take(2097152);
  float2* st1  = (float2*)take(8192);
  float2* st2  = (float2*)take(8192);
  float2* ist  = (float2*)take(262144);
  float* afv   = (float*)take(4096);       // a[c] = rs*g
  float* cfv   = (float*)take(4096);       // c[c] = beta - mu*a
  float* wcv   = (float*)take(4096);       // wc[n] = wvk[n,:]·c + kb[n]
  float* cff   = (float*)take(2048);       // ff consts [32][16]
  float* S2    = (float*)take(2097152);    // ff scores [32][1024][16]

  const dim3 blk(256);

  // conversions
  f2b_kernel<<<dim3(32768), blk, 0, stream>>>(src, SB, 8388608);
  {
    F2B8 j;
    const float* ins[8] = {lan, ip_w, lp_w, vl_qw, mf_kw, mf_vw, ff_ow, op_w};
    u16* outs[8] = {LANB, wip, wlp, wvq, wmk, wmv, wfo, wop};
    int n4s[8] = {393216, 262144, 196608, 262144, 262144, 262144, 262144, 262144};
    for (int i = 0; i < 8; ++i) { j.in[i] = ins[i]; j.out[i] = outs[i]; j.n4[i] = n4s[i]; }
    f2b_multi<<<dim3(1024, 8), blk, 0, stream>>>(j);
  }
  wtrans<<<dim3(16, 16), blk, 0, stream>>>(vl_kw, wvkT);

  // stage 0: input proj -> Y1 (W2); BN stats + fold vectors (no apply!)
  gemm_bt<<<dim3(8, 256), blk, 0, stream>>>(SB, wip, nullptr, W2, 32768, 1024, 1024);
  colstats_partial_b<<<dim3(256), blk, 0, stream>>>(W2, ps, pq);
  colstats_final<<<dim3(32), blk, 0, stream>>>(ps, pq, st1, ip_g, ip_beta, afv, cfv, 1.0f / 32768.0f);

  // lan proj + vl q proj
  gemm_bt<<<dim3(8, 16), blk, 0, stream>>>(LANB, wlp, lp_b, LP, 2048, 1024, 768);
  gemm_bt<<<dim3(8, 16), blk, 0, stream>>>(LP, wvq, vl_qb, QV, 2048, 1024, 1024);

  // stage 1 (vl, k-proj folded): q'' = (QV_h @ wvk_h) * a  -> Q2 (W1)
  gemm_qpp<<<dim3(8, 16, 8), blk, 0, stream>>>(QV, wvkT, afv, W1);
  small_gemm<<<dim3(4, 1), blk, 0, stream>>>(cfv, vl_kw, vl_kb, wcv, 1024, 1024);
  gemm_score_b<<<dim3(8, 4, 32), blk, 0, stream>>>(W1, W2, out_vl);
  vl_softmax<<<dim3(16384), blk, 0, stream>>>(out_vl, qmask, QV, wcv);

  // stage 2 (memory fuse)
  small_gemm<<<dim3(4, 1), blk, 0, stream>>>(mem_tok, mf_qw, mf_qb, qmf, 1024, 1024);
  gemm_bt<<<dim3(8, 16), blk, 0, stream>>>(LP, wmk, mf_kb, KM, 2048, 1024, 1024);
  gemm_bt<<<dim3(8, 16), blk, 0, stream>>>(LP, wmv, mf_vb, VM, 2048, 1024, 1024);
  mem_attn<<<dim3(32), blk, 0, stream>>>(qmf, KM, VM, qmask, out_mem, attvm);
  small_gemm<<<dim3(4, 32), blk, 0, stream>>>(attvm, mf_ow, mf_ob, memo, 1024, 1024);
  make_cur<<<dim3(128), blk, 0, stream>>>(neg_tok, memo, out_cur, curw);

  // stage 3 (feature fuse, q-proj folded)
  small_gemm<<<dim3(4, 64), blk, 0, stream>>>(curw, ff_kw, ff_kb, kff, 1024, 1024);
  small_gemm<<<dim3(4, 64), blk, 0, stream>>>(curw, ff_vw, ff_vb, vff, 1024, 1024);
  ffw_fold<<<dim3(16, 32), blk, 0, stream>>>(kff, ff_qw, ff_qb, afv, cfv, w2ff, cff);
  ff_score<<<dim3(8, 32), blk, 0, stream>>>(W2, w2ff, cff, S2);
  ff_attn2<<<dim3(8, 32), blk, 0, stream>>>(S2, vff, out_ff, SB);
  gemm_bt<<<dim3(8, 256), blk, 0, stream>>>(SB, wfo, ff_ob, W2, 32768, 1024, 1024);
  instats_partial_b<<<dim3(8, 32), blk, 0, stream>>>(W2, ps, pq);
  instats_final<<<dim3(32), blk, 0, stream>>>(ps, pq, ist);
  inorm_apply<<<dim3(16384), blk, 0, stream>>>(W2, ist, W1);
  gemm_bt<<<dim3(8, 256), blk, 0, stream>>>(W1, wop, nullptr, SB, 32768, 1024, 1024);
  colstats_partial_b<<<dim3(256), blk, 0, stream>>>(SB, ps, pq);
  colstats_final<<<dim3(32), blk, 0, stream>>>(ps, pq, st2, nullptr, nullptr, nullptr, nullptr, 1.0f / 32768.0f);
  bn_apply_f32<<<dim3(16384), blk, 0, stream>>>(SB, st2, op_g, op_beta, out_final);
}

// Round 7
// 851.187 us; speedup vs baseline: 1.2447x; 1.0451x over previous
//
#include <hip/hip_runtime.h>
#include <stdint.h>

#define EPS 1e-5f
#define SCALE 0.08838834764831845f  /* 1/sqrt(128) */

typedef __bf16 bf16x8 __attribute__((ext_vector_type(8)));
typedef float f32x4 __attribute__((ext_vector_type(4)));
typedef unsigned short u16;
typedef unsigned int u32;
typedef u16 u16x8 __attribute__((ext_vector_type(8)));

__device__ __forceinline__ u16 f2bf(float f) {
  union { float f; u32 u; } x; x.f = f;
  u32 r = x.u + 0x7fffu + ((x.u >> 16) & 1u);
  return (u16)(r >> 16);
}
__device__ __forceinline__ float bf2f(u16 u) {
  union { u32 u; float f; } x; x.u = ((u32)u) << 16; return x.f;
}
__device__ __forceinline__ void glds16(const void* g, void* l) {
  __builtin_amdgcn_global_load_lds((__attribute__((address_space(1))) void*)g,
                                   (__attribute__((address_space(3))) void*)l,
                                   16, 0, 0);
}

// ---------------- f32 -> bf16 convert (single big tensor) --------------------
__global__ __launch_bounds__(256) void f2b_kernel(const float* __restrict__ in,
                                                  u16* __restrict__ out, int n4) {
  int i = blockIdx.x * 256 + threadIdx.x;
  if (i >= n4) return;
  float4 v = ((const float4*)in)[i];
  ((ushort4*)out)[i] = make_ushort4(f2bf(v.x), f2bf(v.y), f2bf(v.z), f2bf(v.w));
}

// ---------------- f32 -> bf16 convert, up to 8 segments ----------------------
struct F2B8 {
  const float* in[8];
  u16* out[8];
  int n4[8];
};
__global__ __launch_bounds__(256) void f2b_multi(F2B8 j) {
  const int seg = blockIdx.y;
  const int n4 = j.n4[seg];
  const float* __restrict__ in = j.in[seg];
  u16* __restrict__ out = j.out[seg];
  for (int i = blockIdx.x * 256 + threadIdx.x; i < n4; i += gridDim.x * 256) {
    float4 v = ((const float4*)in)[i];
    ((ushort4*)out)[i] = make_ushort4(f2bf(v.x), f2bf(v.y), f2bf(v.z), f2bf(v.w));
  }
}

// ---------------- transpose weight: WT[m,n] = W[n,m], f32 -> bf16 ------------
__global__ __launch_bounds__(256)
void wtrans(const float* __restrict__ W, u16* __restrict__ WT) {
  __shared__ float tile[64][65];
  const int bx = blockIdx.x, by = blockIdx.y;   // 16 x 16 blocks of 64x64
  const int r = threadIdx.x >> 2, c0 = (threadIdx.x & 3) * 16;
  const float* src = W + (size_t)(by * 64 + r) * 1024 + bx * 64 + c0;
#pragma unroll
  for (int e = 0; e < 16; e += 4) {
    float4 v = *(const float4*)(src + e);
    tile[r][c0 + e] = v.x; tile[r][c0 + e + 1] = v.y;
    tile[r][c0 + e + 2] = v.z; tile[r][c0 + e + 3] = v.w;
  }
  __syncthreads();
  u16* dst = WT + (size_t)(bx * 64 + r) * 1024 + by * 64 + c0;
#pragma unroll
  for (int e = 0; e < 16; e += 4) {
    ushort4 o = make_ushort4(f2bf(tile[c0 + e][r]), f2bf(tile[c0 + e + 1][r]),
                             f2bf(tile[c0 + e + 2][r]), f2bf(tile[c0 + e + 3][r]));
    *(ushort4*)(dst + e) = o;
  }
}

// ---------------- 128x128 bf16 GEMM (BK=64, T1+T2): C=A@B^T (+bias) ----------
__global__ __launch_bounds__(256)
void gemm_bt(const u16* __restrict__ A, const u16* __restrict__ B,
             const float* __restrict__ bias, u16* __restrict__ Cb,
             int M, int N, int K) {
  __shared__ u16 sA[128 * 64];
  __shared__ u16 sB[128 * 64];
  const int nwg = (int)(gridDim.x * gridDim.y);
  const int chunk = nwg >> 3;
  int s = blockIdx.y * gridDim.x + blockIdx.x;
  int t = (s & 7) * chunk + (s >> 3);
  const int bn0 = (t & 7) * 128;
  const int bm0 = (t >> 3) * 128;
  const int tid = threadIdx.x;
  const int w = tid >> 6, l = tid & 63;
  const int wr = w >> 1, wc = w & 1;
  const int lr = l & 15, lk = l >> 4;
  const int swz = lr & 7;

  const int srow = tid >> 3;
  const int scol = ((tid & 7) ^ (srow & 7)) << 3;
  const u16* Ab = A + (size_t)(bm0 + srow) * K + scol;
  const u16* Bb = B + (size_t)(bn0 + srow) * K + scol;
  const size_t rstride32 = (size_t)32 * K;

  f32x4 acc[4][4] = {};

  for (int k0 = 0; k0 < K; k0 += 64) {
#pragma unroll
    for (int p = 0; p < 4; ++p) {
      glds16(Ab + p * rstride32 + k0, sA + p * 2048 + w * 512);
      glds16(Bb + p * rstride32 + k0, sB + p * 2048 + w * 512);
    }
    __syncthreads();
#pragma unroll
    for (int ks = 0; ks < 2; ++ks) {
      const int off = (((ks << 2) + lk) ^ swz) << 3;
      bf16x8 af[4], bfr[4];
#pragma unroll
      for (int m = 0; m < 4; ++m)
        af[m] = *(const bf16x8*)(sA + (wr * 64 + m * 16 + lr) * 64 + off);
#pragma unroll
      for (int n = 0; n < 4; ++n)
        bfr[n] = *(const bf16x8*)(sB + (wc * 64 + n * 16 + lr) * 64 + off);
#pragma unroll
      for (int m = 0; m < 4; ++m)
#pragma unroll
        for (int n = 0; n < 4; ++n)
          acc[m][n] = __builtin_amdgcn_mfma_f32_16x16x32_bf16(af[m], bfr[n], acc[m][n], 0, 0, 0);
    }
    __syncthreads();
  }

#pragma unroll
  for (int m = 0; m < 4; ++m) {
    const int grow0 = bm0 + wr * 64 + m * 16 + lk * 4;
#pragma unroll
    for (int n = 0; n < 4; ++n) {
      const int gcol = bn0 + wc * 64 + n * 16 + lr;
      const float bv = bias ? bias[gcol] : 0.0f;
#pragma unroll
      for (int i = 0; i < 4; ++i) {
        const float v = acc[m][n][i] + bv;
        Cb[(size_t)(grow0 + i) * N + gcol] = f2bf(v);
      }
    }
  }
}

// ---------------- q'' GEMM: Q2[b*512+h*64+i, m] = (QV[:,hs]@WT[:,hs]^T)*a[m] -
__global__ __launch_bounds__(256)
void gemm_qpp(const u16* __restrict__ QV, const u16* __restrict__ WT,
              const float* __restrict__ afv, u16* __restrict__ Q2) {
  __shared__ u16 sA[128 * 64];
  __shared__ u16 sB[128 * 64];
  const int h = blockIdx.z;
  int s = blockIdx.y * 8 + blockIdx.x;
  int t = (s & 7) * 16 + (s >> 3);
  const int bn0 = (t & 7) * 128;
  const int bm0 = (t >> 3) * 128;
  const int tid = threadIdx.x;
  const int w = tid >> 6, l = tid & 63;
  const int wr = w >> 1, wc = w & 1;
  const int lr = l & 15, lk = l >> 4;
  const int swz = lr & 7;

  const int srow = tid >> 3;
  const int scol = ((tid & 7) ^ (srow & 7)) << 3;
  const u16* Ab = QV + (size_t)(bm0 + srow) * 1024 + h * 128 + scol;
  const u16* Bb = WT + (size_t)(bn0 + srow) * 1024 + h * 128 + scol;
  const size_t rstride32 = (size_t)32 * 1024;

  f32x4 acc[4][4] = {};

  for (int k0 = 0; k0 < 128; k0 += 64) {
#pragma unroll
    for (int p = 0; p < 4; ++p) {
      glds16(Ab + p * rstride32 + k0, sA + p * 2048 + w * 512);
      glds16(Bb + p * rstride32 + k0, sB + p * 2048 + w * 512);
    }
    __syncthreads();
#pragma unroll
    for (int ks = 0; ks < 2; ++ks) {
      const int off = (((ks << 2) + lk) ^ swz) << 3;
      bf16x8 af[4], bfr[4];
#pragma unroll
      for (int m = 0; m < 4; ++m)
        af[m] = *(const bf16x8*)(sA + (wr * 64 + m * 16 + lr) * 64 + off);
#pragma unroll
      for (int n = 0; n < 4; ++n)
        bfr[n] = *(const bf16x8*)(sB + (wc * 64 + n * 16 + lr) * 64 + off);
#pragma unroll
      for (int m = 0; m < 4; ++m)
#pragma unroll
        for (int n = 0; n < 4; ++n)
          acc[m][n] = __builtin_amdgcn_mfma_f32_16x16x32_bf16(af[m], bfr[n], acc[m][n], 0, 0, 0);
    }
    __syncthreads();
  }

#pragma unroll
  for (int m = 0; m < 4; ++m) {
    const int grow0 = bm0 + wr * 64 + m * 16 + lk * 4;
#pragma unroll
    for (int n = 0; n < 4; ++n) {
      const int gcol = bn0 + wc * 64 + n * 16 + lr;
      const float a = afv[gcol];
#pragma unroll
      for (int i = 0; i < 4; ++i) {
        const int gr = grow0 + i;
        const int q2row = ((gr >> 6) << 9) + h * 64 + (gr & 63);
        Q2[(size_t)q2row * 1024 + gcol] = f2bf(acc[m][n][i] * a);
      }
    }
  }
}

// ---------------- batched vl-score GEMM: per b: S[512,1024] = Q2[b]@Y1[b]^T --
__global__ __launch_bounds__(256)
void gemm_score_b(const u16* __restrict__ Q2, const u16* __restrict__ Y1,
                  float* __restrict__ out) {
  __shared__ u16 sA[128 * 64];
  __shared__ u16 sB[128 * 64];
  int s = (int)((blockIdx.z * gridDim.y + blockIdx.y) * gridDim.x + blockIdx.x);
  int t = (s & 7) * 128 + (s >> 3);
  const int b = t >> 5;
  const int rem = t & 31;
  const int bn0 = (rem & 7) * 128;
  const int bm0 = (rem >> 3) * 128;
  const int tid = threadIdx.x;
  const int w = tid >> 6, l = tid & 63;
  const int wr = w >> 1, wc = w & 1;
  const int lr = l & 15, lk = l >> 4;
  const int swz = lr & 7;

  const int srow = tid >> 3;
  const int scol = ((tid & 7) ^ (srow & 7)) << 3;
  const u16* Ab = Q2 + (size_t)b * 524288 + (size_t)(bm0 + srow) * 1024 + scol;
  const u16* Bb = Y1 + (size_t)b * 1048576 + (size_t)(bn0 + srow) * 1024 + scol;
  const size_t rstride32 = (size_t)32 * 1024;

  f32x4 acc[4][4] = {};

  for (int k0 = 0; k0 < 1024; k0 += 64) {
#pragma unroll
    for (int p = 0; p < 4; ++p) {
      glds16(Ab + p * rstride32 + k0, sA + p * 2048 + w * 512);
      glds16(Bb + p * rstride32 + k0, sB + p * 2048 + w * 512);
    }
    __syncthreads();
#pragma unroll
    for (int ks = 0; ks < 2; ++ks) {
      const int off = (((ks << 2) + lk) ^ swz) << 3;
      bf16x8 af[4], bfr[4];
#pragma unroll
      for (int m = 0; m < 4; ++m)
        af[m] = *(const bf16x8*)(sA + (wr * 64 + m * 16 + lr) * 64 + off);
#pragma unroll
      for (int n = 0; n < 4; ++n)
        bfr[n] = *(const bf16x8*)(sB + (wc * 64 + n * 16 + lr) * 64 + off);
#pragma unroll
      for (int m = 0; m < 4; ++m)
#pragma unroll
        for (int n = 0; n < 4; ++n)
          acc[m][n] = __builtin_amdgcn_mfma_f32_16x16x32_bf16(af[m], bfr[n], acc[m][n], 0, 0, 0);
    }
    __syncthreads();
  }

  float* C = out + (size_t)b * 524288;
#pragma unroll
  for (int m = 0; m < 4; ++m) {
    const int grow0 = bm0 + wr * 64 + m * 16 + lk * 4;
#pragma unroll
    for (int n = 0; n < 4; ++n) {
      const int gcol = bn0 + wc * 64 + n * 16 + lr;
#pragma unroll
      for (int i = 0; i < 4; ++i)
        C[(size_t)(grow0 + i) * 1024 + gcol] = acc[m][n][i];
    }
  }
}

// ---------------- vl softmax (+folded const from QV·wc, query-mask scale) ----
__global__ __launch_bounds__(256)
void vl_softmax(float* __restrict__ S, const float* __restrict__ qmask,
                const u16* __restrict__ QV, const float* __restrict__ wcv) {
  __shared__ float red[4];
  __shared__ float red2[4];
  const int row = blockIdx.x;          // (b*8+h)*64+i
  const int b = row >> 9;
  const int h = (row >> 6) & 7;
  const int i = row & 63;
  const int t = threadIdx.x;
  float cp = 0.f;
  if (t < 128) cp = bf2f(QV[(size_t)(b * 64 + i) * 1024 + h * 128 + t]) * wcv[h * 128 + t];
  for (int o = 32; o > 0; o >>= 1) cp += __shfl_xor(cp, o, 64);
  if ((t & 63) == 0) red2[t >> 6] = cp;
  __syncthreads();
  const float cst = red2[0] + red2[1];
  const float scale = qmask[b * 64 + i] * SCALE;
  float* p = S + (size_t)row * 1024;
  float4 v = ((const float4*)p)[t];
  v.x = (v.x + cst) * scale; v.y = (v.y + cst) * scale;
  v.z = (v.z + cst) * scale; v.w = (v.w + cst) * scale;
  float mx = fmaxf(fmaxf(v.x, v.y), fmaxf(v.z, v.w));
  for (int o = 32; o > 0; o >>= 1) mx = fmaxf(mx, __shfl_xor(mx, o, 64));
  __syncthreads();
  if ((t & 63) == 0) red[t >> 6] = mx;
  __syncthreads();
  mx = fmaxf(fmaxf(red[0], red[1]), fmaxf(red[2], red[3]));
  const float e0 = expf(v.x - mx), e1 = expf(v.y - mx);
  const float e2 = expf(v.z - mx), e3 = expf(v.w - mx);
  float sm = e0 + e1 + e2 + e3;
  for (int o = 32; o > 0; o >>= 1) sm += __shfl_xor(sm, o, 64);
  __syncthreads();
  if ((t & 63) == 0) red[t >> 6] = sm;
  __syncthreads();
  sm = red[0] + red[1] + red[2] + red[3];
  const float inv = 1.0f / sm;
  ((float4*)p)[t] = make_float4(e0 * inv, e1 * inv, e2 * inv, e3 * inv);
}

// ---------------- column stats over bf16 [32768,1024] ------------------------
__global__ __launch_bounds__(256)
void colstats_partial_b(const u16* __restrict__ X, float* __restrict__ ps,
                        float* __restrict__ pq) {
  const int tid = threadIdx.x;
  const int chunk = blockIdx.x;
  const int colb = (tid & 127) * 8;
  const int rg = tid >> 7;
  const u16* p = X + ((size_t)chunk * 128 + rg * 64) * 1024 + colb;
  float s[8] = {}, q[8] = {};
  for (int r = 0; r < 64; ++r) {
    u16x8 v = *(const u16x8*)(p + (size_t)r * 1024);
#pragma unroll
    for (int j = 0; j < 8; ++j) {
      float f = bf2f(v[j]);
      s[j] += f; q[j] += f * f;
    }
  }
  float* dps = ps + (size_t)(chunk * 2 + rg) * 1024 + colb;
  float* dpq = pq + (size_t)(chunk * 2 + rg) * 1024 + colb;
  *(float4*)(dps) = make_float4(s[0], s[1], s[2], s[3]);
  *(float4*)(dps + 4) = make_float4(s[4], s[5], s[6], s[7]);
  *(float4*)(dpq) = make_float4(q[0], q[1], q[2], q[3]);
  *(float4*)(dpq + 4) = make_float4(q[4], q[5], q[6], q[7]);
}
// reduce 512 chunks -> stats + BN-fold vectors a, c
__global__ __launch_bounds__(256)
void colstats_final(const float* __restrict__ ps, const float* __restrict__ pq,
                    float2* __restrict__ st, const float* __restrict__ g,
                    const float* __restrict__ be, float* __restrict__ afv,
                    float* __restrict__ cfv, float inv_n) {
  __shared__ float rs_[8][32], rq_[8][32];
  const int cg = threadIdx.x >> 5, cl = threadIdx.x & 31;
  const int col = blockIdx.x * 32 + cl;
  float s = 0.f, q = 0.f;
  for (int i = 0; i < 64; ++i) {
    const size_t idx = (size_t)(cg * 64 + i) * 1024 + col;
    s += ps[idx]; q += pq[idx];
  }
  rs_[cg][cl] = s; rq_[cg][cl] = q;
  __syncthreads();
  if (cg == 0) {
    for (int i = 1; i < 8; ++i) { s += rs_[i][cl]; q += rq_[i][cl]; }
    const float m = s * inv_n;
    const float v = q * inv_n - m * m;
    const float rs = rsqrtf(v + EPS);
    st[col] = make_float2(m, rs);
    if (afv) {
      const float a = rs * g[col];
      afv[col] = a;
      cfv[col] = be[col] - m * a;
    }
  }
}

// ---------------- small f32 GEMM: out[m,n] = A[m,:]·W[n,:] + bias[n] ---------
__global__ __launch_bounds__(256)
void small_gemm(const float* __restrict__ A, const float* __restrict__ W,
                const float* __restrict__ bias, float* __restrict__ out,
                int N, int K) {
  __shared__ float sA[1024];
  const int m = blockIdx.y;
  const int n = blockIdx.x * 256 + threadIdx.x;
  for (int i = threadIdx.x; i < K; i += 256) sA[i] = A[(size_t)m * K + i];
  __syncthreads();
  const float4* w4 = (const float4*)(W + (size_t)n * K);
  const float4* a4 = (const float4*)sA;
  float acc = bias ? bias[n] : 0.0f;
  for (int k = 0; k < K / 4; ++k) {
    float4 wv = w4[k], av = a4[k];
    acc += av.x * wv.x + av.y * wv.y + av.z * wv.z + av.w * wv.w;
  }
  out[(size_t)m * N + n] = acc;
}

// ---------------- memory-fuse attention (per batch) --------------------------
__global__ __launch_bounds__(256)
void mem_attn(const float* __restrict__ qmf, const u16* __restrict__ KM,
              const u16* __restrict__ VM, const float* __restrict__ mask,
              float* __restrict__ att_out, float* __restrict__ attv_out) {
  __shared__ float qs[1024];
  __shared__ float sS[512];
  __shared__ float sP[512];
  __shared__ float sM[64];
  const int b = blockIdx.x;
  const int tid = threadIdx.x;
  for (int i = tid; i < 1024; i += 256) qs[i] = qmf[i];
  if (tid < 64) sM[tid] = mask[b * 64 + tid];
  __syncthreads();
  for (int p = tid; p < 512; p += 256) {
    const int h = p >> 6, j = p & 63;
    const u16* kr = KM + (size_t)(b * 64 + j) * 1024 + h * 128;
    float acc = 0.f;
    for (int d = 0; d < 128; ++d) acc += qs[h * 128 + d] * bf2f(kr[d]);
    sS[p] = acc * sM[j] * SCALE;
  }
  __syncthreads();
  if (tid < 8) {
    const int h = tid;
    float mx = -3.4e38f;
    for (int j = 0; j < 64; ++j) mx = fmaxf(mx, sS[h * 64 + j]);
    float sum = 0.f;
    for (int j = 0; j < 64; ++j) {
      float e = expf(sS[h * 64 + j] - mx);
      sP[h * 64 + j] = e; sum += e;
    }
    const float inv = 1.0f / sum;
    for (int j = 0; j < 64; ++j) {
      float pp = sP[h * 64 + j] * inv;
      sP[h * 64 + j] = pp;
      att_out[(size_t)(b * 8 + h) * 64 + j] = pp;
    }
  }
  __syncthreads();
  for (int c = tid; c < 1024; c += 256) {
    const int h = c >> 7;
    float acc = 0.f;
    for (int j = 0; j < 64; ++j)
      acc += sP[h * 64 + j] * sM[j] * bf2f(VM[(size_t)(b * 64 + j) * 1024 + c]);
    attv_out[(size_t)b * 1024 + c] = acc;
  }
}

// ---------------- cur = inorm(concat(neg_tok, mem_out)) ----------------------
__global__ __launch_bounds__(256)
void make_cur(const float* __restrict__ neg, const float* __restrict__ memo,
              float* __restrict__ cur_out, float* __restrict__ curw) {
  const int i = blockIdx.x * 256 + threadIdx.x;   // 32768
  const int b = i >> 10, c = i & 1023;
  const float a = neg[c], x = memo[i];
  const float mean = 0.5f * (a + x);
  const float d = a - mean;
  const float rs = rsqrtf(d * d + EPS);
  const float o0 = d * rs, o1 = -d * rs;
  cur_out[(size_t)(b * 2) * 1024 + c] = o0;
  cur_out[(size_t)(b * 2 + 1) * 1024 + c] = o1;
  curw[(size_t)(b * 2) * 1024 + c] = o0;
  curw[(size_t)(b * 2 + 1) * 1024 + c] = o1;
}

// ---------------- ff fold: w''[b,j,h,:] and const_ff[b,j,h] ------------------
__global__ __launch_bounds__(256)
void ffw_fold(const float* __restrict__ kff, const float* __restrict__ wfq,
              const float* __restrict__ qb, const float* __restrict__ afv,
              const float* __restrict__ cfv, u16* __restrict__ w2ff,
              float* __restrict__ cff) {
  __shared__ float redl[4];
  const int b = blockIdx.y, jh = blockIdx.x;
  const int j = jh >> 3, h = jh & 7;
  const int tid = threadIdx.x;
  const int m0 = tid * 4;
  const float* kp = kff + (size_t)b * 2048 + j * 1024 + h * 128;
  float a0 = 0, a1 = 0, a2 = 0, a3 = 0;
  for (int n = 0; n < 128; ++n) {
    const float kv = kp[n];
    const float4 wv = *(const float4*)(wfq + (size_t)(h * 128 + n) * 1024 + m0);
    a0 += kv * wv.x; a1 += kv * wv.y; a2 += kv * wv.z; a3 += kv * wv.w;
  }
  float cpart = a0 * cfv[m0] + a1 * cfv[m0 + 1] + a2 * cfv[m0 + 2] + a3 * cfv[m0 + 3];
  if (tid < 128) cpart += qb[h * 128 + tid] * kp[tid];
  ushort4 o = make_ushort4(f2bf(a0 * afv[m0]), f2bf(a1 * afv[m0 + 1]),
                           f2bf(a2 * afv[m0 + 2]), f2bf(a3 * afv[m0 + 3]));
  *(ushort4*)(w2ff + (size_t)(b * 16 + jh) * 1024 + m0) = o;
  for (int o2 = 32; o2 > 0; o2 >>= 1) cpart += __shfl_xor(cpart, o2, 64);
  if ((tid & 63) == 0) redl[tid >> 6] = cpart;
  __syncthreads();
  if (tid == 0) cff[b * 16 + jh] = redl[0] + redl[1] + redl[2] + redl[3];
}

// ---------------- ff score: S2[b,t,jh] = Y1[b,t,:]·w''[b,jh,:] + cff ---------
__global__ __launch_bounds__(256)
void ff_score(const u16* __restrict__ Y1, const u16* __restrict__ w2ff,
              const float* __restrict__ cff, float* __restrict__ S2) {
  __shared__ u16 sA[128 * 64];
  __shared__ u16 sB[16 * 1024];
  const int chunk = blockIdx.x, b = blockIdx.y;
  const int tid = threadIdx.x;
  const int w = tid >> 6, l = tid & 63;
  const int lr = l & 15, lk = l >> 4;
  const int swz = lr & 7;

  {
    const int n = tid >> 4;
    const int sb = (tid & 15) * 8;
#pragma unroll
    for (int v = 0; v < 8; ++v) {
      const int sidx = sb + v;
      u16x8 val = *(const u16x8*)(w2ff + (size_t)(b * 16 + n) * 1024 + sidx * 8);
      *(u16x8*)(sB + n * 1024 + ((sidx ^ (n & 7)) << 3)) = val;
    }
  }

  const int srow = tid >> 3;
  const int scol = ((tid & 7) ^ (srow & 7)) << 3;
  const u16* Ab = Y1 + ((size_t)(b * 1024 + chunk * 128) + srow) * 1024 + scol;
  const size_t rstride32 = (size_t)32 * 1024;

  f32x4 acc[2] = {};

  for (int k0 = 0; k0 < 1024; k0 += 64) {
#pragma unroll
    for (int p = 0; p < 4; ++p)
      glds16(Ab + p * rstride32 + k0, sA + p * 2048 + w * 512);
    __syncthreads();
#pragma unroll
    for (int ks = 0; ks < 2; ++ks) {
      const int off = (((ks << 2) + lk) ^ swz) << 3;
      bf16x8 a0 = *(const bf16x8*)(sA + (w * 32 + lr) * 64 + off);
      bf16x8 a1 = *(const bf16x8*)(sA + (w * 32 + 16 + lr) * 64 + off);
      const int bs = (k0 >> 3) + (ks << 2) + lk;
      bf16x8 bf_ = *(const bf16x8*)(sB + lr * 1024 + ((bs ^ swz) << 3));
      acc[0] = __builtin_amdgcn_mfma_f32_16x16x32_bf16(a0, bf_, acc[0], 0, 0, 0);
      acc[1] = __builtin_amdgcn_mfma_f32_16x16x32_bf16(a1, bf_, acc[1], 0, 0, 0);
    }
    __syncthreads();
  }

  const float cadd = cff[b * 16 + lr];
#pragma unroll
  for (int m = 0; m < 2; ++m)
#pragma unroll
    for (int i = 0; i < 4; ++i) {
      const int trow = chunk * 128 + w * 32 + m * 16 + lk * 4 + i;
      S2[((size_t)b * 1024 + trow) * 16 + lr] = acc[m][i] + cadd;
    }
}

// ---------------- ff softmax -> P[32768][16] f32 + att output ----------------
__global__ __launch_bounds__(256)
void ff_soft(const float* __restrict__ S2, float* __restrict__ P,
             float* __restrict__ att_out) {
  const int t = blockIdx.x * 256 + threadIdx.x;  // 0..32767
  const int b = t >> 10, tl = t & 1023;
  const float* srow = S2 + (size_t)t * 16;
  float4 s0 = *(const float4*)(srow);
  float4 s1 = *(const float4*)(srow + 4);
  float4 s2 = *(const float4*)(srow + 8);
  float4 s3 = *(const float4*)(srow + 12);
  float sj0[8] = {s0.x, s0.y, s0.z, s0.w, s1.x, s1.y, s1.z, s1.w};
  float sj1[8] = {s2.x, s2.y, s2.z, s2.w, s3.x, s3.y, s3.z, s3.w};
  float p0[8], p1[8];
#pragma unroll
  for (int h = 0; h < 8; ++h) {
    const float a0 = sj0[h] * SCALE, a1 = sj1[h] * SCALE;
    const float mx = fmaxf(a0, a1);
    const float e0 = expf(a0 - mx), e1 = expf(a1 - mx);
    const float inv = 1.f / (e0 + e1);
    p0[h] = e0 * inv; p1[h] = e1 * inv;
    float* o = att_out + ((size_t)(b * 8 + h) * 1024 + tl) * 2;
    o[0] = p0[h]; o[1] = p1[h];
  }
  float* pr = P + (size_t)t * 16;
  *(float4*)(pr)      = make_float4(p0[0], p0[1], p0[2], p0[3]);
  *(float4*)(pr + 4)  = make_float4(p0[4], p0[5], p0[6], p0[7]);
  *(float4*)(pr + 8)  = make_float4(p1[0], p1[1], p1[2], p1[3]);
  *(float4*)(pr + 12) = make_float4(p1[4], p1[5], p1[6], p1[7]);
}

// ---------------- pbar[b][16] = mean_t P; G[b][16][16] = (1/T) P^T P ---------
__global__ __launch_bounds__(256)
void pg_kernel(const float* __restrict__ P, float* __restrict__ G,
               float* __restrict__ pbar) {
  __shared__ float Pl[128][16];
  const int b = blockIdx.x;
  const int tid = threadIdx.x;
  const int j = tid >> 4, j2 = tid & 15;
  float acc = 0.f, accp = 0.f;
  for (int c = 0; c < 8; ++c) {
    __syncthreads();
    for (int i = tid; i < 2048; i += 256)
      Pl[i >> 4][i & 15] = P[((size_t)b * 1024 + c * 128 + (i >> 4)) * 16 + (i & 15)];
    __syncthreads();
    for (int t = 0; t < 128; ++t) {
      acc += Pl[t][j] * Pl[t][j2];
      if (j == 0) accp += Pl[t][j2];
    }
  }
  G[b * 256 + tid] = acc * (1.f / 1024.f);
  if (j == 0) pbar[b * 16 + j2] = accp * (1.f / 1024.f);
}

// ---------------- U[b][jh][m] = sum_d vff[b,j,h*128+d] * wfo[m,h*128+d] ------
__global__ __launch_bounds__(256)
void ufold(const float* __restrict__ vff, const u16* __restrict__ wfoT,
           float* __restrict__ U) {
  const int b = blockIdx.y, jh = blockIdx.x;
  const int j = jh >> 3, h = jh & 7;
  const int m0 = threadIdx.x * 4;
  const float* vp = vff + (size_t)b * 2048 + j * 1024 + h * 128;
  float a0 = 0, a1 = 0, a2 = 0, a3 = 0;
  for (int d = 0; d < 128; ++d) {
    const float kv = vp[d];
    ushort4 wv = *(const ushort4*)(wfoT + (size_t)(h * 128 + d) * 1024 + m0);
    a0 += kv * bf2f(wv.x); a1 += kv * bf2f(wv.y);
    a2 += kv * bf2f(wv.z); a3 += kv * bf2f(wv.w);
  }
  *(float4*)(U + (size_t)(b * 16 + jh) * 1024 + m0) = make_float4(a0, a1, a2, a3);
}

// ---------------- analytic instance-norm stats of ff_out ---------------------
__global__ __launch_bounds__(256)
void istats_a(const float* __restrict__ U, const float* __restrict__ G,
              const float* __restrict__ pbar, const float* __restrict__ ob,
              float* __restrict__ mi, float* __restrict__ rsi) {
  __shared__ float Gs[256], pb[16];
  const int b = blockIdx.x;
  const int tid = threadIdx.x;
  Gs[tid] = G[b * 256 + tid];
  if (tid < 16) pb[tid] = pbar[b * 16 + tid];
  __syncthreads();
#pragma unroll
  for (int e = 0; e < 4; ++e) {
    const int m = tid * 4 + e;
    float u[16];
#pragma unroll
    for (int jj = 0; jj < 16; ++jj) u[jj] = U[(size_t)(b * 16 + jj) * 1024 + m];
    const float o = ob[m];
    float s1 = 0.f;
#pragma unroll
    for (int jj = 0; jj < 16; ++jj) s1 += pb[jj] * u[jj];
    float q = 0.f;
#pragma unroll
    for (int jj = 0; jj < 16; ++jj) {
      float gq = 0.f;
#pragma unroll
      for (int j2 = 0; j2 < 16; ++j2) gq += Gs[jj * 16 + j2] * u[j2];
      q += u[jj] * gq;
    }
    const float mean = s1 + o;
    const float e2 = q + 2.f * o * s1 + o * o;
    const float var = fmaxf(e2 - mean * mean, 0.f);
    mi[b * 1024 + m] = mean;
    rsi[b * 1024 + m] = rsqrtf(var + EPS);
  }
}

// ---------------- U2b[b][32][1024] bf16: rows 0-15 U*rsi, 16 = (ob-mi)*rsi ---
__global__ __launch_bounds__(256)
void u2prep(const float* __restrict__ U, const float* __restrict__ mi,
            const float* __restrict__ rsi, const float* __restrict__ ob,
            u16* __restrict__ U2b) {
  const int b = blockIdx.x;
  const int m0 = threadIdx.x * 4;
  float4 rs4 = *(const float4*)(rsi + b * 1024 + m0);
  const float rr[4] = {rs4.x, rs4.y, rs4.z, rs4.w};
#pragma unroll
  for (int jj = 0; jj < 16; ++jj) {
    float4 u4 = *(const float4*)(U + (size_t)(b * 16 + jj) * 1024 + m0);
    ushort4 o = make_ushort4(f2bf(u4.x * rr[0]), f2bf(u4.y * rr[1]),
                             f2bf(u4.z * rr[2]), f2bf(u4.w * rr[3]));
    *(ushort4*)(U2b + (size_t)(b * 32 + jj) * 1024 + m0) = o;
  }
  float4 mi4 = *(const float4*)(mi + b * 1024 + m0);
  float4 ob4 = *(const float4*)(ob + m0);
  ushort4 od = make_ushort4(
      f2bf((ob4.x - mi4.x) * rr[0]), f2bf((ob4.y - mi4.y) * rr[1]),
      f2bf((ob4.z - mi4.z) * rr[2]), f2bf((ob4.w - mi4.w) * rr[3]));
  *(ushort4*)(U2b + (size_t)(b * 32 + 16) * 1024 + m0) = od;
  ushort4 z = make_ushort4(0, 0, 0, 0);
#pragma unroll
  for (int jj = 17; jj < 32; ++jj)
    *(ushort4*)(U2b + (size_t)(b * 32 + jj) * 1024 + m0) = z;
}

// ---------------- W2op[b][32][1024] = U2b[b] @ wop^T (MFMA, M=32) ------------
__global__ __launch_bounds__(256)
void w2op_gemm(const u16* __restrict__ U2b, const u16* __restrict__ wop,
               float* __restrict__ W2op) {
  __shared__ u16 sA[32 * 64];
  __shared__ u16 sB[128 * 64];
  const int b = blockIdx.y;
  const int bn0 = blockIdx.x * 128;
  const int tid = threadIdx.x;
  const int w = tid >> 6, l = tid & 63;
  const int lr = l & 15, lk = l >> 4;
  const int swz = lr & 7;
  const int srow = tid >> 3;
  const int scol = ((tid & 7) ^ (srow & 7)) << 3;
  const u16* Ab = U2b + (size_t)b * 32768 + (size_t)srow * 1024 + scol;
  const u16* Bb = wop + (size_t)(bn0 + srow) * 1024 + scol;
  const size_t rstride32 = (size_t)32 * 1024;

  f32x4 acc[2][2] = {};
  for (int k0 = 0; k0 < 1024; k0 += 64) {
    glds16(Ab + k0, sA + w * 512);
#pragma unroll
    for (int p = 0; p < 4; ++p)
      glds16(Bb + p * rstride32 + k0, sB + p * 2048 + w * 512);
    __syncthreads();
#pragma unroll
    for (int ks = 0; ks < 2; ++ks) {
      const int off = (((ks << 2) + lk) ^ swz) << 3;
      bf16x8 af[2], bfr[2];
#pragma unroll
      for (int m = 0; m < 2; ++m)
        af[m] = *(const bf16x8*)(sA + (m * 16 + lr) * 64 + off);
#pragma unroll
      for (int n = 0; n < 2; ++n)
        bfr[n] = *(const bf16x8*)(sB + (w * 32 + n * 16 + lr) * 64 + off);
#pragma unroll
      for (int m = 0; m < 2; ++m)
#pragma unroll
        for (int n = 0; n < 2; ++n)
          acc[m][n] = __builtin_amdgcn_mfma_f32_16x16x32_bf16(af[m], bfr[n], acc[m][n], 0, 0, 0);
    }
    __syncthreads();
  }
#pragma unroll
  for (int m = 0; m < 2; ++m)
#pragma unroll
    for (int n = 0; n < 2; ++n)
#pragma unroll
      for (int i = 0; i < 4; ++i) {
        const int row = m * 16 + lk * 4 + i;
        const int col = bn0 + w * 32 + n * 16 + lr;
        W2op[((size_t)b * 32 + row) * 1024 + col] = acc[m][n][i];
      }
}

// ---------------- analytic BN stats of Z (partials over b-groups) ------------
__global__ __launch_bounds__(256)
void znstats_part(const float* __restrict__ W2op, const float* __restrict__ G,
                  const float* __restrict__ pbar, float* __restrict__ pmu,
                  float* __restrict__ pe2) {
  __shared__ float Gs[256], pb[16];
  const int m = blockIdx.x * 256 + threadIdx.x;
  const int bg = blockIdx.y;
  float amu = 0.f, ae2 = 0.f;
  for (int bi = 0; bi < 4; ++bi) {
    const int b = bg * 4 + bi;
    __syncthreads();
    Gs[threadIdx.x] = G[b * 256 + threadIdx.x];
    if (threadIdx.x < 16) pb[threadIdx.x] = pbar[b * 16 + threadIdx.x];
    __syncthreads();
    float wv[17];
#pragma unroll
    for (int jj = 0; jj < 17; ++jj) wv[jj] = W2op[((size_t)b * 32 + jj) * 1024 + m];
    float s1 = 0.f;
#pragma unroll
    for (int jj = 0; jj < 16; ++jj) s1 += pb[jj] * wv[jj];
    float q = 0.f;
#pragma unroll
    for (int jj = 0; jj < 16; ++jj) {
      float gq = 0.f;
#pragma unroll
      for (int j2 = 0; j2 < 16; ++j2) gq += Gs[jj * 16 + j2] * wv[j2];
      q += wv[jj] * gq;
    }
    const float cz = wv[16];
    amu += s1 + cz;
    ae2 += q + 2.f * cz * s1 + cz * cz;
  }
  pmu[bg * 1024 + m] = amu;
  pe2[bg * 1024 + m] = ae2;
}

__global__ __launch_bounds__(256)
void znfin(const float* __restrict__ pmu, const float* __restrict__ pe2,
           const float* __restrict__ g, const float* __restrict__ be,
           float* __restrict__ afin, float* __restrict__ cf0) {
  const int m = blockIdx.x * 256 + threadIdx.x;
  float mu = 0.f, e2 = 0.f;
#pragma unroll
  for (int i = 0; i < 8; ++i) { mu += pmu[i * 1024 + m]; e2 += pe2[i * 1024 + m]; }
  mu *= (1.f / 32.f); e2 *= (1.f / 32.f);
  const float var = fmaxf(e2 - mu * mu, 0.f);
  const float A = rsqrtf(var + EPS) * g[m];
  afin[m] = A;
  cf0[m] = be[m] - mu * A;
}

// ---------------- final: out[t,m] = sum_j P[t,j]*W2op[b][j,m]*A[m] + const ---
__global__ __launch_bounds__(256)
void zfinal(const float* __restrict__ P, const float* __restrict__ W2op,
            const float* __restrict__ afin, const float* __restrict__ cf0,
            float* __restrict__ out) {
  __shared__ float WF[16][1024];
  __shared__ float CFb[1024];
  const int b = blockIdx.x >> 3, tc = blockIdx.x & 7;
  const int tid = threadIdx.x;
  for (int i = tid; i < 1024; i += 256) {
    const float A = afin[i];
    CFb[i] = W2op[((size_t)b * 32 + 16) * 1024 + i] * A + cf0[i];
#pragma unroll
    for (int jj = 0; jj < 16; ++jj)
      WF[jj][i] = W2op[((size_t)b * 32 + jj) * 1024 + i] * A;
  }
  __syncthreads();
  const int tl = tid >> 1, half = tid & 1;
  const int trow = b * 1024 + tc * 128 + tl;
  const float* pr = P + (size_t)trow * 16;
  float p[16];
  float4 p0 = *(const float4*)(pr), p1 = *(const float4*)(pr + 4);
  float4 p2 = *(const float4*)(pr + 8), p3 = *(const float4*)(pr + 12);
  p[0] = p0.x; p[1] = p0.y; p[2] = p0.z; p[3] = p0.w;
  p[4] = p1.x; p[5] = p1.y; p[6] = p1.z; p[7] = p1.w;
  p[8] = p2.x; p[9] = p2.y; p[10] = p2.z; p[11] = p2.w;
  p[12] = p3.x; p[13] = p3.y; p[14] = p3.z; p[15] = p3.w;
  float* orow = out + (size_t)trow * 1024 + half * 512;
  const int mb = half * 512;
  for (int m4 = 0; m4 < 512; m4 += 4) {
    float o[4];
#pragma unroll
    for (int e = 0; e < 4; ++e) {
      const int m = mb + m4 + e;
      float a = CFb[m];
#pragma unroll
      for (int jj = 0; jj < 16; ++jj) a += p[jj] * WF[jj][m];
      o[e] = a;
    }
    *(float4*)(orow + m4) = make_float4(o[0], o[1], o[2], o[3]);
  }
}

// =============================================================================
extern "C" void kernel_launch(void* const* d_in, const int* in_sizes, int n_in,
                              void* d_out, int out_size, void* d_ws, size_t ws_size,
                              hipStream_t stream) {
  (void)in_sizes; (void)n_in; (void)out_size; (void)ws_size;

  const float* src      = (const float*)d_in[0];
  const float* lan      = (const float*)d_in[1];
  const float* qmask    = (const float*)d_in[3];
  const float* ip_w     = (const float*)d_in[4];
  const float* ip_g     = (const float*)d_in[6];
  const float* ip_beta  = (const float*)d_in[7];
  const float* lp_w     = (const float*)d_in[8];
  const float* lp_b     = (const float*)d_in[9];
  const float* mem_tok  = (const float*)d_in[10];
  const float* neg_tok  = (const float*)d_in[11];
  const float* vl_qw    = (const float*)d_in[12];
  const float* vl_qb    = (const float*)d_in[13];
  const float* vl_kw    = (const float*)d_in[14];
  const float* vl_kb    = (const float*)d_in[15];
  const float* mf_qw    = (const float*)d_in[20];
  const float* mf_qb    = (const float*)d_in[21];
  const float* mf_kw    = (const float*)d_in[22];
  const float* mf_kb    = (const float*)d_in[23];
  const float* mf_vw    = (const float*)d_in[24];
  const float* mf_vb    = (const float*)d_in[25];
  const float* mf_ow    = (const float*)d_in[26];
  const float* mf_ob    = (const float*)d_in[27];
  const float* ff_qw    = (const float*)d_in[28];
  const float* ff_qb    = (const float*)d_in[29];
  const float* ff_kw    = (const float*)d_in[30];
  const float* ff_kb    = (const float*)d_in[31];
  const float* ff_vw    = (const float*)d_in[32];
  const float* ff_vb    = (const float*)d_in[33];
  const float* ff_ow    = (const float*)d_in[34];
  const float* ff_ob    = (const float*)d_in[35];
  const float* op_w     = (const float*)d_in[36];
  const float* op_g     = (const float*)d_in[38];
  const float* op_beta  = (const float*)d_in[39];

  float* out_final = (float*)d_out;
  float* out_cur   = out_final + 33554432ull;
  float* out_vl    = out_cur + 65536ull;
  float* out_mem   = out_vl + 16777216ull;
  float* out_ff    = out_mem + 16384ull;

  // ---- workspace carve ----
  char* wp = (char*)d_ws;
  auto take = [&](size_t sz) { char* r = wp; wp += (sz + 255) & ~(size_t)255; return r; };
  u16*   W1   = (u16*)  take(67108864);    // Q2 (vl q'')
  u16*   W2   = (u16*)  take(67108864);    // Y1 (pre-BN ip output), live to ff_score
  u16*   SB   = (u16*)  take(67108864);    // src bf16
  u16*   LP   = (u16*)  take(4194304);     // lan_p bf16
  u16*   QV   = (u16*)  take(4194304);     // vl q bf16
  u16*   KM   = (u16*)  take(4194304);     // mf k bf16
  u16*   VM   = (u16*)  take(4194304);     // mf v bf16
  u16*   LANB = (u16*)  take(3145728);     // lan bf16
  u16*   wip  = (u16*)  take(2097152);
  u16*   wlp  = (u16*)  take(1572864);
  u16*   wvq  = (u16*)  take(2097152);
  u16*   wmk  = (u16*)  take(2097152);
  u16*   wmv  = (u16*)  take(2097152);
  u16*   wop  = (u16*)  take(2097152);     // op_w bf16 [m][c]
  u16*   wvkT = (u16*)  take(2097152);     // vl_kw^T bf16
  u16*   wfoT = (u16*)  take(2097152);     // ff_ow^T bf16
  u16*   w2ff = (u16*)  take(1048576);     // folded ff-q weights [32][16][1024]
  u16*   U2b  = (u16*)  take(2097152);     // [32][32][1024] bf16
  float* qmf   = (float*)take(4096);
  float* attvm = (float*)take(131072);
  float* memo  = (float*)take(131072);
  float* curw  = (float*)take(262144);
  float* kff   = (float*)take(262144);
  float* vff   = (float*)take(262144);
  float* ps    = (float*)take(2097152);
  float* pq    = (float*)take(2097152);
  float2* st1  = (float2*)take(8192);
  float* afv   = (float*)take(4096);
  float* cfv   = (float*)take(4096);
  float* wcv   = (float*)take(4096);
  float* cff   = (float*)take(2048);
  float* S2    = (float*)take(2097152);    // [32][1024][16]
  float* Pbuf  = (float*)take(2097152);    // [32768][16]
  float* Ub    = (float*)take(2097152);    // [32][16][1024]
  float* W2opb = (float*)take(4194304);    // [32][32][1024] f32
  float* Gb    = (float*)take(32768);      // [32][256]
  float* pbarb = (float*)take(2048);       // [32][16]
  float* miw   = (float*)take(131072);     // [32][1024]
  float* rsiw  = (float*)take(131072);     // [32][1024]
  float* pmu   = (float*)take(32768);      // [8][1024]
  float* pe2   = (float*)take(32768);      // [8][1024]
  float* afin  = (float*)take(4096);
  float* cf0   = (float*)take(4096);

  const dim3 blk(256);

  // conversions
  f2b_kernel<<<dim3(32768), blk, 0, stream>>>(src, SB, 8388608);
  {
    F2B8 j;
    const float* ins[7] = {lan, ip_w, lp_w, vl_qw, mf_kw, mf_vw, op_w};
    u16* outs[7] = {LANB, wip, wlp, wvq, wmk, wmv, wop};
    int n4s[7] = {393216, 262144, 196608, 262144, 262144, 262144, 262144};
    for (int i = 0; i < 7; ++i) { j.in[i] = ins[i]; j.out[i] = outs[i]; j.n4[i] = n4s[i]; }
    f2b_multi<<<dim3(1024, 7), blk, 0, stream>>>(j);
  }
  wtrans<<<dim3(16, 16), blk, 0, stream>>>(vl_kw, wvkT);
  wtrans<<<dim3(16, 16), blk, 0, stream>>>(ff_ow, wfoT);

  // stage 0: input proj -> Y1 (W2); BN stats + fold vectors
  gemm_bt<<<dim3(8, 256), blk, 0, stream>>>(SB, wip, nullptr, W2, 32768, 1024, 1024);
  colstats_partial_b<<<dim3(256), blk, 0, stream>>>(W2, ps, pq);
  colstats_final<<<dim3(32), blk, 0, stream>>>(ps, pq, st1, ip_g, ip_beta, afv, cfv, 1.0f / 32768.0f);

  // lan proj + vl q proj
  gemm_bt<<<dim3(8, 16), blk, 0, stream>>>(LANB, wlp, lp_b, LP, 2048, 1024, 768);
  gemm_bt<<<dim3(8, 16), blk, 0, stream>>>(LP, wvq, vl_qb, QV, 2048, 1024, 1024);

  // stage 1 (vl, k-proj folded)
  gemm_qpp<<<dim3(8, 16, 8), blk, 0, stream>>>(QV, wvkT, afv, W1);
  small_gemm<<<dim3(4, 1), blk, 0, stream>>>(cfv, vl_kw, vl_kb, wcv, 1024, 1024);
  gemm_score_b<<<dim3(8, 4, 32), blk, 0, stream>>>(W1, W2, out_vl);
  vl_softmax<<<dim3(16384), blk, 0, stream>>>(out_vl, qmask, QV, wcv);

  // stage 2 (memory fuse)
  small_gemm<<<dim3(4, 1), blk, 0, stream>>>(mem_tok, mf_qw, mf_qb, qmf, 1024, 1024);
  gemm_bt<<<dim3(8, 16), blk, 0, stream>>>(LP, wmk, mf_kb, KM, 2048, 1024, 1024);
  gemm_bt<<<dim3(8, 16), blk, 0, stream>>>(LP, wmv, mf_vb, VM, 2048, 1024, 1024);
  mem_attn<<<dim3(32), blk, 0, stream>>>(qmf, KM, VM, qmask, out_mem, attvm);
  small_gemm<<<dim3(4, 32), blk, 0, stream>>>(attvm, mf_ow, mf_ob, memo, 1024, 1024);
  make_cur<<<dim3(128), blk, 0, stream>>>(neg_tok, memo, out_cur, curw);

  // stage 3 (feature fuse, fully rank-16 folded)
  small_gemm<<<dim3(4, 64), blk, 0, stream>>>(curw, ff_kw, ff_kb, kff, 1024, 1024);
  small_gemm<<<dim3(4, 64), blk, 0, stream>>>(curw, ff_vw, ff_vb, vff, 1024, 1024);
  ffw_fold<<<dim3(16, 32), blk, 0, stream>>>(kff, ff_qw, ff_qb, afv, cfv, w2ff, cff);
  ff_score<<<dim3(8, 32), blk, 0, stream>>>(W2, w2ff, cff, S2);
  ff_soft<<<dim3(128), blk, 0, stream>>>(S2, Pbuf, out_ff);
  pg_kernel<<<dim3(32), blk, 0, stream>>>(Pbuf, Gb, pbarb);
  ufold<<<dim3(16, 32), blk, 0, stream>>>(vff, wfoT, Ub);
  istats_a<<<dim3(32), blk, 0, stream>>>(Ub, Gb, pbarb, ff_ob, miw, rsiw);
  u2prep<<<dim3(32), blk, 0, stream>>>(Ub, miw, rsiw, ff_ob, U2b);
  w2op_gemm<<<dim3(8, 32), blk, 0, stream>>>(U2b, wop, W2opb);
  znstats_part<<<dim3(4, 8), blk, 0, stream>>>(W2opb, Gb, pbarb, pmu, pe2);
  znfin<<<dim3(4), blk, 0, stream>>>(pmu, pe2, op_g, op_beta, afin, cf0);
  zfinal<<<dim3(256), blk, 0, stream>>>(Pbuf, W2opb, afin, cf0, out_final);
}

// Round 8
// 750.032 us; speedup vs baseline: 1.4125x; 1.1349x over previous
//
#include <hip/hip_runtime.h>
#include <stdint.h>

#define EPS 1e-5f
#define SCALE 0.08838834764831845f  /* 1/sqrt(128) */

typedef __bf16 bf16x8 __attribute__((ext_vector_type(8)));
typedef float f32x4 __attribute__((ext_vector_type(4)));
typedef unsigned short u16;
typedef unsigned int u32;
typedef u16 u16x8 __attribute__((ext_vector_type(8)));

__device__ __forceinline__ u16 f2bf(float f) {
  union { float f; u32 u; } x; x.f = f;
  u32 r = x.u + 0x7fffu + ((x.u >> 16) & 1u);
  return (u16)(r >> 16);
}
__device__ __forceinline__ float bf2f(u16 u) {
  union { u32 u; float f; } x; x.u = ((u32)u) << 16; return x.f;
}
__device__ __forceinline__ void glds16(const void* g, void* l) {
  __builtin_amdgcn_global_load_lds((__attribute__((address_space(1))) void*)g,
                                   (__attribute__((address_space(3))) void*)l,
                                   16, 0, 0);
}

// ---------------- f32 -> bf16 convert (single big tensor) --------------------
__global__ __launch_bounds__(256) void f2b_kernel(const float* __restrict__ in,
                                                  u16* __restrict__ out, int n4) {
  int i = blockIdx.x * 256 + threadIdx.x;
  if (i >= n4) return;
  float4 v = ((const float4*)in)[i];
  ((ushort4*)out)[i] = make_ushort4(f2bf(v.x), f2bf(v.y), f2bf(v.z), f2bf(v.w));
}

// ---------------- f32 -> bf16 convert, up to 8 segments ----------------------
struct F2B8 {
  const float* in[8];
  u16* out[8];
  int n4[8];
};
__global__ __launch_bounds__(256) void f2b_multi(F2B8 j) {
  const int seg = blockIdx.y;
  const int n4 = j.n4[seg];
  const float* __restrict__ in = j.in[seg];
  u16* __restrict__ out = j.out[seg];
  for (int i = blockIdx.x * 256 + threadIdx.x; i < n4; i += gridDim.x * 256) {
    float4 v = ((const float4*)in)[i];
    ((ushort4*)out)[i] = make_ushort4(f2bf(v.x), f2bf(v.y), f2bf(v.z), f2bf(v.w));
  }
}

// ---------------- transpose weight: WT[m,n] = W[n,m], f32 -> bf16 ------------
__global__ __launch_bounds__(256)
void wtrans(const float* __restrict__ W, u16* __restrict__ WT) {
  __shared__ float tile[64][65];
  const int bx = blockIdx.x, by = blockIdx.y;   // 16 x 16 blocks of 64x64
  const int r = threadIdx.x >> 2, c0 = (threadIdx.x & 3) * 16;
  const float* src = W + (size_t)(by * 64 + r) * 1024 + bx * 64 + c0;
#pragma unroll
  for (int e = 0; e < 16; e += 4) {
    float4 v = *(const float4*)(src + e);
    tile[r][c0 + e] = v.x; tile[r][c0 + e + 1] = v.y;
    tile[r][c0 + e + 2] = v.z; tile[r][c0 + e + 3] = v.w;
  }
  __syncthreads();
  u16* dst = WT + (size_t)(bx * 64 + r) * 1024 + by * 64 + c0;
#pragma unroll
  for (int e = 0; e < 16; e += 4) {
    ushort4 o = make_ushort4(f2bf(tile[c0 + e][r]), f2bf(tile[c0 + e + 1][r]),
                             f2bf(tile[c0 + e + 2][r]), f2bf(tile[c0 + e + 3][r]));
    *(ushort4*)(dst + e) = o;
  }
}

// ---------------- 128x128 bf16 GEMM (BK=64, T1+T2): C=A@B^T (+bias) ----------
__global__ __launch_bounds__(256)
void gemm_bt(const u16* __restrict__ A, const u16* __restrict__ B,
             const float* __restrict__ bias, u16* __restrict__ Cb,
             int M, int N, int K) {
  __shared__ u16 sA[128 * 64];
  __shared__ u16 sB[128 * 64];
  const int nwg = (int)(gridDim.x * gridDim.y);
  const int chunk = nwg >> 3;
  int s = blockIdx.y * gridDim.x + blockIdx.x;
  int t = (s & 7) * chunk + (s >> 3);
  const int bn0 = (t & 7) * 128;
  const int bm0 = (t >> 3) * 128;
  const int tid = threadIdx.x;
  const int w = tid >> 6, l = tid & 63;
  const int wr = w >> 1, wc = w & 1;
  const int lr = l & 15, lk = l >> 4;
  const int swz = lr & 7;

  const int srow = tid >> 3;
  const int scol = ((tid & 7) ^ (srow & 7)) << 3;
  const u16* Ab = A + (size_t)(bm0 + srow) * K + scol;
  const u16* Bb = B + (size_t)(bn0 + srow) * K + scol;
  const size_t rstride32 = (size_t)32 * K;

  f32x4 acc[4][4] = {};

  for (int k0 = 0; k0 < K; k0 += 64) {
#pragma unroll
    for (int p = 0; p < 4; ++p) {
      glds16(Ab + p * rstride32 + k0, sA + p * 2048 + w * 512);
      glds16(Bb + p * rstride32 + k0, sB + p * 2048 + w * 512);
    }
    __syncthreads();
#pragma unroll
    for (int ks = 0; ks < 2; ++ks) {
      const int off = (((ks << 2) + lk) ^ swz) << 3;
      bf16x8 af[4], bfr[4];
#pragma unroll
      for (int m = 0; m < 4; ++m)
        af[m] = *(const bf16x8*)(sA + (wr * 64 + m * 16 + lr) * 64 + off);
#pragma unroll
      for (int n = 0; n < 4; ++n)
        bfr[n] = *(const bf16x8*)(sB + (wc * 64 + n * 16 + lr) * 64 + off);
#pragma unroll
      for (int m = 0; m < 4; ++m)
#pragma unroll
        for (int n = 0; n < 4; ++n)
          acc[m][n] = __builtin_amdgcn_mfma_f32_16x16x32_bf16(af[m], bfr[n], acc[m][n], 0, 0, 0);
    }
    __syncthreads();
  }

#pragma unroll
  for (int m = 0; m < 4; ++m) {
    const int grow0 = bm0 + wr * 64 + m * 16 + lk * 4;
#pragma unroll
    for (int n = 0; n < 4; ++n) {
      const int gcol = bn0 + wc * 64 + n * 16 + lr;
      const float bv = bias ? bias[gcol] : 0.0f;
#pragma unroll
      for (int i = 0; i < 4; ++i) {
        const float v = acc[m][n][i] + bv;
        Cb[(size_t)(grow0 + i) * N + gcol] = f2bf(v);
      }
    }
  }
}

// ---------------- q'' GEMM: Q2[b*512+h*64+i, m] = (QV[:,hs]@WT[:,hs]^T)*a[m] -
__global__ __launch_bounds__(256)
void gemm_qpp(const u16* __restrict__ QV, const u16* __restrict__ WT,
              const float* __restrict__ afv, u16* __restrict__ Q2) {
  __shared__ u16 sA[128 * 64];
  __shared__ u16 sB[128 * 64];
  const int h = blockIdx.z;
  int s = blockIdx.y * 8 + blockIdx.x;
  int t = (s & 7) * 16 + (s >> 3);
  const int bn0 = (t & 7) * 128;
  const int bm0 = (t >> 3) * 128;
  const int tid = threadIdx.x;
  const int w = tid >> 6, l = tid & 63;
  const int wr = w >> 1, wc = w & 1;
  const int lr = l & 15, lk = l >> 4;
  const int swz = lr & 7;

  const int srow = tid >> 3;
  const int scol = ((tid & 7) ^ (srow & 7)) << 3;
  const u16* Ab = QV + (size_t)(bm0 + srow) * 1024 + h * 128 + scol;
  const u16* Bb = WT + (size_t)(bn0 + srow) * 1024 + h * 128 + scol;
  const size_t rstride32 = (size_t)32 * 1024;

  f32x4 acc[4][4] = {};

  for (int k0 = 0; k0 < 128; k0 += 64) {
#pragma unroll
    for (int p = 0; p < 4; ++p) {
      glds16(Ab + p * rstride32 + k0, sA + p * 2048 + w * 512);
      glds16(Bb + p * rstride32 + k0, sB + p * 2048 + w * 512);
    }
    __syncthreads();
#pragma unroll
    for (int ks = 0; ks < 2; ++ks) {
      const int off = (((ks << 2) + lk) ^ swz) << 3;
      bf16x8 af[4], bfr[4];
#pragma unroll
      for (int m = 0; m < 4; ++m)
        af[m] = *(const bf16x8*)(sA + (wr * 64 + m * 16 + lr) * 64 + off);
#pragma unroll
      for (int n = 0; n < 4; ++n)
        bfr[n] = *(const bf16x8*)(sB + (wc * 64 + n * 16 + lr) * 64 + off);
#pragma unroll
      for (int m = 0; m < 4; ++m)
#pragma unroll
        for (int n = 0; n < 4; ++n)
          acc[m][n] = __builtin_amdgcn_mfma_f32_16x16x32_bf16(af[m], bfr[n], acc[m][n], 0, 0, 0);
    }
    __syncthreads();
  }

#pragma unroll
  for (int m = 0; m < 4; ++m) {
    const int grow0 = bm0 + wr * 64 + m * 16 + lk * 4;
#pragma unroll
    for (int n = 0; n < 4; ++n) {
      const int gcol = bn0 + wc * 64 + n * 16 + lr;
      const float a = afv[gcol];
#pragma unroll
      for (int i = 0; i < 4; ++i) {
        const int gr = grow0 + i;
        const int q2row = ((gr >> 6) << 9) + h * 64 + (gr & 63);
        Q2[(size_t)q2row * 1024 + gcol] = f2bf(acc[m][n][i] * a);
      }
    }
  }
}

// ---------------- batched vl-score GEMM: per b: S[512,1024] = Q2[b]@Y1[b]^T --
__global__ __launch_bounds__(256)
void gemm_score_b(const u16* __restrict__ Q2, const u16* __restrict__ Y1,
                  float* __restrict__ out) {
  __shared__ u16 sA[128 * 64];
  __shared__ u16 sB[128 * 64];
  int s = (int)((blockIdx.z * gridDim.y + blockIdx.y) * gridDim.x + blockIdx.x);
  int t = (s & 7) * 128 + (s >> 3);
  const int b = t >> 5;
  const int rem = t & 31;
  const int bn0 = (rem & 7) * 128;
  const int bm0 = (rem >> 3) * 128;
  const int tid = threadIdx.x;
  const int w = tid >> 6, l = tid & 63;
  const int wr = w >> 1, wc = w & 1;
  const int lr = l & 15, lk = l >> 4;
  const int swz = lr & 7;

  const int srow = tid >> 3;
  const int scol = ((tid & 7) ^ (srow & 7)) << 3;
  const u16* Ab = Q2 + (size_t)b * 524288 + (size_t)(bm0 + srow) * 1024 + scol;
  const u16* Bb = Y1 + (size_t)b * 1048576 + (size_t)(bn0 + srow) * 1024 + scol;
  const size_t rstride32 = (size_t)32 * 1024;

  f32x4 acc[4][4] = {};

  for (int k0 = 0; k0 < 1024; k0 += 64) {
#pragma unroll
    for (int p = 0; p < 4; ++p) {
      glds16(Ab + p * rstride32 + k0, sA + p * 2048 + w * 512);
      glds16(Bb + p * rstride32 + k0, sB + p * 2048 + w * 512);
    }
    __syncthreads();
#pragma unroll
    for (int ks = 0; ks < 2; ++ks) {
      const int off = (((ks << 2) + lk) ^ swz) << 3;
      bf16x8 af[4], bfr[4];
#pragma unroll
      for (int m = 0; m < 4; ++m)
        af[m] = *(const bf16x8*)(sA + (wr * 64 + m * 16 + lr) * 64 + off);
#pragma unroll
      for (int n = 0; n < 4; ++n)
        bfr[n] = *(const bf16x8*)(sB + (wc * 64 + n * 16 + lr) * 64 + off);
#pragma unroll
      for (int m = 0; m < 4; ++m)
#pragma unroll
        for (int n = 0; n < 4; ++n)
          acc[m][n] = __builtin_amdgcn_mfma_f32_16x16x32_bf16(af[m], bfr[n], acc[m][n], 0, 0, 0);
    }
    __syncthreads();
  }

  float* C = out + (size_t)b * 524288;
#pragma unroll
  for (int m = 0; m < 4; ++m) {
    const int grow0 = bm0 + wr * 64 + m * 16 + lk * 4;
#pragma unroll
    for (int n = 0; n < 4; ++n) {
      const int gcol = bn0 + wc * 64 + n * 16 + lr;
#pragma unroll
      for (int i = 0; i < 4; ++i)
        C[(size_t)(grow0 + i) * 1024 + gcol] = acc[m][n][i];
    }
  }
}

// ---------------- vl softmax (+folded const from QV·wc, query-mask scale) ----
__global__ __launch_bounds__(256)
void vl_softmax(float* __restrict__ S, const float* __restrict__ qmask,
                const u16* __restrict__ QV, const float* __restrict__ wcv) {
  __shared__ float red[4];
  __shared__ float red2[4];
  const int row = blockIdx.x;          // (b*8+h)*64+i
  const int b = row >> 9;
  const int h = (row >> 6) & 7;
  const int i = row & 63;
  const int t = threadIdx.x;
  float cp = 0.f;
  if (t < 128) cp = bf2f(QV[(size_t)(b * 64 + i) * 1024 + h * 128 + t]) * wcv[h * 128 + t];
  for (int o = 32; o > 0; o >>= 1) cp += __shfl_xor(cp, o, 64);
  if ((t & 63) == 0) red2[t >> 6] = cp;
  __syncthreads();
  const float cst = red2[0] + red2[1];
  const float scale = qmask[b * 64 + i] * SCALE;
  float* p = S + (size_t)row * 1024;
  float4 v = ((const float4*)p)[t];
  v.x = (v.x + cst) * scale; v.y = (v.y + cst) * scale;
  v.z = (v.z + cst) * scale; v.w = (v.w + cst) * scale;
  float mx = fmaxf(fmaxf(v.x, v.y), fmaxf(v.z, v.w));
  for (int o = 32; o > 0; o >>= 1) mx = fmaxf(mx, __shfl_xor(mx, o, 64));
  __syncthreads();
  if ((t & 63) == 0) red[t >> 6] = mx;
  __syncthreads();
  mx = fmaxf(fmaxf(red[0], red[1]), fmaxf(red[2], red[3]));
  const float e0 = expf(v.x - mx), e1 = expf(v.y - mx);
  const float e2 = expf(v.z - mx), e3 = expf(v.w - mx);
  float sm = e0 + e1 + e2 + e3;
  for (int o = 32; o > 0; o >>= 1) sm += __shfl_xor(sm, o, 64);
  __syncthreads();
  if ((t & 63) == 0) red[t >> 6] = sm;
  __syncthreads();
  sm = red[0] + red[1] + red[2] + red[3];
  const float inv = 1.0f / sm;
  ((float4*)p)[t] = make_float4(e0 * inv, e1 * inv, e2 * inv, e3 * inv);
}

// ---------------- column stats over bf16 [32768,1024] ------------------------
__global__ __launch_bounds__(256)
void colstats_partial_b(const u16* __restrict__ X, float* __restrict__ ps,
                        float* __restrict__ pq) {
  const int tid = threadIdx.x;
  const int chunk = blockIdx.x;
  const int colb = (tid & 127) * 8;
  const int rg = tid >> 7;
  const u16* p = X + ((size_t)chunk * 128 + rg * 64) * 1024 + colb;
  float s[8] = {}, q[8] = {};
  for (int r = 0; r < 64; ++r) {
    u16x8 v = *(const u16x8*)(p + (size_t)r * 1024);
#pragma unroll
    for (int j = 0; j < 8; ++j) {
      float f = bf2f(v[j]);
      s[j] += f; q[j] += f * f;
    }
  }
  float* dps = ps + (size_t)(chunk * 2 + rg) * 1024 + colb;
  float* dpq = pq + (size_t)(chunk * 2 + rg) * 1024 + colb;
  *(float4*)(dps) = make_float4(s[0], s[1], s[2], s[3]);
  *(float4*)(dps + 4) = make_float4(s[4], s[5], s[6], s[7]);
  *(float4*)(dpq) = make_float4(q[0], q[1], q[2], q[3]);
  *(float4*)(dpq + 4) = make_float4(q[4], q[5], q[6], q[7]);
}
// reduce 512 chunks -> stats + BN-fold vectors a, c
__global__ __launch_bounds__(256)
void colstats_final(const float* __restrict__ ps, const float* __restrict__ pq,
                    float2* __restrict__ st, const float* __restrict__ g,
                    const float* __restrict__ be, float* __restrict__ afv,
                    float* __restrict__ cfv, float inv_n) {
  __shared__ float rs_[8][32], rq_[8][32];
  const int cg = threadIdx.x >> 5, cl = threadIdx.x & 31;
  const int col = blockIdx.x * 32 + cl;
  float s = 0.f, q = 0.f;
  for (int i = 0; i < 64; ++i) {
    const size_t idx = (size_t)(cg * 64 + i) * 1024 + col;
    s += ps[idx]; q += pq[idx];
  }
  rs_[cg][cl] = s; rq_[cg][cl] = q;
  __syncthreads();
  if (cg == 0) {
    for (int i = 1; i < 8; ++i) { s += rs_[i][cl]; q += rq_[i][cl]; }
    const float m = s * inv_n;
    const float v = q * inv_n - m * m;
    const float rs = rsqrtf(v + EPS);
    st[col] = make_float2(m, rs);
    if (afv) {
      const float a = rs * g[col];
      afv[col] = a;
      cfv[col] = be[col] - m * a;
    }
  }
}

// ---------------- small f32 GEMM: out[m,n] = A[m,:]·W[n,:] + bias[n] ---------
__global__ __launch_bounds__(256)
void small_gemm(const float* __restrict__ A, const float* __restrict__ W,
                const float* __restrict__ bias, float* __restrict__ out,
                int N, int K) {
  __shared__ float sA[1024];
  const int m = blockIdx.y;
  const int n = blockIdx.x * 256 + threadIdx.x;
  for (int i = threadIdx.x; i < K; i += 256) sA[i] = A[(size_t)m * K + i];
  __syncthreads();
  const float4* w4 = (const float4*)(W + (size_t)n * K);
  const float4* a4 = (const float4*)sA;
  float acc = bias ? bias[n] : 0.0f;
  for (int k = 0; k < K / 4; ++k) {
    float4 wv = w4[k], av = a4[k];
    acc += av.x * wv.x + av.y * wv.y + av.z * wv.z + av.w * wv.w;
  }
  out[(size_t)m * N + n] = acc;
}

// ---------------- memory-fuse attention (per batch) --------------------------
__global__ __launch_bounds__(256)
void mem_attn(const float* __restrict__ qmf, const u16* __restrict__ KM,
              const u16* __restrict__ VM, const float* __restrict__ mask,
              float* __restrict__ att_out, float* __restrict__ attv_out) {
  __shared__ float qs[1024];
  __shared__ float sS[512];
  __shared__ float sP[512];
  __shared__ float sM[64];
  const int b = blockIdx.x;
  const int tid = threadIdx.x;
  for (int i = tid; i < 1024; i += 256) qs[i] = qmf[i];
  if (tid < 64) sM[tid] = mask[b * 64 + tid];
  __syncthreads();
  for (int p = tid; p < 512; p += 256) {
    const int h = p >> 6, j = p & 63;
    const u16* kr = KM + (size_t)(b * 64 + j) * 1024 + h * 128;
    float acc = 0.f;
    for (int d = 0; d < 128; ++d) acc += qs[h * 128 + d] * bf2f(kr[d]);
    sS[p] = acc * sM[j] * SCALE;
  }
  __syncthreads();
  if (tid < 8) {
    const int h = tid;
    float mx = -3.4e38f;
    for (int j = 0; j < 64; ++j) mx = fmaxf(mx, sS[h * 64 + j]);
    float sum = 0.f;
    for (int j = 0; j < 64; ++j) {
      float e = expf(sS[h * 64 + j] - mx);
      sP[h * 64 + j] = e; sum += e;
    }
    const float inv = 1.0f / sum;
    for (int j = 0; j < 64; ++j) {
      float pp = sP[h * 64 + j] * inv;
      sP[h * 64 + j] = pp;
      att_out[(size_t)(b * 8 + h) * 64 + j] = pp;
    }
  }
  __syncthreads();
  for (int c = tid; c < 1024; c += 256) {
    const int h = c >> 7;
    float acc = 0.f;
    for (int j = 0; j < 64; ++j)
      acc += sP[h * 64 + j] * sM[j] * bf2f(VM[(size_t)(b * 64 + j) * 1024 + c]);
    attv_out[(size_t)b * 1024 + c] = acc;
  }
}

// ---------------- cur = inorm(concat(neg_tok, mem_out)) ----------------------
__global__ __launch_bounds__(256)
void make_cur(const float* __restrict__ neg, const float* __restrict__ memo,
              float* __restrict__ cur_out, float* __restrict__ curw) {
  const int i = blockIdx.x * 256 + threadIdx.x;   // 32768
  const int b = i >> 10, c = i & 1023;
  const float a = neg[c], x = memo[i];
  const float mean = 0.5f * (a + x);
  const float d = a - mean;
  const float rs = rsqrtf(d * d + EPS);
  const float o0 = d * rs, o1 = -d * rs;
  cur_out[(size_t)(b * 2) * 1024 + c] = o0;
  cur_out[(size_t)(b * 2 + 1) * 1024 + c] = o1;
  curw[(size_t)(b * 2) * 1024 + c] = o0;
  curw[(size_t)(b * 2 + 1) * 1024 + c] = o1;
}

// ---------------- ff fold: w''[b,j,h,:] and const_ff[b,j,h] ------------------
__global__ __launch_bounds__(256)
void ffw_fold(const float* __restrict__ kff, const float* __restrict__ wfq,
              const float* __restrict__ qb, const float* __restrict__ afv,
              const float* __restrict__ cfv, u16* __restrict__ w2ff,
              float* __restrict__ cff) {
  __shared__ float redl[4];
  const int b = blockIdx.y, jh = blockIdx.x;
  const int j = jh >> 3, h = jh & 7;
  const int tid = threadIdx.x;
  const int m0 = tid * 4;
  const float* kp = kff + (size_t)b * 2048 + j * 1024 + h * 128;
  float a0 = 0, a1 = 0, a2 = 0, a3 = 0;
  for (int n = 0; n < 128; ++n) {
    const float kv = kp[n];
    const float4 wv = *(const float4*)(wfq + (size_t)(h * 128 + n) * 1024 + m0);
    a0 += kv * wv.x; a1 += kv * wv.y; a2 += kv * wv.z; a3 += kv * wv.w;
  }
  float cpart = a0 * cfv[m0] + a1 * cfv[m0 + 1] + a2 * cfv[m0 + 2] + a3 * cfv[m0 + 3];
  if (tid < 128) cpart += qb[h * 128 + tid] * kp[tid];
  ushort4 o = make_ushort4(f2bf(a0 * afv[m0]), f2bf(a1 * afv[m0 + 1]),
                           f2bf(a2 * afv[m0 + 2]), f2bf(a3 * afv[m0 + 3]));
  *(ushort4*)(w2ff + (size_t)(b * 16 + jh) * 1024 + m0) = o;
  for (int o2 = 32; o2 > 0; o2 >>= 1) cpart += __shfl_xor(cpart, o2, 64);
  if ((tid & 63) == 0) redl[tid >> 6] = cpart;
  __syncthreads();
  if (tid == 0) cff[b * 16 + jh] = redl[0] + redl[1] + redl[2] + redl[3];
}

// ---------------- ff score: S2[b,t,jh] = Y1[b,t,:]·w''[b,jh,:] + cff ---------
__global__ __launch_bounds__(256)
void ff_score(const u16* __restrict__ Y1, const u16* __restrict__ w2ff,
              const float* __restrict__ cff, float* __restrict__ S2) {
  __shared__ u16 sA[128 * 64];
  __shared__ u16 sB[16 * 1024];
  const int chunk = blockIdx.x, b = blockIdx.y;
  const int tid = threadIdx.x;
  const int w = tid >> 6, l = tid & 63;
  const int lr = l & 15, lk = l >> 4;
  const int swz = lr & 7;

  {
    const int n = tid >> 4;
    const int sb = (tid & 15) * 8;
#pragma unroll
    for (int v = 0; v < 8; ++v) {
      const int sidx = sb + v;
      u16x8 val = *(const u16x8*)(w2ff + (size_t)(b * 16 + n) * 1024 + sidx * 8);
      *(u16x8*)(sB + n * 1024 + ((sidx ^ (n & 7)) << 3)) = val;
    }
  }

  const int srow = tid >> 3;
  const int scol = ((tid & 7) ^ (srow & 7)) << 3;
  const u16* Ab = Y1 + ((size_t)(b * 1024 + chunk * 128) + srow) * 1024 + scol;
  const size_t rstride32 = (size_t)32 * 1024;

  f32x4 acc[2] = {};

  for (int k0 = 0; k0 < 1024; k0 += 64) {
#pragma unroll
    for (int p = 0; p < 4; ++p)
      glds16(Ab + p * rstride32 + k0, sA + p * 2048 + w * 512);
    __syncthreads();
#pragma unroll
    for (int ks = 0; ks < 2; ++ks) {
      const int off = (((ks << 2) + lk) ^ swz) << 3;
      bf16x8 a0 = *(const bf16x8*)(sA + (w * 32 + lr) * 64 + off);
      bf16x8 a1 = *(const bf16x8*)(sA + (w * 32 + 16 + lr) * 64 + off);
      const int bs = (k0 >> 3) + (ks << 2) + lk;
      bf16x8 bf_ = *(const bf16x8*)(sB + lr * 1024 + ((bs ^ swz) << 3));
      acc[0] = __builtin_amdgcn_mfma_f32_16x16x32_bf16(a0, bf_, acc[0], 0, 0, 0);
      acc[1] = __builtin_amdgcn_mfma_f32_16x16x32_bf16(a1, bf_, acc[1], 0, 0, 0);
    }
    __syncthreads();
  }

  const float cadd = cff[b * 16 + lr];
#pragma unroll
  for (int m = 0; m < 2; ++m)
#pragma unroll
    for (int i = 0; i < 4; ++i) {
      const int trow = chunk * 128 + w * 32 + m * 16 + lk * 4 + i;
      S2[((size_t)b * 1024 + trow) * 16 + lr] = acc[m][i] + cadd;
    }
}

// ---------------- ff softmax -> P[32768][16] f32 + att output ----------------
__global__ __launch_bounds__(256)
void ff_soft(const float* __restrict__ S2, float* __restrict__ P,
             float* __restrict__ att_out) {
  const int t = blockIdx.x * 256 + threadIdx.x;  // 0..32767
  const int b = t >> 10, tl = t & 1023;
  const float* srow = S2 + (size_t)t * 16;
  float4 s0 = *(const float4*)(srow);
  float4 s1 = *(const float4*)(srow + 4);
  float4 s2 = *(const float4*)(srow + 8);
  float4 s3 = *(const float4*)(srow + 12);
  float sj0[8] = {s0.x, s0.y, s0.z, s0.w, s1.x, s1.y, s1.z, s1.w};
  float sj1[8] = {s2.x, s2.y, s2.z, s2.w, s3.x, s3.y, s3.z, s3.w};
  float p0[8], p1[8];
#pragma unroll
  for (int h = 0; h < 8; ++h) {
    const float a0 = sj0[h] * SCALE, a1 = sj1[h] * SCALE;
    const float mx = fmaxf(a0, a1);
    const float e0 = expf(a0 - mx), e1 = expf(a1 - mx);
    const float inv = 1.f / (e0 + e1);
    p0[h] = e0 * inv; p1[h] = e1 * inv;
    float* o = att_out + ((size_t)(b * 8 + h) * 1024 + tl) * 2;
    o[0] = p0[h]; o[1] = p1[h];
  }
  float* pr = P + (size_t)t * 16;
  *(float4*)(pr)      = make_float4(p0[0], p0[1], p0[2], p0[3]);
  *(float4*)(pr + 4)  = make_float4(p0[4], p0[5], p0[6], p0[7]);
  *(float4*)(pr + 8)  = make_float4(p1[0], p1[1], p1[2], p1[3]);
  *(float4*)(pr + 12) = make_float4(p1[4], p1[5], p1[6], p1[7]);
}

// ---------------- pbar[b][16] = mean_t P; G[b][16][16] = (1/T) P^T P ---------
__global__ __launch_bounds__(256)
void pg_kernel(const float* __restrict__ P, float* __restrict__ G,
               float* __restrict__ pbar) {
  __shared__ float Pl[128][16];
  const int b = blockIdx.x;
  const int tid = threadIdx.x;
  const int j = tid >> 4, j2 = tid & 15;
  float acc = 0.f, accp = 0.f;
  for (int c = 0; c < 8; ++c) {
    __syncthreads();
    for (int i = tid; i < 2048; i += 256)
      Pl[i >> 4][i & 15] = P[((size_t)b * 1024 + c * 128 + (i >> 4)) * 16 + (i & 15)];
    __syncthreads();
    for (int t = 0; t < 128; ++t) {
      acc += Pl[t][j] * Pl[t][j2];
      if (j == 0) accp += Pl[t][j2];
    }
  }
  G[b * 256 + tid] = acc * (1.f / 1024.f);
  if (j == 0) pbar[b * 16 + j2] = accp * (1.f / 1024.f);
}

// ---------------- U[b][jh][m] = sum_d vff[b,j,h*128+d] * wfo[m,h*128+d] ------
__global__ __launch_bounds__(256)
void ufold(const float* __restrict__ vff, const u16* __restrict__ wfoT,
           float* __restrict__ U) {
  const int b = blockIdx.y, jh = blockIdx.x;
  const int j = jh >> 3, h = jh & 7;
  const int m0 = threadIdx.x * 4;
  const float* vp = vff + (size_t)b * 2048 + j * 1024 + h * 128;
  float a0 = 0, a1 = 0, a2 = 0, a3 = 0;
  for (int d = 0; d < 128; ++d) {
    const float kv = vp[d];
    ushort4 wv = *(const ushort4*)(wfoT + (size_t)(h * 128 + d) * 1024 + m0);
    a0 += kv * bf2f(wv.x); a1 += kv * bf2f(wv.y);
    a2 += kv * bf2f(wv.z); a3 += kv * bf2f(wv.w);
  }
  *(float4*)(U + (size_t)(b * 16 + jh) * 1024 + m0) = make_float4(a0, a1, a2, a3);
}

// ---------------- analytic instance-norm stats of ff_out ---------------------
__global__ __launch_bounds__(256)
void istats_a(const float* __restrict__ U, const float* __restrict__ G,
              const float* __restrict__ pbar, const float* __restrict__ ob,
              float* __restrict__ mi, float* __restrict__ rsi) {
  __shared__ float Gs[256], pb[16];
  const int b = blockIdx.x;
  const int tid = threadIdx.x;
  Gs[tid] = G[b * 256 + tid];
  if (tid < 16) pb[tid] = pbar[b * 16 + tid];
  __syncthreads();
#pragma unroll
  for (int e = 0; e < 4; ++e) {
    const int m = tid * 4 + e;
    float u[16];
#pragma unroll
    for (int jj = 0; jj < 16; ++jj) u[jj] = U[(size_t)(b * 16 + jj) * 1024 + m];
    const float o = ob[m];
    float s1 = 0.f;
#pragma unroll
    for (int jj = 0; jj < 16; ++jj) s1 += pb[jj] * u[jj];
    float q = 0.f;
#pragma unroll
    for (int jj = 0; jj < 16; ++jj) {
      float gq = 0.f;
#pragma unroll
      for (int j2 = 0; j2 < 16; ++j2) gq += Gs[jj * 16 + j2] * u[j2];
      q += u[jj] * gq;
    }
    const float mean = s1 + o;
    const float e2 = q + 2.f * o * s1 + o * o;
    const float var = fmaxf(e2 - mean * mean, 0.f);
    mi[b * 1024 + m] = mean;
    rsi[b * 1024 + m] = rsqrtf(var + EPS);
  }
}

// ---------------- U2b[b][32][1024] bf16: rows 0-15 U*rsi, 16 = (ob-mi)*rsi ---
__global__ __launch_bounds__(256)
void u2prep(const float* __restrict__ U, const float* __restrict__ mi,
            const float* __restrict__ rsi, const float* __restrict__ ob,
            u16* __restrict__ U2b) {
  const int b = blockIdx.x;
  const int m0 = threadIdx.x * 4;
  float4 rs4 = *(const float4*)(rsi + b * 1024 + m0);
  const float rr[4] = {rs4.x, rs4.y, rs4.z, rs4.w};
#pragma unroll
  for (int jj = 0; jj < 16; ++jj) {
    float4 u4 = *(const float4*)(U + (size_t)(b * 16 + jj) * 1024 + m0);
    ushort4 o = make_ushort4(f2bf(u4.x * rr[0]), f2bf(u4.y * rr[1]),
                             f2bf(u4.z * rr[2]), f2bf(u4.w * rr[3]));
    *(ushort4*)(U2b + (size_t)(b * 32 + jj) * 1024 + m0) = o;
  }
  float4 mi4 = *(const float4*)(mi + b * 1024 + m0);
  float4 ob4 = *(const float4*)(ob + m0);
  ushort4 od = make_ushort4(
      f2bf((ob4.x - mi4.x) * rr[0]), f2bf((ob4.y - mi4.y) * rr[1]),
      f2bf((ob4.z - mi4.z) * rr[2]), f2bf((ob4.w - mi4.w) * rr[3]));
  *(ushort4*)(U2b + (size_t)(b * 32 + 16) * 1024 + m0) = od;
  ushort4 z = make_ushort4(0, 0, 0, 0);
#pragma unroll
  for (int jj = 17; jj < 32; ++jj)
    *(ushort4*)(U2b + (size_t)(b * 32 + jj) * 1024 + m0) = z;
}

// ---------------- W2op[b][32][1024] = U2b[b] @ wop^T (MFMA, M=32) ------------
__global__ __launch_bounds__(256)
void w2op_gemm(const u16* __restrict__ U2b, const u16* __restrict__ wop,
               float* __restrict__ W2op) {
  __shared__ u16 sA[32 * 64];
  __shared__ u16 sB[128 * 64];
  const int b = blockIdx.y;
  const int bn0 = blockIdx.x * 128;
  const int tid = threadIdx.x;
  const int w = tid >> 6, l = tid & 63;
  const int lr = l & 15, lk = l >> 4;
  const int swz = lr & 7;
  const int srow = tid >> 3;
  const int scol = ((tid & 7) ^ (srow & 7)) << 3;
  const u16* Ab = U2b + (size_t)b * 32768 + (size_t)srow * 1024 + scol;
  const u16* Bb = wop + (size_t)(bn0 + srow) * 1024 + scol;
  const size_t rstride32 = (size_t)32 * 1024;

  f32x4 acc[2][2] = {};
  for (int k0 = 0; k0 < 1024; k0 += 64) {
    glds16(Ab + k0, sA + w * 512);
#pragma unroll
    for (int p = 0; p < 4; ++p)
      glds16(Bb + p * rstride32 + k0, sB + p * 2048 + w * 512);
    __syncthreads();
#pragma unroll
    for (int ks = 0; ks < 2; ++ks) {
      const int off = (((ks << 2) + lk) ^ swz) << 3;
      bf16x8 af[2], bfr[2];
#pragma unroll
      for (int m = 0; m < 2; ++m)
        af[m] = *(const bf16x8*)(sA + (m * 16 + lr) * 64 + off);
#pragma unroll
      for (int n = 0; n < 2; ++n)
        bfr[n] = *(const bf16x8*)(sB + (w * 32 + n * 16 + lr) * 64 + off);
#pragma unroll
      for (int m = 0; m < 2; ++m)
#pragma unroll
        for (int n = 0; n < 2; ++n)
          acc[m][n] = __builtin_amdgcn_mfma_f32_16x16x32_bf16(af[m], bfr[n], acc[m][n], 0, 0, 0);
    }
    __syncthreads();
  }
#pragma unroll
  for (int m = 0; m < 2; ++m)
#pragma unroll
    for (int n = 0; n < 2; ++n)
#pragma unroll
      for (int i = 0; i < 4; ++i) {
        const int row = m * 16 + lk * 4 + i;
        const int col = bn0 + w * 32 + n * 16 + lr;
        W2op[((size_t)b * 32 + row) * 1024 + col] = acc[m][n][i];
      }
}

// ---------------- analytic BN stats of Z (partials over b-groups) ------------
__global__ __launch_bounds__(256)
void znstats_part(const float* __restrict__ W2op, const float* __restrict__ G,
                  const float* __restrict__ pbar, float* __restrict__ pmu,
                  float* __restrict__ pe2) {
  __shared__ float Gs[256], pb[16];
  const int m = blockIdx.x * 256 + threadIdx.x;
  const int bg = blockIdx.y;
  float amu = 0.f, ae2 = 0.f;
  for (int bi = 0; bi < 4; ++bi) {
    const int b = bg * 4 + bi;
    __syncthreads();
    Gs[threadIdx.x] = G[b * 256 + threadIdx.x];
    if (threadIdx.x < 16) pb[threadIdx.x] = pbar[b * 16 + threadIdx.x];
    __syncthreads();
    float wv[17];
#pragma unroll
    for (int jj = 0; jj < 17; ++jj) wv[jj] = W2op[((size_t)b * 32 + jj) * 1024 + m];
    float s1 = 0.f;
#pragma unroll
    for (int jj = 0; jj < 16; ++jj) s1 += pb[jj] * wv[jj];
    float q = 0.f;
#pragma unroll
    for (int jj = 0; jj < 16; ++jj) {
      float gq = 0.f;
#pragma unroll
      for (int j2 = 0; j2 < 16; ++j2) gq += Gs[jj * 16 + j2] * wv[j2];
      q += wv[jj] * gq;
    }
    const float cz = wv[16];
    amu += s1 + cz;
    ae2 += q + 2.f * cz * s1 + cz * cz;
  }
  pmu[bg * 1024 + m] = amu;
  pe2[bg * 1024 + m] = ae2;
}

__global__ __launch_bounds__(256)
void znfin(const float* __restrict__ pmu, const float* __restrict__ pe2,
           const float* __restrict__ g, const float* __restrict__ be,
           float* __restrict__ afin, float* __restrict__ cf0) {
  const int m = blockIdx.x * 256 + threadIdx.x;
  float mu = 0.f, e2 = 0.f;
#pragma unroll
  for (int i = 0; i < 8; ++i) { mu += pmu[i * 1024 + m]; e2 += pe2[i * 1024 + m]; }
  mu *= (1.f / 32.f); e2 *= (1.f / 32.f);
  const float var = fmaxf(e2 - mu * mu, 0.f);
  const float A = rsqrtf(var + EPS) * g[m];
  afin[m] = A;
  cf0[m] = be[m] - mu * A;
}

// ---------------- final: out[t,m] = sum_j P[t,j]*W2op[b][j,m]*A[m] + const ---
// v2: coalesced wave writes (lane l writes col chunk*256+l*4), P staged in LDS,
// 2 rows per inner iteration (halves LDS read traffic). grid (16 tc, 32 b);
// block handles 64 rows; wave w owns rows [w*16, w*16+16).
__global__ __launch_bounds__(256)
void zfinal(const float* __restrict__ P, const float* __restrict__ W2op,
            const float* __restrict__ afin, const float* __restrict__ cf0,
            float* __restrict__ out) {
  __shared__ float WF[17][1024];
  __shared__ float PL[64][16];
  const int tc = blockIdx.x;
  const int b = blockIdx.y;
  const int tid = threadIdx.x;
  for (int i = tid; i < 1024; i += 256) {
    const float A = afin[i];
    WF[16][i] = W2op[((size_t)b * 32 + 16) * 1024 + i] * A + cf0[i];
#pragma unroll
    for (int jj = 0; jj < 16; ++jj)
      WF[jj][i] = W2op[((size_t)b * 32 + jj) * 1024 + i] * A;
  }
  for (int i = tid; i < 1024; i += 256)
    PL[i >> 4][i & 15] = P[((size_t)(b * 1024 + tc * 64) + (i >> 4)) * 16 + (i & 15)];
  __syncthreads();
  const int w = tid >> 6, l = tid & 63;
  float* obase = out + ((size_t)b * 1024 + tc * 64) * 1024;
  for (int r = 0; r < 16; r += 2) {
    const int row0 = w * 16 + r;
    float p0[16], p1[16];
#pragma unroll
    for (int j = 0; j < 16; ++j) { p0[j] = PL[row0][j]; p1[j] = PL[row0 + 1][j]; }
#pragma unroll
    for (int c = 0; c < 4; ++c) {
      const int col = c * 256 + l * 4;
      f32x4 base = *(const f32x4*)&WF[16][col];
      f32x4 a0 = base, a1 = base;
#pragma unroll
      for (int j = 0; j < 16; ++j) {
        f32x4 wv = *(const f32x4*)&WF[j][col];
        a0 += p0[j] * wv;
        a1 += p1[j] * wv;
      }
      *(f32x4*)(obase + (size_t)row0 * 1024 + col) = a0;
      *(f32x4*)(obase + (size_t)(row0 + 1) * 1024 + col) = a1;
    }
  }
}

// =============================================================================
extern "C" void kernel_launch(void* const* d_in, const int* in_sizes, int n_in,
                              void* d_out, int out_size, void* d_ws, size_t ws_size,
                              hipStream_t stream) {
  (void)in_sizes; (void)n_in; (void)out_size; (void)ws_size;

  const float* src      = (const float*)d_in[0];
  const float* lan      = (const float*)d_in[1];
  const float* qmask    = (const float*)d_in[3];
  const float* ip_w     = (const float*)d_in[4];
  const float* ip_g     = (const float*)d_in[6];
  const float* ip_beta  = (const float*)d_in[7];
  const float* lp_w     = (const float*)d_in[8];
  const float* lp_b     = (const float*)d_in[9];
  const float* mem_tok  = (const float*)d_in[10];
  const float* neg_tok  = (const float*)d_in[11];
  const float* vl_qw    = (const float*)d_in[12];
  const float* vl_qb    = (const float*)d_in[13];
  const float* vl_kw    = (const float*)d_in[14];
  const float* vl_kb    = (const float*)d_in[15];
  const float* mf_qw    = (const float*)d_in[20];
  const float* mf_qb    = (const float*)d_in[21];
  const float* mf_kw    = (const float*)d_in[22];
  const float* mf_kb    = (const float*)d_in[23];
  const float* mf_vw    = (const float*)d_in[24];
  const float* mf_vb    = (const float*)d_in[25];
  const float* mf_ow    = (const float*)d_in[26];
  const float* mf_ob    = (const float*)d_in[27];
  const float* ff_qw    = (const float*)d_in[28];
  const float* ff_qb    = (const float*)d_in[29];
  const float* ff_kw    = (const float*)d_in[30];
  const float* ff_kb    = (const float*)d_in[31];
  const float* ff_vw    = (const float*)d_in[32];
  const float* ff_vb    = (const float*)d_in[33];
  const float* ff_ow    = (const float*)d_in[34];
  const float* ff_ob    = (const float*)d_in[35];
  const float* op_w     = (const float*)d_in[36];
  const float* op_g     = (const float*)d_in[38];
  const float* op_beta  = (const float*)d_in[39];

  float* out_final = (float*)d_out;
  float* out_cur   = out_final + 33554432ull;
  float* out_vl    = out_cur + 65536ull;
  float* out_mem   = out_vl + 16777216ull;
  float* out_ff    = out_mem + 16384ull;

  // ---- workspace carve ----
  char* wp = (char*)d_ws;
  auto take = [&](size_t sz) { char* r = wp; wp += (sz + 255) & ~(size_t)255; return r; };
  u16*   W1   = (u16*)  take(67108864);    // Q2 (vl q'')
  u16*   W2   = (u16*)  take(67108864);    // Y1 (pre-BN ip output), live to ff_score
  u16*   SB   = (u16*)  take(67108864);    // src bf16
  u16*   LP   = (u16*)  take(4194304);     // lan_p bf16
  u16*   QV   = (u16*)  take(4194304);     // vl q bf16
  u16*   KM   = (u16*)  take(4194304);     // mf k bf16
  u16*   VM   = (u16*)  take(4194304);     // mf v bf16
  u16*   LANB = (u16*)  take(3145728);     // lan bf16
  u16*   wip  = (u16*)  take(2097152);
  u16*   wlp  = (u16*)  take(1572864);
  u16*   wvq  = (u16*)  take(2097152);
  u16*   wmk  = (u16*)  take(2097152);
  u16*   wmv  = (u16*)  take(2097152);
  u16*   wop  = (u16*)  take(2097152);     // op_w bf16 [m][c]
  u16*   wvkT = (u16*)  take(2097152);     // vl_kw^T bf16
  u16*   wfoT = (u16*)  take(2097152);     // ff_ow^T bf16
  u16*   w2ff = (u16*)  take(1048576);     // folded ff-q weights [32][16][1024]
  u16*   U2b  = (u16*)  take(2097152);     // [32][32][1024] bf16
  float* qmf   = (float*)take(4096);
  float* attvm = (float*)take(131072);
  float* memo  = (float*)take(131072);
  float* curw  = (float*)take(262144);
  float* kff   = (float*)take(262144);
  float* vff   = (float*)take(262144);
  float* ps    = (float*)take(2097152);
  float* pq    = (float*)take(2097152);
  float2* st1  = (float2*)take(8192);
  float* afv   = (float*)take(4096);
  float* cfv   = (float*)take(4096);
  float* wcv   = (float*)take(4096);
  float* cff   = (float*)take(2048);
  float* S2    = (float*)take(2097152);    // [32][1024][16]
  float* Pbuf  = (float*)take(2097152);    // [32768][16]
  float* Ub    = (float*)take(2097152);    // [32][16][1024]
  float* W2opb = (float*)take(4194304);    // [32][32][1024] f32
  float* Gb    = (float*)take(32768);      // [32][256]
  float* pbarb = (float*)take(2048);       // [32][16]
  float* miw   = (float*)take(131072);     // [32][1024]
  float* rsiw  = (float*)take(131072);     // [32][1024]
  float* pmu   = (float*)take(32768);      // [8][1024]
  float* pe2   = (float*)take(32768);      // [8][1024]
  float* afin  = (float*)take(4096);
  float* cf0   = (float*)take(4096);

  const dim3 blk(256);

  // conversions
  f2b_kernel<<<dim3(32768), blk, 0, stream>>>(src, SB, 8388608);
  {
    F2B8 j;
    const float* ins[7] = {lan, ip_w, lp_w, vl_qw, mf_kw, mf_vw, op_w};
    u16* outs[7] = {LANB, wip, wlp, wvq, wmk, wmv, wop};
    int n4s[7] = {393216, 262144, 196608, 262144, 262144, 262144, 262144};
    for (int i = 0; i < 7; ++i) { j.in[i] = ins[i]; j.out[i] = outs[i]; j.n4[i] = n4s[i]; }
    f2b_multi<<<dim3(1024, 7), blk, 0, stream>>>(j);
  }
  wtrans<<<dim3(16, 16), blk, 0, stream>>>(vl_kw, wvkT);
  wtrans<<<dim3(16, 16), blk, 0, stream>>>(ff_ow, wfoT);

  // stage 0: input proj -> Y1 (W2); BN stats + fold vectors
  gemm_bt<<<dim3(8, 256), blk, 0, stream>>>(SB, wip, nullptr, W2, 32768, 1024, 1024);
  colstats_partial_b<<<dim3(256), blk, 0, stream>>>(W2, ps, pq);
  colstats_final<<<dim3(32), blk, 0, stream>>>(ps, pq, st1, ip_g, ip_beta, afv, cfv, 1.0f / 32768.0f);

  // lan proj + vl q proj
  gemm_bt<<<dim3(8, 16), blk, 0, stream>>>(LANB, wlp, lp_b, LP, 2048, 1024, 768);
  gemm_bt<<<dim3(8, 16), blk, 0, stream>>>(LP, wvq, vl_qb, QV, 2048, 1024, 1024);

  // stage 1 (vl, k-proj folded)
  gemm_qpp<<<dim3(8, 16, 8), blk, 0, stream>>>(QV, wvkT, afv, W1);
  small_gemm<<<dim3(4, 1), blk, 0, stream>>>(cfv, vl_kw, vl_kb, wcv, 1024, 1024);
  gemm_score_b<<<dim3(8, 4, 32), blk, 0, stream>>>(W1, W2, out_vl);
  vl_softmax<<<dim3(16384), blk, 0, stream>>>(out_vl, qmask, QV, wcv);

  // stage 2 (memory fuse)
  small_gemm<<<dim3(4, 1), blk, 0, stream>>>(mem_tok, mf_qw, mf_qb, qmf, 1024, 1024);
  gemm_bt<<<dim3(8, 16), blk, 0, stream>>>(LP, wmk, mf_kb, KM, 2048, 1024, 1024);
  gemm_bt<<<dim3(8, 16), blk, 0, stream>>>(LP, wmv, mf_vb, VM, 2048, 1024, 1024);
  mem_attn<<<dim3(32), blk, 0, stream>>>(qmf, KM, VM, qmask, out_mem, attvm);
  small_gemm<<<dim3(4, 32), blk, 0, stream>>>(attvm, mf_ow, mf_ob, memo, 1024, 1024);
  make_cur<<<dim3(128), blk, 0, stream>>>(neg_tok, memo, out_cur, curw);

  // stage 3 (feature fuse, fully rank-16 folded)
  small_gemm<<<dim3(4, 64), blk, 0, stream>>>(curw, ff_kw, ff_kb, kff, 1024, 1024);
  small_gemm<<<dim3(4, 64), blk, 0, stream>>>(curw, ff_vw, ff_vb, vff, 1024, 1024);
  ffw_fold<<<dim3(16, 32), blk, 0, stream>>>(kff, ff_qw, ff_qb, afv, cfv, w2ff, cff);
  ff_score<<<dim3(8, 32), blk, 0, stream>>>(W2, w2ff, cff, S2);
  ff_soft<<<dim3(128), blk, 0, stream>>>(S2, Pbuf, out_ff);
  pg_kernel<<<dim3(32), blk, 0, stream>>>(Pbuf, Gb, pbarb);
  ufold<<<dim3(16, 32), blk, 0, stream>>>(vff, wfoT, Ub);
  istats_a<<<dim3(32), blk, 0, stream>>>(Ub, Gb, pbarb, ff_ob, miw, rsiw);
  u2prep<<<dim3(32), blk, 0, stream>>>(Ub, miw, rsiw, ff_ob, U2b);
  w2op_gemm<<<dim3(8, 32), blk, 0, stream>>>(U2b, wop, W2opb);
  znstats_part<<<dim3(4, 8), blk, 0, stream>>>(W2opb, Gb, pbarb, pmu, pe2);
  znfin<<<dim3(4), blk, 0, stream>>>(pmu, pe2, op_g, op_beta, afin, cf0);
  zfinal<<<dim3(16, 32), blk, 0, stream>>>(Pbuf, W2opb, afin, cf0, out_final);
}

// Round 9
// 740.049 us; speedup vs baseline: 1.4316x; 1.0135x over previous
//
#include <hip/hip_runtime.h>
#include <stdint.h>

#define EPS 1e-5f
#define SCALE 0.08838834764831845f  /* 1/sqrt(128) */

typedef __bf16 bf16x8 __attribute__((ext_vector_type(8)));
typedef float f32x4 __attribute__((ext_vector_type(4)));
typedef unsigned short u16;
typedef unsigned int u32;
typedef u16 u16x8 __attribute__((ext_vector_type(8)));

__device__ __forceinline__ u16 f2bf(float f) {
  union { float f; u32 u; } x; x.f = f;
  u32 r = x.u + 0x7fffu + ((x.u >> 16) & 1u);
  return (u16)(r >> 16);
}
__device__ __forceinline__ float bf2f(u16 u) {
  union { u32 u; float f; } x; x.u = ((u32)u) << 16; return x.f;
}
__device__ __forceinline__ void glds16(const void* g, void* l) {
  __builtin_amdgcn_global_load_lds((__attribute__((address_space(1))) void*)g,
                                   (__attribute__((address_space(3))) void*)l,
                                   16, 0, 0);
}

// ---------------- f32 -> bf16 convert (single big tensor) --------------------
__global__ __launch_bounds__(256) void f2b_kernel(const float* __restrict__ in,
                                                  u16* __restrict__ out, int n4) {
  int i = blockIdx.x * 256 + threadIdx.x;
  if (i >= n4) return;
  float4 v = ((const float4*)in)[i];
  ((ushort4*)out)[i] = make_ushort4(f2bf(v.x), f2bf(v.y), f2bf(v.z), f2bf(v.w));
}

// ---------------- f32 -> bf16 convert, up to 8 segments ----------------------
struct F2B8 {
  const float* in[8];
  u16* out[8];
  int n4[8];
};
__global__ __launch_bounds__(256) void f2b_multi(F2B8 j) {
  const int seg = blockIdx.y;
  const int n4 = j.n4[seg];
  const float* __restrict__ in = j.in[seg];
  u16* __restrict__ out = j.out[seg];
  for (int i = blockIdx.x * 256 + threadIdx.x; i < n4; i += gridDim.x * 256) {
    float4 v = ((const float4*)in)[i];
    ((ushort4*)out)[i] = make_ushort4(f2bf(v.x), f2bf(v.y), f2bf(v.z), f2bf(v.w));
  }
}

// ---------------- transpose weight: WT[m,n] = W[n,m], f32 -> bf16 ------------
__global__ __launch_bounds__(256)
void wtrans(const float* __restrict__ W, u16* __restrict__ WT) {
  __shared__ float tile[64][65];
  const int bx = blockIdx.x, by = blockIdx.y;   // 16 x 16 blocks of 64x64
  const int r = threadIdx.x >> 2, c0 = (threadIdx.x & 3) * 16;
  const float* src = W + (size_t)(by * 64 + r) * 1024 + bx * 64 + c0;
#pragma unroll
  for (int e = 0; e < 16; e += 4) {
    float4 v = *(const float4*)(src + e);
    tile[r][c0 + e] = v.x; tile[r][c0 + e + 1] = v.y;
    tile[r][c0 + e + 2] = v.z; tile[r][c0 + e + 3] = v.w;
  }
  __syncthreads();
  u16* dst = WT + (size_t)(bx * 64 + r) * 1024 + by * 64 + c0;
#pragma unroll
  for (int e = 0; e < 16; e += 4) {
    ushort4 o = make_ushort4(f2bf(tile[c0 + e][r]), f2bf(tile[c0 + e + 1][r]),
                             f2bf(tile[c0 + e + 2][r]), f2bf(tile[c0 + e + 3][r]));
    *(ushort4*)(dst + e) = o;
  }
}

// ---------------- 128x128 bf16 GEMM (BK=64, T1+T2): C=A@B^T (+bias) ----------
__global__ __launch_bounds__(256)
void gemm_bt(const u16* __restrict__ A, const u16* __restrict__ B,
             const float* __restrict__ bias, u16* __restrict__ Cb,
             int M, int N, int K) {
  __shared__ u16 sA[128 * 64];
  __shared__ u16 sB[128 * 64];
  const int nwg = (int)(gridDim.x * gridDim.y);
  const int chunk = nwg >> 3;
  int s = blockIdx.y * gridDim.x + blockIdx.x;
  int t = (s & 7) * chunk + (s >> 3);
  const int bn0 = (t & 7) * 128;
  const int bm0 = (t >> 3) * 128;
  const int tid = threadIdx.x;
  const int w = tid >> 6, l = tid & 63;
  const int wr = w >> 1, wc = w & 1;
  const int lr = l & 15, lk = l >> 4;
  const int swz = lr & 7;

  const int srow = tid >> 3;
  const int scol = ((tid & 7) ^ (srow & 7)) << 3;
  const u16* Ab = A + (size_t)(bm0 + srow) * K + scol;
  const u16* Bb = B + (size_t)(bn0 + srow) * K + scol;
  const size_t rstride32 = (size_t)32 * K;

  f32x4 acc[4][4] = {};

  for (int k0 = 0; k0 < K; k0 += 64) {
#pragma unroll
    for (int p = 0; p < 4; ++p) {
      glds16(Ab + p * rstride32 + k0, sA + p * 2048 + w * 512);
      glds16(Bb + p * rstride32 + k0, sB + p * 2048 + w * 512);
    }
    __syncthreads();
#pragma unroll
    for (int ks = 0; ks < 2; ++ks) {
      const int off = (((ks << 2) + lk) ^ swz) << 3;
      bf16x8 af[4], bfr[4];
#pragma unroll
      for (int m = 0; m < 4; ++m)
        af[m] = *(const bf16x8*)(sA + (wr * 64 + m * 16 + lr) * 64 + off);
#pragma unroll
      for (int n = 0; n < 4; ++n)
        bfr[n] = *(const bf16x8*)(sB + (wc * 64 + n * 16 + lr) * 64 + off);
#pragma unroll
      for (int m = 0; m < 4; ++m)
#pragma unroll
        for (int n = 0; n < 4; ++n)
          acc[m][n] = __builtin_amdgcn_mfma_f32_16x16x32_bf16(af[m], bfr[n], acc[m][n], 0, 0, 0);
    }
    __syncthreads();
  }

#pragma unroll
  for (int m = 0; m < 4; ++m) {
    const int grow0 = bm0 + wr * 64 + m * 16 + lk * 4;
#pragma unroll
    for (int n = 0; n < 4; ++n) {
      const int gcol = bn0 + wc * 64 + n * 16 + lr;
      const float bv = bias ? bias[gcol] : 0.0f;
#pragma unroll
      for (int i = 0; i < 4; ++i) {
        const float v = acc[m][n][i] + bv;
        Cb[(size_t)(grow0 + i) * N + gcol] = f2bf(v);
      }
    }
  }
}

// ---------------- q'' GEMM: Q2[b*512+h*64+i, m] = (QV[:,hs]@WT[:,hs]^T)*a[m] -
__global__ __launch_bounds__(256)
void gemm_qpp(const u16* __restrict__ QV, const u16* __restrict__ WT,
              const float* __restrict__ afv, u16* __restrict__ Q2) {
  __shared__ u16 sA[128 * 64];
  __shared__ u16 sB[128 * 64];
  const int h = blockIdx.z;
  int s = blockIdx.y * 8 + blockIdx.x;
  int t = (s & 7) * 16 + (s >> 3);
  const int bn0 = (t & 7) * 128;
  const int bm0 = (t >> 3) * 128;
  const int tid = threadIdx.x;
  const int w = tid >> 6, l = tid & 63;
  const int wr = w >> 1, wc = w & 1;
  const int lr = l & 15, lk = l >> 4;
  const int swz = lr & 7;

  const int srow = tid >> 3;
  const int scol = ((tid & 7) ^ (srow & 7)) << 3;
  const u16* Ab = QV + (size_t)(bm0 + srow) * 1024 + h * 128 + scol;
  const u16* Bb = WT + (size_t)(bn0 + srow) * 1024 + h * 128 + scol;
  const size_t rstride32 = (size_t)32 * 1024;

  f32x4 acc[4][4] = {};

  for (int k0 = 0; k0 < 128; k0 += 64) {
#pragma unroll
    for (int p = 0; p < 4; ++p) {
      glds16(Ab + p * rstride32 + k0, sA + p * 2048 + w * 512);
      glds16(Bb + p * rstride32 + k0, sB + p * 2048 + w * 512);
    }
    __syncthreads();
#pragma unroll
    for (int ks = 0; ks < 2; ++ks) {
      const int off = (((ks << 2) + lk) ^ swz) << 3;
      bf16x8 af[4], bfr[4];
#pragma unroll
      for (int m = 0; m < 4; ++m)
        af[m] = *(const bf16x8*)(sA + (wr * 64 + m * 16 + lr) * 64 + off);
#pragma unroll
      for (int n = 0; n < 4; ++n)
        bfr[n] = *(const bf16x8*)(sB + (wc * 64 + n * 16 + lr) * 64 + off);
#pragma unroll
      for (int m = 0; m < 4; ++m)
#pragma unroll
        for (int n = 0; n < 4; ++n)
          acc[m][n] = __builtin_amdgcn_mfma_f32_16x16x32_bf16(af[m], bfr[n], acc[m][n], 0, 0, 0);
    }
    __syncthreads();
  }

#pragma unroll
  for (int m = 0; m < 4; ++m) {
    const int grow0 = bm0 + wr * 64 + m * 16 + lk * 4;
#pragma unroll
    for (int n = 0; n < 4; ++n) {
      const int gcol = bn0 + wc * 64 + n * 16 + lr;
      const float a = afv[gcol];
#pragma unroll
      for (int i = 0; i < 4; ++i) {
        const int gr = grow0 + i;
        const int q2row = ((gr >> 6) << 9) + h * 64 + (gr & 63);
        Q2[(size_t)q2row * 1024 + gcol] = f2bf(acc[m][n][i] * a);
      }
    }
  }
}

// ---------------- batched vl-score GEMM: per b: S[512,1024] = Q2[b]@Y1[b]^T --
__global__ __launch_bounds__(256)
void gemm_score_b(const u16* __restrict__ Q2, const u16* __restrict__ Y1,
                  float* __restrict__ out) {
  __shared__ u16 sA[128 * 64];
  __shared__ u16 sB[128 * 64];
  int s = (int)((blockIdx.z * gridDim.y + blockIdx.y) * gridDim.x + blockIdx.x);
  int t = (s & 7) * 128 + (s >> 3);
  const int b = t >> 5;
  const int rem = t & 31;
  const int bn0 = (rem & 7) * 128;
  const int bm0 = (rem >> 3) * 128;
  const int tid = threadIdx.x;
  const int w = tid >> 6, l = tid & 63;
  const int wr = w >> 1, wc = w & 1;
  const int lr = l & 15, lk = l >> 4;
  const int swz = lr & 7;

  const int srow = tid >> 3;
  const int scol = ((tid & 7) ^ (srow & 7)) << 3;
  const u16* Ab = Q2 + (size_t)b * 524288 + (size_t)(bm0 + srow) * 1024 + scol;
  const u16* Bb = Y1 + (size_t)b * 1048576 + (size_t)(bn0 + srow) * 1024 + scol;
  const size_t rstride32 = (size_t)32 * 1024;

  f32x4 acc[4][4] = {};

  for (int k0 = 0; k0 < 1024; k0 += 64) {
#pragma unroll
    for (int p = 0; p < 4; ++p) {
      glds16(Ab + p * rstride32 + k0, sA + p * 2048 + w * 512);
      glds16(Bb + p * rstride32 + k0, sB + p * 2048 + w * 512);
    }
    __syncthreads();
#pragma unroll
    for (int ks = 0; ks < 2; ++ks) {
      const int off = (((ks << 2) + lk) ^ swz) << 3;
      bf16x8 af[4], bfr[4];
#pragma unroll
      for (int m = 0; m < 4; ++m)
        af[m] = *(const bf16x8*)(sA + (wr * 64 + m * 16 + lr) * 64 + off);
#pragma unroll
      for (int n = 0; n < 4; ++n)
        bfr[n] = *(const bf16x8*)(sB + (wc * 64 + n * 16 + lr) * 64 + off);
#pragma unroll
      for (int m = 0; m < 4; ++m)
#pragma unroll
        for (int n = 0; n < 4; ++n)
          acc[m][n] = __builtin_amdgcn_mfma_f32_16x16x32_bf16(af[m], bfr[n], acc[m][n], 0, 0, 0);
    }
    __syncthreads();
  }

  float* C = out + (size_t)b * 524288;
#pragma unroll
  for (int m = 0; m < 4; ++m) {
    const int grow0 = bm0 + wr * 64 + m * 16 + lk * 4;
#pragma unroll
    for (int n = 0; n < 4; ++n) {
      const int gcol = bn0 + wc * 64 + n * 16 + lr;
#pragma unroll
      for (int i = 0; i < 4; ++i)
        C[(size_t)(grow0 + i) * 1024 + gcol] = acc[m][n][i];
    }
  }
}

// ---------------- vl softmax (+folded const from QV·wc, query-mask scale) ----
__global__ __launch_bounds__(256)
void vl_softmax(float* __restrict__ S, const float* __restrict__ qmask,
                const u16* __restrict__ QV, const float* __restrict__ wcv) {
  __shared__ float red[4];
  __shared__ float red2[4];
  const int row = blockIdx.x;          // (b*8+h)*64+i
  const int b = row >> 9;
  const int h = (row >> 6) & 7;
  const int i = row & 63;
  const int t = threadIdx.x;
  float cp = 0.f;
  if (t < 128) cp = bf2f(QV[(size_t)(b * 64 + i) * 1024 + h * 128 + t]) * wcv[h * 128 + t];
  for (int o = 32; o > 0; o >>= 1) cp += __shfl_xor(cp, o, 64);
  if ((t & 63) == 0) red2[t >> 6] = cp;
  __syncthreads();
  const float cst = red2[0] + red2[1];
  const float scale = qmask[b * 64 + i] * SCALE;
  float* p = S + (size_t)row * 1024;
  float4 v = ((const float4*)p)[t];
  v.x = (v.x + cst) * scale; v.y = (v.y + cst) * scale;
  v.z = (v.z + cst) * scale; v.w = (v.w + cst) * scale;
  float mx = fmaxf(fmaxf(v.x, v.y), fmaxf(v.z, v.w));
  for (int o = 32; o > 0; o >>= 1) mx = fmaxf(mx, __shfl_xor(mx, o, 64));
  __syncthreads();
  if ((t & 63) == 0) red[t >> 6] = mx;
  __syncthreads();
  mx = fmaxf(fmaxf(red[0], red[1]), fmaxf(red[2], red[3]));
  const float e0 = expf(v.x - mx), e1 = expf(v.y - mx);
  const float e2 = expf(v.z - mx), e3 = expf(v.w - mx);
  float sm = e0 + e1 + e2 + e3;
  for (int o = 32; o > 0; o >>= 1) sm += __shfl_xor(sm, o, 64);
  __syncthreads();
  if ((t & 63) == 0) red[t >> 6] = sm;
  __syncthreads();
  sm = red[0] + red[1] + red[2] + red[3];
  const float inv = 1.0f / sm;
  ((float4*)p)[t] = make_float4(e0 * inv, e1 * inv, e2 * inv, e3 * inv);
}

// ---------------- column stats over bf16 [32768,1024] ------------------------
__global__ __launch_bounds__(256)
void colstats_partial_b(const u16* __restrict__ X, float* __restrict__ ps,
                        float* __restrict__ pq) {
  const int tid = threadIdx.x;
  const int chunk = blockIdx.x;
  const int colb = (tid & 127) * 8;
  const int rg = tid >> 7;
  const u16* p = X + ((size_t)chunk * 128 + rg * 64) * 1024 + colb;
  float s[8] = {}, q[8] = {};
  for (int r = 0; r < 64; ++r) {
    u16x8 v = *(const u16x8*)(p + (size_t)r * 1024);
#pragma unroll
    for (int j = 0; j < 8; ++j) {
      float f = bf2f(v[j]);
      s[j] += f; q[j] += f * f;
    }
  }
  float* dps = ps + (size_t)(chunk * 2 + rg) * 1024 + colb;
  float* dpq = pq + (size_t)(chunk * 2 + rg) * 1024 + colb;
  *(float4*)(dps) = make_float4(s[0], s[1], s[2], s[3]);
  *(float4*)(dps + 4) = make_float4(s[4], s[5], s[6], s[7]);
  *(float4*)(dpq) = make_float4(q[0], q[1], q[2], q[3]);
  *(float4*)(dpq + 4) = make_float4(q[4], q[5], q[6], q[7]);
}
// reduce 512 chunks -> stats + BN-fold vectors a, c
__global__ __launch_bounds__(256)
void colstats_final(const float* __restrict__ ps, const float* __restrict__ pq,
                    float2* __restrict__ st, const float* __restrict__ g,
                    const float* __restrict__ be, float* __restrict__ afv,
                    float* __restrict__ cfv, float inv_n) {
  __shared__ float rs_[8][32], rq_[8][32];
  const int cg = threadIdx.x >> 5, cl = threadIdx.x & 31;
  const int col = blockIdx.x * 32 + cl;
  float s = 0.f, q = 0.f;
  for (int i = 0; i < 64; ++i) {
    const size_t idx = (size_t)(cg * 64 + i) * 1024 + col;
    s += ps[idx]; q += pq[idx];
  }
  rs_[cg][cl] = s; rq_[cg][cl] = q;
  __syncthreads();
  if (cg == 0) {
    for (int i = 1; i < 8; ++i) { s += rs_[i][cl]; q += rq_[i][cl]; }
    const float m = s * inv_n;
    const float v = q * inv_n - m * m;
    const float rs = rsqrtf(v + EPS);
    st[col] = make_float2(m, rs);
    if (afv) {
      const float a = rs * g[col];
      afv[col] = a;
      cfv[col] = be[col] - m * a;
    }
  }
}

// ---------------- small f32 GEMM: out[m,n] = A[m,:]·W[n,:] + bias[n] ---------
__global__ __launch_bounds__(256)
void small_gemm(const float* __restrict__ A, const float* __restrict__ W,
                const float* __restrict__ bias, float* __restrict__ out,
                int N, int K) {
  __shared__ float sA[1024];
  const int m = blockIdx.y;
  const int n = blockIdx.x * 256 + threadIdx.x;
  for (int i = threadIdx.x; i < K; i += 256) sA[i] = A[(size_t)m * K + i];
  __syncthreads();
  const float4* w4 = (const float4*)(W + (size_t)n * K);
  const float4* a4 = (const float4*)sA;
  float acc = bias ? bias[n] : 0.0f;
  for (int k = 0; k < K / 4; ++k) {
    float4 wv = w4[k], av = a4[k];
    acc += av.x * wv.x + av.y * wv.y + av.z * wv.z + av.w * wv.w;
  }
  out[(size_t)m * N + n] = acc;
}

// ---------------- memory-fuse attention (per batch) --------------------------
__global__ __launch_bounds__(256)
void mem_attn(const float* __restrict__ qmf, const u16* __restrict__ KM,
              const u16* __restrict__ VM, const float* __restrict__ mask,
              float* __restrict__ att_out, float* __restrict__ attv_out) {
  __shared__ float qs[1024];
  __shared__ float sS[512];
  __shared__ float sP[512];
  __shared__ float sM[64];
  const int b = blockIdx.x;
  const int tid = threadIdx.x;
  for (int i = tid; i < 1024; i += 256) qs[i] = qmf[i];
  if (tid < 64) sM[tid] = mask[b * 64 + tid];
  __syncthreads();
  for (int p = tid; p < 512; p += 256) {
    const int h = p >> 6, j = p & 63;
    const u16* kr = KM + (size_t)(b * 64 + j) * 1024 + h * 128;
    float acc = 0.f;
    for (int d = 0; d < 128; ++d) acc += qs[h * 128 + d] * bf2f(kr[d]);
    sS[p] = acc * sM[j] * SCALE;
  }
  __syncthreads();
  if (tid < 8) {
    const int h = tid;
    float mx = -3.4e38f;
    for (int j = 0; j < 64; ++j) mx = fmaxf(mx, sS[h * 64 + j]);
    float sum = 0.f;
    for (int j = 0; j < 64; ++j) {
      float e = expf(sS[h * 64 + j] - mx);
      sP[h * 64 + j] = e; sum += e;
    }
    const float inv = 1.0f / sum;
    for (int j = 0; j < 64; ++j) {
      float pp = sP[h * 64 + j] * inv;
      sP[h * 64 + j] = pp;
      att_out[(size_t)(b * 8 + h) * 64 + j] = pp;
    }
  }
  __syncthreads();
  for (int c = tid; c < 1024; c += 256) {
    const int h = c >> 7;
    float acc = 0.f;
    for (int j = 0; j < 64; ++j)
      acc += sP[h * 64 + j] * sM[j] * bf2f(VM[(size_t)(b * 64 + j) * 1024 + c]);
    attv_out[(size_t)b * 1024 + c] = acc;
  }
}

// ---------------- cur = inorm(concat(neg_tok, mem_out)) ----------------------
__global__ __launch_bounds__(256)
void make_cur(const float* __restrict__ neg, const float* __restrict__ memo,
              float* __restrict__ cur_out, float* __restrict__ curw) {
  const int i = blockIdx.x * 256 + threadIdx.x;   // 32768
  const int b = i >> 10, c = i & 1023;
  const float a = neg[c], x = memo[i];
  const float mean = 0.5f * (a + x);
  const float d = a - mean;
  const float rs = rsqrtf(d * d + EPS);
  const float o0 = d * rs, o1 = -d * rs;
  cur_out[(size_t)(b * 2) * 1024 + c] = o0;
  cur_out[(size_t)(b * 2 + 1) * 1024 + c] = o1;
  curw[(size_t)(b * 2) * 1024 + c] = o0;
  curw[(size_t)(b * 2 + 1) * 1024 + c] = o1;
}

// ---------------- ff fold: w''[b,j,h,:] and const_ff[b,j,h] ------------------
__global__ __launch_bounds__(256)
void ffw_fold(const float* __restrict__ kff, const float* __restrict__ wfq,
              const float* __restrict__ qb, const float* __restrict__ afv,
              const float* __restrict__ cfv, u16* __restrict__ w2ff,
              float* __restrict__ cff) {
  __shared__ float redl[4];
  const int b = blockIdx.y, jh = blockIdx.x;
  const int j = jh >> 3, h = jh & 7;
  const int tid = threadIdx.x;
  const int m0 = tid * 4;
  const float* kp = kff + (size_t)b * 2048 + j * 1024 + h * 128;
  float a0 = 0, a1 = 0, a2 = 0, a3 = 0;
  for (int n = 0; n < 128; ++n) {
    const float kv = kp[n];
    const float4 wv = *(const float4*)(wfq + (size_t)(h * 128 + n) * 1024 + m0);
    a0 += kv * wv.x; a1 += kv * wv.y; a2 += kv * wv.z; a3 += kv * wv.w;
  }
  float cpart = a0 * cfv[m0] + a1 * cfv[m0 + 1] + a2 * cfv[m0 + 2] + a3 * cfv[m0 + 3];
  if (tid < 128) cpart += qb[h * 128 + tid] * kp[tid];
  ushort4 o = make_ushort4(f2bf(a0 * afv[m0]), f2bf(a1 * afv[m0 + 1]),
                           f2bf(a2 * afv[m0 + 2]), f2bf(a3 * afv[m0 + 3]));
  *(ushort4*)(w2ff + (size_t)(b * 16 + jh) * 1024 + m0) = o;
  for (int o2 = 32; o2 > 0; o2 >>= 1) cpart += __shfl_xor(cpart, o2, 64);
  if ((tid & 63) == 0) redl[tid >> 6] = cpart;
  __syncthreads();
  if (tid == 0) cff[b * 16 + jh] = redl[0] + redl[1] + redl[2] + redl[3];
}

// ---------------- ff score: S2[b,t,jh] = Y1[b,t,:]·w''[b,jh,:] + cff ---------
__global__ __launch_bounds__(256)
void ff_score(const u16* __restrict__ Y1, const u16* __restrict__ w2ff,
              const float* __restrict__ cff, float* __restrict__ S2) {
  __shared__ u16 sA[128 * 64];
  __shared__ u16 sB[16 * 1024];
  const int chunk = blockIdx.x, b = blockIdx.y;
  const int tid = threadIdx.x;
  const int w = tid >> 6, l = tid & 63;
  const int lr = l & 15, lk = l >> 4;
  const int swz = lr & 7;

  {
    const int n = tid >> 4;
    const int sb = (tid & 15) * 8;
#pragma unroll
    for (int v = 0; v < 8; ++v) {
      const int sidx = sb + v;
      u16x8 val = *(const u16x8*)(w2ff + (size_t)(b * 16 + n) * 1024 + sidx * 8);
      *(u16x8*)(sB + n * 1024 + ((sidx ^ (n & 7)) << 3)) = val;
    }
  }

  const int srow = tid >> 3;
  const int scol = ((tid & 7) ^ (srow & 7)) << 3;
  const u16* Ab = Y1 + ((size_t)(b * 1024 + chunk * 128) + srow) * 1024 + scol;
  const size_t rstride32 = (size_t)32 * 1024;

  f32x4 acc[2] = {};

  for (int k0 = 0; k0 < 1024; k0 += 64) {
#pragma unroll
    for (int p = 0; p < 4; ++p)
      glds16(Ab + p * rstride32 + k0, sA + p * 2048 + w * 512);
    __syncthreads();
#pragma unroll
    for (int ks = 0; ks < 2; ++ks) {
      const int off = (((ks << 2) + lk) ^ swz) << 3;
      bf16x8 a0 = *(const bf16x8*)(sA + (w * 32 + lr) * 64 + off);
      bf16x8 a1 = *(const bf16x8*)(sA + (w * 32 + 16 + lr) * 64 + off);
      const int bs = (k0 >> 3) + (ks << 2) + lk;
      bf16x8 bf_ = *(const bf16x8*)(sB + lr * 1024 + ((bs ^ swz) << 3));
      acc[0] = __builtin_amdgcn_mfma_f32_16x16x32_bf16(a0, bf_, acc[0], 0, 0, 0);
      acc[1] = __builtin_amdgcn_mfma_f32_16x16x32_bf16(a1, bf_, acc[1], 0, 0, 0);
    }
    __syncthreads();
  }

  const float cadd = cff[b * 16 + lr];
#pragma unroll
  for (int m = 0; m < 2; ++m)
#pragma unroll
    for (int i = 0; i < 4; ++i) {
      const int trow = chunk * 128 + w * 32 + m * 16 + lk * 4 + i;
      S2[((size_t)b * 1024 + trow) * 16 + lr] = acc[m][i] + cadd;
    }
}

// ---------------- ff softmax -> P[32768][16] f32 + att output ----------------
__global__ __launch_bounds__(256)
void ff_soft(const float* __restrict__ S2, float* __restrict__ P,
             float* __restrict__ att_out) {
  const int t = blockIdx.x * 256 + threadIdx.x;  // 0..32767
  const int b = t >> 10, tl = t & 1023;
  const float* srow = S2 + (size_t)t * 16;
  float4 s0 = *(const float4*)(srow);
  float4 s1 = *(const float4*)(srow + 4);
  float4 s2 = *(const float4*)(srow + 8);
  float4 s3 = *(const float4*)(srow + 12);
  float sj0[8] = {s0.x, s0.y, s0.z, s0.w, s1.x, s1.y, s1.z, s1.w};
  float sj1[8] = {s2.x, s2.y, s2.z, s2.w, s3.x, s3.y, s3.z, s3.w};
  float p0[8], p1[8];
#pragma unroll
  for (int h = 0; h < 8; ++h) {
    const float a0 = sj0[h] * SCALE, a1 = sj1[h] * SCALE;
    const float mx = fmaxf(a0, a1);
    const float e0 = expf(a0 - mx), e1 = expf(a1 - mx);
    const float inv = 1.f / (e0 + e1);
    p0[h] = e0 * inv; p1[h] = e1 * inv;
    float* o = att_out + ((size_t)(b * 8 + h) * 1024 + tl) * 2;
    o[0] = p0[h]; o[1] = p1[h];
  }
  float* pr = P + (size_t)t * 16;
  *(float4*)(pr)      = make_float4(p0[0], p0[1], p0[2], p0[3]);
  *(float4*)(pr + 4)  = make_float4(p0[4], p0[5], p0[6], p0[7]);
  *(float4*)(pr + 8)  = make_float4(p1[0], p1[1], p1[2], p1[3]);
  *(float4*)(pr + 12) = make_float4(p1[4], p1[5], p1[6], p1[7]);
}

// ---------------- pbar[b][16] = mean_t P; G[b][16][16] = (1/T) P^T P ---------
__global__ __launch_bounds__(256)
void pg_kernel(const float* __restrict__ P, float* __restrict__ G,
               float* __restrict__ pbar) {
  __shared__ float Pl[128][16];
  const int b = blockIdx.x;
  const int tid = threadIdx.x;
  const int j = tid >> 4, j2 = tid & 15;
  float acc = 0.f, accp = 0.f;
  for (int c = 0; c < 8; ++c) {
    __syncthreads();
    for (int i = tid; i < 2048; i += 256)
      Pl[i >> 4][i & 15] = P[((size_t)b * 1024 + c * 128 + (i >> 4)) * 16 + (i & 15)];
    __syncthreads();
    for (int t = 0; t < 128; ++t) {
      acc += Pl[t][j] * Pl[t][j2];
      if (j == 0) accp += Pl[t][j2];
    }
  }
  G[b * 256 + tid] = acc * (1.f / 1024.f);
  if (j == 0) pbar[b * 16 + j2] = accp * (1.f / 1024.f);
}

// ---------------- U[b][jh][m] = sum_d vff[b,j,h*128+d] * wfo[m,h*128+d] ------
__global__ __launch_bounds__(256)
void ufold(const float* __restrict__ vff, const u16* __restrict__ wfoT,
           float* __restrict__ U) {
  const int b = blockIdx.y, jh = blockIdx.x;
  const int j = jh >> 3, h = jh & 7;
  const int m0 = threadIdx.x * 4;
  const float* vp = vff + (size_t)b * 2048 + j * 1024 + h * 128;
  float a0 = 0, a1 = 0, a2 = 0, a3 = 0;
  for (int d = 0; d < 128; ++d) {
    const float kv = vp[d];
    ushort4 wv = *(const ushort4*)(wfoT + (size_t)(h * 128 + d) * 1024 + m0);
    a0 += kv * bf2f(wv.x); a1 += kv * bf2f(wv.y);
    a2 += kv * bf2f(wv.z); a3 += kv * bf2f(wv.w);
  }
  *(float4*)(U + (size_t)(b * 16 + jh) * 1024 + m0) = make_float4(a0, a1, a2, a3);
}

// ---------------- analytic instance-norm stats of ff_out ---------------------
__global__ __launch_bounds__(256)
void istats_a(const float* __restrict__ U, const float* __restrict__ G,
              const float* __restrict__ pbar, const float* __restrict__ ob,
              float* __restrict__ mi, float* __restrict__ rsi) {
  __shared__ float Gs[256], pb[16];
  const int b = blockIdx.x;
  const int tid = threadIdx.x;
  Gs[tid] = G[b * 256 + tid];
  if (tid < 16) pb[tid] = pbar[b * 16 + tid];
  __syncthreads();
#pragma unroll
  for (int e = 0; e < 4; ++e) {
    const int m = tid * 4 + e;
    float u[16];
#pragma unroll
    for (int jj = 0; jj < 16; ++jj) u[jj] = U[(size_t)(b * 16 + jj) * 1024 + m];
    const float o = ob[m];
    float s1 = 0.f;
#pragma unroll
    for (int jj = 0; jj < 16; ++jj) s1 += pb[jj] * u[jj];
    float q = 0.f;
#pragma unroll
    for (int jj = 0; jj < 16; ++jj) {
      float gq = 0.f;
#pragma unroll
      for (int j2 = 0; j2 < 16; ++j2) gq += Gs[jj * 16 + j2] * u[j2];
      q += u[jj] * gq;
    }
    const float mean = s1 + o;
    const float e2 = q + 2.f * o * s1 + o * o;
    const float var = fmaxf(e2 - mean * mean, 0.f);
    mi[b * 1024 + m] = mean;
    rsi[b * 1024 + m] = rsqrtf(var + EPS);
  }
}

// ---------------- U2b[b][32][1024] bf16: rows 0-15 U*rsi, 16 = (ob-mi)*rsi ---
__global__ __launch_bounds__(256)
void u2prep(const float* __restrict__ U, const float* __restrict__ mi,
            const float* __restrict__ rsi, const float* __restrict__ ob,
            u16* __restrict__ U2b) {
  const int b = blockIdx.x;
  const int m0 = threadIdx.x * 4;
  float4 rs4 = *(const float4*)(rsi + b * 1024 + m0);
  const float rr[4] = {rs4.x, rs4.y, rs4.z, rs4.w};
#pragma unroll
  for (int jj = 0; jj < 16; ++jj) {
    float4 u4 = *(const float4*)(U + (size_t)(b * 16 + jj) * 1024 + m0);
    ushort4 o = make_ushort4(f2bf(u4.x * rr[0]), f2bf(u4.y * rr[1]),
                             f2bf(u4.z * rr[2]), f2bf(u4.w * rr[3]));
    *(ushort4*)(U2b + (size_t)(b * 32 + jj) * 1024 + m0) = o;
  }
  float4 mi4 = *(const float4*)(mi + b * 1024 + m0);
  float4 ob4 = *(const float4*)(ob + m0);
  ushort4 od = make_ushort4(
      f2bf((ob4.x - mi4.x) * rr[0]), f2bf((ob4.y - mi4.y) * rr[1]),
      f2bf((ob4.z - mi4.z) * rr[2]), f2bf((ob4.w - mi4.w) * rr[3]));
  *(ushort4*)(U2b + (size_t)(b * 32 + 16) * 1024 + m0) = od;
  ushort4 z = make_ushort4(0, 0, 0, 0);
#pragma unroll
  for (int jj = 17; jj < 32; ++jj)
    *(ushort4*)(U2b + (size_t)(b * 32 + jj) * 1024 + m0) = z;
}

// ---------------- W2op[b][32][1024] = U2b[b] @ wop^T (MFMA, M=32) ------------
__global__ __launch_bounds__(256)
void w2op_gemm(const u16* __restrict__ U2b, const u16* __restrict__ wop,
               float* __restrict__ W2op) {
  __shared__ u16 sA[32 * 64];
  __shared__ u16 sB[128 * 64];
  const int b = blockIdx.y;
  const int bn0 = blockIdx.x * 128;
  const int tid = threadIdx.x;
  const int w = tid >> 6, l = tid & 63;
  const int lr = l & 15, lk = l >> 4;
  const int swz = lr & 7;
  const int srow = tid >> 3;
  const int scol = ((tid & 7) ^ (srow & 7)) << 3;
  const u16* Ab = U2b + (size_t)b * 32768 + (size_t)srow * 1024 + scol;
  const u16* Bb = wop + (size_t)(bn0 + srow) * 1024 + scol;
  const size_t rstride32 = (size_t)32 * 1024;

  f32x4 acc[2][2] = {};
  for (int k0 = 0; k0 < 1024; k0 += 64) {
    glds16(Ab + k0, sA + w * 512);
#pragma unroll
    for (int p = 0; p < 4; ++p)
      glds16(Bb + p * rstride32 + k0, sB + p * 2048 + w * 512);
    __syncthreads();
#pragma unroll
    for (int ks = 0; ks < 2; ++ks) {
      const int off = (((ks << 2) + lk) ^ swz) << 3;
      bf16x8 af[2], bfr[2];
#pragma unroll
      for (int m = 0; m < 2; ++m)
        af[m] = *(const bf16x8*)(sA + (m * 16 + lr) * 64 + off);
#pragma unroll
      for (int n = 0; n < 2; ++n)
        bfr[n] = *(const bf16x8*)(sB + (w * 32 + n * 16 + lr) * 64 + off);
#pragma unroll
      for (int m = 0; m < 2; ++m)
#pragma unroll
        for (int n = 0; n < 2; ++n)
          acc[m][n] = __builtin_amdgcn_mfma_f32_16x16x32_bf16(af[m], bfr[n], acc[m][n], 0, 0, 0);
    }
    __syncthreads();
  }
#pragma unroll
  for (int m = 0; m < 2; ++m)
#pragma unroll
    for (int n = 0; n < 2; ++n)
#pragma unroll
      for (int i = 0; i < 4; ++i) {
        const int row = m * 16 + lk * 4 + i;
        const int col = bn0 + w * 32 + n * 16 + lr;
        W2op[((size_t)b * 32 + row) * 1024 + col] = acc[m][n][i];
      }
}

// ---------------- analytic BN stats of Z (partials over b-groups) ------------
__global__ __launch_bounds__(256)
void znstats_part(const float* __restrict__ W2op, const float* __restrict__ G,
                  const float* __restrict__ pbar, float* __restrict__ pmu,
                  float* __restrict__ pe2) {
  __shared__ float Gs[256], pb[16];
  const int m = blockIdx.x * 256 + threadIdx.x;
  const int bg = blockIdx.y;
  float amu = 0.f, ae2 = 0.f;
  for (int bi = 0; bi < 4; ++bi) {
    const int b = bg * 4 + bi;
    __syncthreads();
    Gs[threadIdx.x] = G[b * 256 + threadIdx.x];
    if (threadIdx.x < 16) pb[threadIdx.x] = pbar[b * 16 + threadIdx.x];
    __syncthreads();
    float wv[17];
#pragma unroll
    for (int jj = 0; jj < 17; ++jj) wv[jj] = W2op[((size_t)b * 32 + jj) * 1024 + m];
    float s1 = 0.f;
#pragma unroll
    for (int jj = 0; jj < 16; ++jj) s1 += pb[jj] * wv[jj];
    float q = 0.f;
#pragma unroll
    for (int jj = 0; jj < 16; ++jj) {
      float gq = 0.f;
#pragma unroll
      for (int j2 = 0; j2 < 16; ++j2) gq += Gs[jj * 16 + j2] * wv[j2];
      q += wv[jj] * gq;
    }
    const float cz = wv[16];
    amu += s1 + cz;
    ae2 += q + 2.f * cz * s1 + cz * cz;
  }
  pmu[bg * 1024 + m] = amu;
  pe2[bg * 1024 + m] = ae2;
}

__global__ __launch_bounds__(256)
void znfin(const float* __restrict__ pmu, const float* __restrict__ pe2,
           const float* __restrict__ g, const float* __restrict__ be,
           float* __restrict__ afin, float* __restrict__ cf0) {
  const int m = blockIdx.x * 256 + threadIdx.x;
  float mu = 0.f, e2 = 0.f;
#pragma unroll
  for (int i = 0; i < 8; ++i) { mu += pmu[i * 1024 + m]; e2 += pe2[i * 1024 + m]; }
  mu *= (1.f / 32.f); e2 *= (1.f / 32.f);
  const float var = fmaxf(e2 - mu * mu, 0.f);
  const float A = rsqrtf(var + EPS) * g[m];
  afin[m] = A;
  cf0[m] = be[m] - mu * A;
}

// ---------------- final: out[t,m] = sum_j P[t,j]*W2op[b][j,m]*A[m] + const ---
// v3: register-resident W (thread owns 4 cols: wreg[17] statically indexed),
// P via 2KB LDS broadcast, 1024 blocks x 32 rows. Stores wave-contiguous 1KB.
__global__ __launch_bounds__(256)
void zfinal(const float* __restrict__ P, const float* __restrict__ W2op,
            const float* __restrict__ afin, const float* __restrict__ cf0,
            float* __restrict__ out) {
  __shared__ float PL[512];            // 32 rows x 16 probs
  const int blk = blockIdx.x;          // 1024 blocks
  const int b = blk >> 5;
  const int r0 = blk * 32;             // global row base
  const int tid = threadIdx.x;
  const int col = tid * 4;

  f32x4 A4 = *(const f32x4*)(afin + col);
  f32x4 wreg[17];
#pragma unroll
  for (int jj = 0; jj < 17; ++jj) {
    f32x4 wv = *(const f32x4*)(W2op + ((size_t)b * 32 + jj) * 1024 + col);
    wreg[jj] = wv * A4;
  }
  const f32x4 basev = wreg[16] + *(const f32x4*)(cf0 + col);

  if (tid < 128)
    ((f32x4*)PL)[tid] = *(const f32x4*)(P + (size_t)r0 * 16 + tid * 4);
  __syncthreads();

  float* obase = out + (size_t)r0 * 1024 + col;
  for (int r = 0; r < 32; ++r) {
    const float* pr = PL + r * 16;
    f32x4 a = basev;
#pragma unroll
    for (int jj = 0; jj < 16; ++jj) a += pr[jj] * wreg[jj];
    *(f32x4*)(obase + (size_t)r * 1024) = a;
  }
}

// =============================================================================
extern "C" void kernel_launch(void* const* d_in, const int* in_sizes, int n_in,
                              void* d_out, int out_size, void* d_ws, size_t ws_size,
                              hipStream_t stream) {
  (void)in_sizes; (void)n_in; (void)out_size; (void)ws_size;

  const float* src      = (const float*)d_in[0];
  const float* lan      = (const float*)d_in[1];
  const float* qmask    = (const float*)d_in[3];
  const float* ip_w     = (const float*)d_in[4];
  const float* ip_g     = (const float*)d_in[6];
  const float* ip_beta  = (const float*)d_in[7];
  const float* lp_w     = (const float*)d_in[8];
  const float* lp_b     = (const float*)d_in[9];
  const float* mem_tok  = (const float*)d_in[10];
  const float* neg_tok  = (const float*)d_in[11];
  const float* vl_qw    = (const float*)d_in[12];
  const float* vl_qb    = (const float*)d_in[13];
  const float* vl_kw    = (const float*)d_in[14];
  const float* vl_kb    = (const float*)d_in[15];
  const float* mf_qw    = (const float*)d_in[20];
  const float* mf_qb    = (const float*)d_in[21];
  const float* mf_kw    = (const float*)d_in[22];
  const float* mf_kb    = (const float*)d_in[23];
  const float* mf_vw    = (const float*)d_in[24];
  const float* mf_vb    = (const float*)d_in[25];
  const float* mf_ow    = (const float*)d_in[26];
  const float* mf_ob    = (const float*)d_in[27];
  const float* ff_qw    = (const float*)d_in[28];
  const float* ff_qb    = (const float*)d_in[29];
  const float* ff_kw    = (const float*)d_in[30];
  const float* ff_kb    = (const float*)d_in[31];
  const float* ff_vw    = (const float*)d_in[32];
  const float* ff_vb    = (const float*)d_in[33];
  const float* ff_ow    = (const float*)d_in[34];
  const float* ff_ob    = (const float*)d_in[35];
  const float* op_w     = (const float*)d_in[36];
  const float* op_g     = (const float*)d_in[38];
  const float* op_beta  = (const float*)d_in[39];

  float* out_final = (float*)d_out;
  float* out_cur   = out_final + 33554432ull;
  float* out_vl    = out_cur + 65536ull;
  float* out_mem   = out_vl + 16777216ull;
  float* out_ff    = out_mem + 16384ull;

  // ---- workspace carve ----
  char* wp = (char*)d_ws;
  auto take = [&](size_t sz) { char* r = wp; wp += (sz + 255) & ~(size_t)255; return r; };
  u16*   W1   = (u16*)  take(67108864);    // Q2 (vl q'')
  u16*   W2   = (u16*)  take(67108864);    // Y1 (pre-BN ip output), live to ff_score
  u16*   SB   = (u16*)  take(67108864);    // src bf16
  u16*   LP   = (u16*)  take(4194304);     // lan_p bf16
  u16*   QV   = (u16*)  take(4194304);     // vl q bf16
  u16*   KM   = (u16*)  take(4194304);     // mf k bf16
  u16*   VM   = (u16*)  take(4194304);     // mf v bf16
  u16*   LANB = (u16*)  take(3145728);     // lan bf16
  u16*   wip  = (u16*)  take(2097152);
  u16*   wlp  = (u16*)  take(1572864);
  u16*   wvq  = (u16*)  take(2097152);
  u16*   wmk  = (u16*)  take(2097152);
  u16*   wmv  = (u16*)  take(2097152);
  u16*   wop  = (u16*)  take(2097152);     // op_w bf16 [m][c]
  u16*   wvkT = (u16*)  take(2097152);     // vl_kw^T bf16
  u16*   wfoT = (u16*)  take(2097152);     // ff_ow^T bf16
  u16*   w2ff = (u16*)  take(1048576);     // folded ff-q weights [32][16][1024]
  u16*   U2b  = (u16*)  take(2097152);     // [32][32][1024] bf16
  float* qmf   = (float*)take(4096);
  float* attvm = (float*)take(131072);
  float* memo  = (float*)take(131072);
  float* curw  = (float*)take(262144);
  float* kff   = (float*)take(262144);
  float* vff   = (float*)take(262144);
  float* ps    = (float*)take(2097152);
  float* pq    = (float*)take(2097152);
  float2* st1  = (float2*)take(8192);
  float* afv   = (float*)take(4096);
  float* cfv   = (float*)take(4096);
  float* wcv   = (float*)take(4096);
  float* cff   = (float*)take(2048);
  float* S2    = (float*)take(2097152);    // [32][1024][16]
  float* Pbuf  = (float*)take(2097152);    // [32768][16]
  float* Ub    = (float*)take(2097152);    // [32][16][1024]
  float* W2opb = (float*)take(4194304);    // [32][32][1024] f32
  float* Gb    = (float*)take(32768);      // [32][256]
  float* pbarb = (float*)take(2048);       // [32][16]
  float* miw   = (float*)take(131072);     // [32][1024]
  float* rsiw  = (float*)take(131072);     // [32][1024]
  float* pmu   = (float*)take(32768);      // [8][1024]
  float* pe2   = (float*)take(32768);      // [8][1024]
  float* afin  = (float*)take(4096);
  float* cf0   = (float*)take(4096);

  const dim3 blk(256);

  // conversions
  f2b_kernel<<<dim3(32768), blk, 0, stream>>>(src, SB, 8388608);
  {
    F2B8 j;
    const float* ins[7] = {lan, ip_w, lp_w, vl_qw, mf_kw, mf_vw, op_w};
    u16* outs[7] = {LANB, wip, wlp, wvq, wmk, wmv, wop};
    int n4s[7] = {393216, 262144, 196608, 262144, 262144, 262144, 262144};
    for (int i = 0; i < 7; ++i) { j.in[i] = ins[i]; j.out[i] = outs[i]; j.n4[i] = n4s[i]; }
    f2b_multi<<<dim3(1024, 7), blk, 0, stream>>>(j);
  }
  wtrans<<<dim3(16, 16), blk, 0, stream>>>(vl_kw, wvkT);
  wtrans<<<dim3(16, 16), blk, 0, stream>>>(ff_ow, wfoT);

  // stage 0: input proj -> Y1 (W2); BN stats + fold vectors
  gemm_bt<<<dim3(8, 256), blk, 0, stream>>>(SB, wip, nullptr, W2, 32768, 1024, 1024);
  colstats_partial_b<<<dim3(256), blk, 0, stream>>>(W2, ps, pq);
  colstats_final<<<dim3(32), blk, 0, stream>>>(ps, pq, st1, ip_g, ip_beta, afv, cfv, 1.0f / 32768.0f);

  // lan proj + vl q proj
  gemm_bt<<<dim3(8, 16), blk, 0, stream>>>(LANB, wlp, lp_b, LP, 2048, 1024, 768);
  gemm_bt<<<dim3(8, 16), blk, 0, stream>>>(LP, wvq, vl_qb, QV, 2048, 1024, 1024);

  // stage 1 (vl, k-proj folded)
  gemm_qpp<<<dim3(8, 16, 8), blk, 0, stream>>>(QV, wvkT, afv, W1);
  small_gemm<<<dim3(4, 1), blk, 0, stream>>>(cfv, vl_kw, vl_kb, wcv, 1024, 1024);
  gemm_score_b<<<dim3(8, 4, 32), blk, 0, stream>>>(W1, W2, out_vl);
  vl_softmax<<<dim3(16384), blk, 0, stream>>>(out_vl, qmask, QV, wcv);

  // stage 2 (memory fuse)
  small_gemm<<<dim3(4, 1), blk, 0, stream>>>(mem_tok, mf_qw, mf_qb, qmf, 1024, 1024);
  gemm_bt<<<dim3(8, 16), blk, 0, stream>>>(LP, wmk, mf_kb, KM, 2048, 1024, 1024);
  gemm_bt<<<dim3(8, 16), blk, 0, stream>>>(LP, wmv, mf_vb, VM, 2048, 1024, 1024);
  mem_attn<<<dim3(32), blk, 0, stream>>>(qmf, KM, VM, qmask, out_mem, attvm);
  small_gemm<<<dim3(4, 32), blk, 0, stream>>>(attvm, mf_ow, mf_ob, memo, 1024, 1024);
  make_cur<<<dim3(128), blk, 0, stream>>>(neg_tok, memo, out_cur, curw);

  // stage 3 (feature fuse, fully rank-16 folded)
  small_gemm<<<dim3(4, 64), blk, 0, stream>>>(curw, ff_kw, ff_kb, kff, 1024, 1024);
  small_gemm<<<dim3(4, 64), blk, 0, stream>>>(curw, ff_vw, ff_vb, vff, 1024, 1024);
  ffw_fold<<<dim3(16, 32), blk, 0, stream>>>(kff, ff_qw, ff_qb, afv, cfv, w2ff, cff);
  ff_score<<<dim3(8, 32), blk, 0, stream>>>(W2, w2ff, cff, S2);
  ff_soft<<<dim3(128), blk, 0, stream>>>(S2, Pbuf, out_ff);
  pg_kernel<<<dim3(32), blk, 0, stream>>>(Pbuf, Gb, pbarb);
  ufold<<<dim3(16, 32), blk, 0, stream>>>(vff, wfoT, Ub);
  istats_a<<<dim3(32), blk, 0, stream>>>(Ub, Gb, pbarb, ff_ob, miw, rsiw);
  u2prep<<<dim3(32), blk, 0, stream>>>(Ub, miw, rsiw, ff_ob, U2b);
  w2op_gemm<<<dim3(8, 32), blk, 0, stream>>>(U2b, wop, W2opb);
  znstats_part<<<dim3(4, 8), blk, 0, stream>>>(W2opb, Gb, pbarb, pmu, pe2);
  znfin<<<dim3(4), blk, 0, stream>>>(pmu, pe2, op_g, op_beta, afin, cf0);
  zfinal<<<dim3(1024), blk, 0, stream>>>(Pbuf, W2opb, afin, cf0, out_final);
}